// Round 4
// baseline (3818.719 us; speedup 1.0000x reference)
//
#include <hip/hip_runtime.h>

typedef __attribute__((ext_vector_type(8))) short bf16x8;
typedef __attribute__((ext_vector_type(4))) float f32x4;
typedef __attribute__((ext_vector_type(4))) unsigned int u32x4;
typedef unsigned short ushort_t;

__device__ inline ushort_t bf16_trunc(float f) { return (ushort_t)(__float_as_uint(f) >> 16); }
__device__ inline float bf16_to_f(ushort_t u) { return __uint_as_float(((unsigned int)u) << 16); }

// ---------------------------------------------------------------------------
// NCHW fp32 -> NHWC bf16 hi/lo planes. One thread per spatial position.
// ---------------------------------------------------------------------------
template<int CI, int HW>
__global__ __launch_bounds__(256)
void convert_nhwc(const float* __restrict__ x, ushort_t* __restrict__ hi,
                  ushort_t* __restrict__ lo, int Mtotal)
{
    const int m = blockIdx.x * 256 + threadIdx.x;
    if (m >= Mtotal) return;
    const int b = m / HW, pos = m - b * HW;
    const float* xp = x + (size_t)b * CI * HW + pos;
    ushort_t* hp = hi + (size_t)m * CI;
    ushort_t* lp = lo + (size_t)m * CI;
#pragma unroll
    for (int ci = 0; ci < CI; ++ci) {
        const float v = xp[(size_t)ci * HW];
        const ushort_t h = bf16_trunc(v);
        hp[ci] = h;
        lp[ci] = bf16_trunc(v - bf16_to_f(h));
    }
}

// ---------------------------------------------------------------------------
// Weight prep: OIHW fp32 -> Bmat bf16 [kk][n][ci] hi/lo, zero-padded in kk,n.
// ---------------------------------------------------------------------------
template<int CI, int KK, int KKPAD, int NPAD, int OC>
__global__ __launch_bounds__(256)
void wprep(const float* __restrict__ w, ushort_t* __restrict__ bhi, ushort_t* __restrict__ blo)
{
    const int idx = blockIdx.x * 256 + threadIdx.x;
    if (idx >= KKPAD * NPAD * CI) return;
    const int kk  = idx / (NPAD * CI);
    const int rem = idx - kk * (NPAD * CI);
    const int n   = rem / CI;
    const int ci  = rem - n * CI;
    const float v = (kk < KK && n < OC) ? w[((size_t)n * CI + ci) * KK + kk] : 0.f;
    const ushort_t h = bf16_trunc(v);
    bhi[idx] = h;
    blo[idx] = bf16_trunc(v - bf16_to_f(h));
}

// ---------------------------------------------------------------------------
// MFMA implicit-im2col conv (offset convs). fp32 via bf16 hi/lo split.
// ---------------------------------------------------------------------------
template<int CI, int K, int H, int W, int Ho, int Wo, int OC, int NT, int KSTEPS>
__global__ __launch_bounds__(256)
void conv_mfma(const ushort_t* __restrict__ Xhi, const ushort_t* __restrict__ Xlo,
               const ushort_t* __restrict__ Bhi, const ushort_t* __restrict__ Blo,
               const float* __restrict__ bias, float* __restrict__ out, int Mtotal)
{
    constexpr int NPAD = NT * 16;
    constexpr int HW   = H * W;
    constexpr int HoWo = Ho * Wo;

    const int lane = threadIdx.x & 63;
    const int wid  = threadIdx.x >> 6;
    const int col  = lane & 15;
    const int quad = lane >> 4;

    const int mBase  = blockIdx.x * 128 + wid * 32;
    const int mLane  = mBase + col;

    f32x4 acc[2][NT];
#pragma unroll
    for (int mt = 0; mt < 2; ++mt)
#pragma unroll
        for (int nt = 0; nt < NT; ++nt) acc[mt][nt] = (f32x4){0.f, 0.f, 0.f, 0.f};

    const int aBase = mLane * CI;
    const int bLane = col * CI;

#pragma unroll
    for (int ks = 0; ks < KSTEPS; ++ks) {
        const int k0  = ks * 32 + quad * 8;
        const int tap = k0 / CI;
        const int ci  = k0 - tap * CI;
        const int dkk = (tap / K) * W + (tap - (tap / K) * K);

        bf16x8 a[2][2];
#pragma unroll
        for (int mt = 0; mt < 2; ++mt) {
            const int aoff = aBase + mt * 16 * CI + dkk * CI + ci;
            a[mt][0] = *(const bf16x8*)(Xhi + aoff);
            a[mt][1] = *(const bf16x8*)(Xlo + aoff);
        }
#pragma unroll
        for (int nt = 0; nt < NT; ++nt) {
            const int boff = tap * NPAD * CI + nt * 16 * CI + bLane + ci;
            const bf16x8 bh = *(const bf16x8*)(Bhi + boff);
            const bf16x8 bl = *(const bf16x8*)(Blo + boff);
#pragma unroll
            for (int mt = 0; mt < 2; ++mt) {
                acc[mt][nt] = __builtin_amdgcn_mfma_f32_16x16x32_bf16(a[mt][0], bh, acc[mt][nt], 0, 0, 0);
                acc[mt][nt] = __builtin_amdgcn_mfma_f32_16x16x32_bf16(a[mt][1], bh, acc[mt][nt], 0, 0, 0);
                acc[mt][nt] = __builtin_amdgcn_mfma_f32_16x16x32_bf16(a[mt][0], bl, acc[mt][nt], 0, 0, 0);
            }
        }
    }

#pragma unroll
    for (int mt = 0; mt < 2; ++mt) {
#pragma unroll
        for (int nt = 0; nt < NT; ++nt) {
            const int n = nt * 16 + col;
            if (n < OC) {
                const float bv = bias[n];
#pragma unroll
                for (int r = 0; r < 4; ++r) {
                    const int m = mBase + mt * 16 + quad * 4 + r;
                    if (m < Mtotal) {
                        const int b   = m / HW;
                        const int pos = m - b * HW;
                        const int y   = pos / W;
                        const int x   = pos - y * W;
                        if (y < Ho && x < Wo)
                            out[((size_t)b * OC + n) * HoWo + y * Wo + x] = acc[mt][nt][r] + bv;
                    }
                }
            }
        }
    }
}

// ---------------------------------------------------------------------------
// Reconstruct 8 fp32 channel values from hi/lo bf16 planes (one 16B load each).
// ---------------------------------------------------------------------------
__device__ inline void recon8(const ushort_t* __restrict__ hp,
                              const ushort_t* __restrict__ lp, float* v)
{
    const u32x4 h = *(const u32x4*)hp;
    const u32x4 l = *(const u32x4*)lp;
#pragma unroll
    for (int d = 0; d < 4; ++d) {
        const unsigned int hw = h[d], lw = l[d];
        v[2 * d]     = __uint_as_float(hw << 16)         + __uint_as_float(lw << 16);
        v[2 * d + 1] = __uint_as_float(hw & 0xffff0000u) + __uint_as_float(lw & 0xffff0000u);
    }
}

// ---------------------------------------------------------------------------
// Deformable conv reading NHWC bf16 hi/lo planes (channel-vectorized gathers).
// Each thread: one output pixel, all CO channels.
// ---------------------------------------------------------------------------
template<int K, int CI, int CO, int H, int W, int Ho, int Wo, bool RELU>
__global__ __launch_bounds__(256)
void deform_hilo(const ushort_t* __restrict__ Xhi, const ushort_t* __restrict__ Xlo,
                 const float* __restrict__ off, const float* __restrict__ w,
                 const float* __restrict__ bias, float* __restrict__ out)
{
    constexpr int KK   = K * K;
    constexpr int HW   = H * W;
    constexpr int HoWo = Ho * Wo;
    const int b = blockIdx.y;
    const int s = blockIdx.x * 256 + threadIdx.x;
    if (s >= HoWo) return;
    const int oy = s / Wo;
    const int ox = s - oy * Wo;

    const float* offp = off + (size_t)(b * 2 * KK) * HoWo + s;
    const size_t xb = (size_t)b * HW;

    float acc[CO];
#pragma unroll
    for (int o = 0; o < CO; ++o) acc[o] = 0.f;

    for (int kk = 0; kk < KK; ++kk) {
        const float dy = offp[(size_t)(2 * kk + 0) * HoWo];
        const float dx = offp[(size_t)(2 * kk + 1) * HoWo];
        const float py = (float)(kk / K + oy) + dy;
        const float px = (float)(kk % K + ox) + dx;
        const float y0f = floorf(py), x0f = floorf(px);
        const float wy = py - y0f, wx = px - x0f;
        const int y0 = (int)y0f, x0 = (int)x0f;
        const int y1 = y0 + 1,   x1 = x0 + 1;

        const float m00 = (y0 >= 0 && y0 < H && x0 >= 0 && x0 < W) ? 1.f : 0.f;
        const float m01 = (y0 >= 0 && y0 < H && x1 >= 0 && x1 < W) ? 1.f : 0.f;
        const float m10 = (y1 >= 0 && y1 < H && x0 >= 0 && x0 < W) ? 1.f : 0.f;
        const float m11 = (y1 >= 0 && y1 < H && x1 >= 0 && x1 < W) ? 1.f : 0.f;

        const float w00 = (1.f - wy) * (1.f - wx) * m00;
        const float w01 = (1.f - wy) * wx         * m01;
        const float w10 = wy         * (1.f - wx) * m10;
        const float w11 = wy         * wx         * m11;

        const int y0c = min(max(y0, 0), H - 1), y1c = min(max(y1, 0), H - 1);
        const int x0c = min(max(x0, 0), W - 1), x1c = min(max(x1, 0), W - 1);
        const size_t p00 = (xb + (size_t)(y0c * W + x0c)) * CI;
        const size_t p01 = (xb + (size_t)(y0c * W + x1c)) * CI;
        const size_t p10 = (xb + (size_t)(y1c * W + x0c)) * CI;
        const size_t p11 = (xb + (size_t)(y1c * W + x1c)) * CI;

#pragma unroll
        for (int c0 = 0; c0 < CI; c0 += 8) {
            float v00[8], v01[8], v10[8], v11[8];
            recon8(Xhi + p00 + c0, Xlo + p00 + c0, v00);
            recon8(Xhi + p01 + c0, Xlo + p01 + c0, v01);
            recon8(Xhi + p10 + c0, Xlo + p10 + c0, v10);
            recon8(Xhi + p11 + c0, Xlo + p11 + c0, v11);
            float sv[8];
#pragma unroll
            for (int j = 0; j < 8; ++j)
                sv[j] = fmaf(v11[j], w11, fmaf(v10[j], w10, fmaf(v01[j], w01, v00[j] * w00)));
#pragma unroll
            for (int j = 0; j < 8; ++j) {
#pragma unroll
                for (int o = 0; o < CO; ++o)
                    acc[o] = fmaf(sv[j], w[(size_t)(o * CI + c0 + j) * KK + kk], acc[o]);
            }
        }
    }

    float* op = out + ((size_t)b * CO) * HoWo + s;
#pragma unroll
    for (int o = 0; o < CO; ++o) {
        float v = acc[o] + bias[o];
        if (RELU) v = fmaxf(v, 0.f);
        op[(size_t)o * HoWo] = v;
    }
}

// ---------------------------------------------------------------------------
// Register-tiled direct VALID conv (stages 1 and 6 offset convs).
// ---------------------------------------------------------------------------
template<int K, int CI, int NOC, int OC, int H, int W, int Ho, int Wo, int PIX>
__global__ __launch_bounds__(256)
void conv_tile(const float* __restrict__ x, const float* __restrict__ w,
               const float* __restrict__ bias, float* __restrict__ out)
{
    constexpr int KK   = K * K;
    constexpr int HoWo = Ho * Wo;
    constexpr int WoG  = (Wo + PIX - 1) / PIX;
    constexpr int G    = Ho * WoG;
    constexpr int XV   = PIX + K - 1;

    const int oc0   = blockIdx.y * NOC;
    const int g_all = blockIdx.x * 256 + threadIdx.x;
    const int b     = g_all / G;
    const int g     = g_all - b * G;
    const int oy    = g / WoG;
    const int ox0   = (g - oy * WoG) * PIX;

    const float* xbp = x + (b * CI) * (H * W) + oy * W + ox0;
    const float* wp  = w + oc0 * (CI * KK);

    float acc[PIX][NOC];
#pragma unroll
    for (int p = 0; p < PIX; ++p)
#pragma unroll
        for (int j = 0; j < NOC; ++j) acc[p][j] = bias[oc0 + j];

    const int lim = W - 1 - ox0;

    for (int ci = 0; ci < CI; ++ci) {
        const float* xc = xbp + ci * (H * W);
#pragma unroll
        for (int ky = 0; ky < K; ++ky) {
            float xv[XV];
#pragma unroll
            for (int i = 0; i < XV; ++i) {
                const int off = (i <= lim) ? i : lim;
                xv[i] = xc[ky * W + off];
            }
#pragma unroll
            for (int kx = 0; kx < K; ++kx) {
#pragma unroll
                for (int p = 0; p < PIX; ++p) {
                    const float v = xv[p + kx];
#pragma unroll
                    for (int j = 0; j < NOC; ++j)
                        acc[p][j] = fmaf(v, wp[j * (CI * KK) + ci * KK + ky * K + kx], acc[p][j]);
                }
            }
        }
    }

    float* op = out + (b * OC + oc0) * HoWo + oy * Wo + ox0;
#pragma unroll
    for (int p = 0; p < PIX; ++p) {
        if (ox0 + p < Wo) {
#pragma unroll
            for (int j = 0; j < NOC; ++j) op[j * HoWo + p] = acc[p][j];
        }
    }
}

// ---------------------------------------------------------------------------
// Original NCHW deform (stage 1 only, CI=1).
// ---------------------------------------------------------------------------
template<int K, int CI, int CO, int H, int W, int Ho, int Wo, bool RELU>
__global__ __launch_bounds__(256)
void deform_conv(const float* __restrict__ x, const float* __restrict__ off,
                 const float* __restrict__ w, const float* __restrict__ bias,
                 float* __restrict__ out)
{
    constexpr int KK   = K * K;
    constexpr int HoWo = Ho * Wo;
    const int b = blockIdx.y;
    const int s = blockIdx.x * 256 + threadIdx.x;
    if (s >= HoWo) return;
    const int oy = s / Wo;
    const int ox = s - oy * Wo;

    const float* xb   = x + b * (CI * H * W);
    const float* offp = off + (b * 2 * KK) * HoWo + s;

    float acc[CO];
#pragma unroll
    for (int o = 0; o < CO; ++o) acc[o] = 0.f;

    for (int kk = 0; kk < KK; ++kk) {
        const float dy = offp[(2 * kk + 0) * HoWo];
        const float dx = offp[(2 * kk + 1) * HoWo];
        const float py = (float)(kk / K + oy) + dy;
        const float px = (float)(kk % K + ox) + dx;
        const float y0f = floorf(py), x0f = floorf(px);
        const float wy = py - y0f, wx = px - x0f;
        const int y0 = (int)y0f, x0 = (int)x0f;
        const int y1 = y0 + 1,   x1 = x0 + 1;

        const float m00 = (y0 >= 0 && y0 < H && x0 >= 0 && x0 < W) ? 1.f : 0.f;
        const float m01 = (y0 >= 0 && y0 < H && x1 >= 0 && x1 < W) ? 1.f : 0.f;
        const float m10 = (y1 >= 0 && y1 < H && x0 >= 0 && x0 < W) ? 1.f : 0.f;
        const float m11 = (y1 >= 0 && y1 < H && x1 >= 0 && x1 < W) ? 1.f : 0.f;

        const float w00 = (1.f - wy) * (1.f - wx) * m00;
        const float w01 = (1.f - wy) * wx         * m01;
        const float w10 = wy         * (1.f - wx) * m10;
        const float w11 = wy         * wx         * m11;

        const int y0c = min(max(y0, 0), H - 1), y1c = min(max(y1, 0), H - 1);
        const int x0c = min(max(x0, 0), W - 1), x1c = min(max(x1, 0), W - 1);
        const int i00 = y0c * W + x0c, i01 = y0c * W + x1c;
        const int i10 = y1c * W + x0c, i11 = y1c * W + x1c;

        for (int c = 0; c < CI; ++c) {
            const float* xc = xb + c * (H * W);
            float sv = xc[i00] * w00;
            sv = fmaf(xc[i01], w01, sv);
            sv = fmaf(xc[i10], w10, sv);
            sv = fmaf(xc[i11], w11, sv);
#pragma unroll
            for (int o = 0; o < CO; ++o)
                acc[o] = fmaf(sv, w[(o * CI + c) * KK + kk], acc[o]);
        }
    }

    float* op = out + (b * CO) * HoWo + s;
#pragma unroll
    for (int o = 0; o < CO; ++o) {
        float v = acc[o] + bias[o];
        if (RELU) v = fmaxf(v, 0.f);
        op[o * HoWo] = v;
    }
}

__global__ void fc_kernel(const float* __restrict__ h, const float* __restrict__ w,
                          const float* __restrict__ bias, float* __restrict__ out,
                          int B, int IN, int OUT, int relu)
{
    const int idx = blockIdx.x * blockDim.x + threadIdx.x;
    if (idx >= B * OUT) return;
    const int b = idx / OUT;
    const int j = idx - b * OUT;
    const float* hb = h + b * IN;
    const float* wj = w + j * IN;
    float acc = bias[j];
    for (int i = 0; i < IN; ++i) acc = fmaf(hb[i], wj[i], acc);
    if (relu) acc = fmaxf(acc, 0.f);
    out[idx] = acc;
}

// ---------------------------------------------------------------------------
// Buffer rotation: stage input NCHW always in A; convert writes hi/lo planes
// into Bb; after convert the NCHW input is dead, so deform output reuses A.
// ---------------------------------------------------------------------------
extern "C" void kernel_launch(void* const* d_in, const int* in_sizes, int n_in,
                              void* d_out, int out_size, void* d_ws, size_t ws_size,
                              hipStream_t stream)
{
    const int B = 512;
    const float* x = (const float*)d_in[0];
    const float *ow[6], *ob[6], *w[6], *bi[6];
    for (int i = 0; i < 6; ++i) {
        ow[i] = (const float*)d_in[1 + 4 * i];
        ob[i] = (const float*)d_in[2 + 4 * i];
        w[i]  = (const float*)d_in[3 + 4 * i];
        bi[i] = (const float*)d_in[4 + 4 * i];
    }
    const float* fc1w = (const float*)d_in[25];
    const float* fc1b = (const float*)d_in[26];
    const float* fc2w = (const float*)d_in[27];
    const float* fc2b = (const float*)d_in[28];
    float* out = (float*)d_out;

    float* A   = (float*)d_ws;        // activations (14M floats)
    float* Bb  = A  + 14000000;       // bf16 hi/lo planes (14M floats = 28M ushorts)
    float* OFF = Bb + 14000000;       // offsets (18.2M floats)
    float* Z   = OFF + 18200000;      // fc intermediate
    ushort_t* WBhi = (ushort_t*)(Z + 200000);
    ushort_t* WBlo = WBhi + 200000;

    const dim3 blk(256);
    #define GRIDT(Ho, Wo, PIX, NG) dim3((B * (Ho) * (((Wo) + (PIX) - 1) / (PIX)) + 255) / 256, (NG), 1)
    #define GRIDD(HoWo)            dim3(((HoWo) + 255) / 256, B)
    #define CEILDIV(a, b) (((a) + (b) - 1) / (b))

    // ---- stage 1: input x (CI=1), conv_tile + NCHW deform -> A ----
    conv_tile<3, 1, 6, 18, 33, 33, 31, 31, 4><<<GRIDT(31, 31, 4, 3), blk, 0, stream>>>(x, ow[0], ob[0], OFF);
    deform_conv<3, 1, 16, 33, 33, 31, 31, true><<<GRIDD(961), blk, 0, stream>>>(x, OFF, w[0], bi[0], A);

    // ---- stage 2: CI=16 K=3 31x31->29x29 OC(off)=18 CO=32 ----
    {
        const int M = B * 961;
        ushort_t* Xhi = (ushort_t*)Bb;
        ushort_t* Xlo = Xhi + (size_t)(M + 2048) * 16;
        convert_nhwc<16, 961><<<CEILDIV(M, 256), blk, 0, stream>>>(A, Xhi, Xlo, M);
        wprep<16, 9, 10, 32, 18><<<CEILDIV(10 * 32 * 16, 256), blk, 0, stream>>>(ow[1], WBhi, WBlo);
        conv_mfma<16, 3, 31, 31, 29, 29, 18, 2, 5><<<CEILDIV(M, 128), blk, 0, stream>>>(Xhi, Xlo, WBhi, WBlo, ob[1], OFF, M);
        deform_hilo<3, 16, 32, 31, 31, 29, 29, true><<<GRIDD(841), blk, 0, stream>>>(Xhi, Xlo, OFF, w[1], bi[1], A);
    }
    // ---- stage 3: CI=32 K=5 29x29->25x25 OC(off)=50 CO=16 (no relu) ----
    {
        const int M = B * 841;
        ushort_t* Xhi = (ushort_t*)Bb;
        ushort_t* Xlo = Xhi + (size_t)(M + 2048) * 32;
        convert_nhwc<32, 841><<<CEILDIV(M, 256), blk, 0, stream>>>(A, Xhi, Xlo, M);
        wprep<32, 25, 25, 64, 50><<<CEILDIV(25 * 64 * 32, 256), blk, 0, stream>>>(ow[2], WBhi, WBlo);
        conv_mfma<32, 5, 29, 29, 25, 25, 50, 4, 25><<<CEILDIV(M, 128), blk, 0, stream>>>(Xhi, Xlo, WBhi, WBlo, ob[2], OFF, M);
        deform_hilo<5, 32, 16, 29, 29, 25, 25, false><<<GRIDD(625), blk, 0, stream>>>(Xhi, Xlo, OFF, w[2], bi[2], A);
    }
    // ---- stage 4: CI=16 K=7 25x25->19x19 OC(off)=98 CO=16 ----
    {
        const int M = B * 625;
        ushort_t* Xhi = (ushort_t*)Bb;
        ushort_t* Xlo = Xhi + (size_t)(M + 2048) * 16;
        convert_nhwc<16, 625><<<CEILDIV(M, 256), blk, 0, stream>>>(A, Xhi, Xlo, M);
        wprep<16, 49, 50, 112, 98><<<CEILDIV(50 * 112 * 16, 256), blk, 0, stream>>>(ow[3], WBhi, WBlo);
        conv_mfma<16, 7, 25, 25, 19, 19, 98, 7, 25><<<CEILDIV(M, 128), blk, 0, stream>>>(Xhi, Xlo, WBhi, WBlo, ob[3], OFF, M);
        deform_hilo<7, 16, 16, 25, 25, 19, 19, true><<<GRIDD(361), blk, 0, stream>>>(Xhi, Xlo, OFF, w[3], bi[3], A);
    }
    // ---- stage 5: CI=16 K=5 19x19->15x15 OC(off)=50 CO=8 ----
    {
        const int M = B * 361;
        ushort_t* Xhi = (ushort_t*)Bb;
        ushort_t* Xlo = Xhi + (size_t)(M + 2048) * 16;
        convert_nhwc<16, 361><<<CEILDIV(M, 256), blk, 0, stream>>>(A, Xhi, Xlo, M);
        wprep<16, 25, 26, 64, 50><<<CEILDIV(26 * 64 * 16, 256), blk, 0, stream>>>(ow[4], WBhi, WBlo);
        conv_mfma<16, 5, 19, 19, 15, 15, 50, 4, 13><<<CEILDIV(M, 128), blk, 0, stream>>>(Xhi, Xlo, WBhi, WBlo, ob[4], OFF, M);
        deform_hilo<5, 16, 8, 19, 19, 15, 15, true><<<GRIDD(225), blk, 0, stream>>>(Xhi, Xlo, OFF, w[4], bi[4], A);
    }
    // ---- stage 6: CI=8 K=3 15x15->13x13, conv_tile + hilo deform -> A ----
    {
        const int M = B * 225;
        ushort_t* Xhi = (ushort_t*)Bb;
        ushort_t* Xlo = Xhi + (size_t)(M + 2048) * 8;
        conv_tile<3, 8, 6, 18, 15, 15, 13, 13, 4><<<GRIDT(13, 13, 4, 3), blk, 0, stream>>>(A, ow[5], ob[5], OFF);
        convert_nhwc<8, 225><<<CEILDIV(M, 256), blk, 0, stream>>>(A, Xhi, Xlo, M);
        deform_hilo<3, 8, 4, 15, 15, 13, 13, true><<<GRIDD(169), blk, 0, stream>>>(Xhi, Xlo, OFF, w[5], bi[5], A);
    }

    // ---- FC head (reads A = 512 x 4 x 13 x 13) ----
    fc_kernel<<<dim3(CEILDIV(B * 256, 256)), blk, 0, stream>>>(A, fc1w, fc1b, Z, B, 676, 256, 1);
    fc_kernel<<<dim3(CEILDIV(B * 10, 256)), blk, 0, stream>>>(Z, fc2w, fc2b, out, B, 256, 10, 0);

    #undef GRIDT
    #undef GRIDD
    #undef CEILDIV
}

// Round 5
// 2109.864 us; speedup vs baseline: 1.8099x; 1.8099x over previous
//
#include <hip/hip_runtime.h>

typedef __attribute__((ext_vector_type(8))) short bf16x8;
typedef __attribute__((ext_vector_type(4))) float f32x4;
typedef unsigned short ushort_t;

__device__ inline ushort_t bf16_trunc(float f) { return (ushort_t)(__float_as_uint(f) >> 16); }
__device__ inline float bf16_to_f(ushort_t u) { return __uint_as_float(((unsigned int)u) << 16); }

// ---------------------------------------------------------------------------
// NCHW fp32 -> NHWC bf16 hi/lo planes (A-operand for conv_mfma).
// ---------------------------------------------------------------------------
template<int CI, int HW>
__global__ __launch_bounds__(256)
void convert_nhwc(const float* __restrict__ x, ushort_t* __restrict__ hi,
                  ushort_t* __restrict__ lo, int Mtotal)
{
    const int m = blockIdx.x * 256 + threadIdx.x;
    if (m >= Mtotal) return;
    const int b = m / HW, pos = m - b * HW;
    const float* xp = x + (size_t)b * CI * HW + pos;
    ushort_t* hp = hi + (size_t)m * CI;
    ushort_t* lp = lo + (size_t)m * CI;
#pragma unroll
    for (int ci = 0; ci < CI; ++ci) {
        const float v = xp[(size_t)ci * HW];
        const ushort_t h = bf16_trunc(v);
        hp[ci] = h;
        lp[ci] = bf16_trunc(v - bf16_to_f(h));
    }
}

// ---------------------------------------------------------------------------
// Weight prep: OIHW fp32 -> Bmat bf16 [kk][n][ci] hi/lo, zero-padded in kk,n.
// ---------------------------------------------------------------------------
template<int CI, int KK, int KKPAD, int NPAD, int OC>
__global__ __launch_bounds__(256)
void wprep(const float* __restrict__ w, ushort_t* __restrict__ bhi, ushort_t* __restrict__ blo)
{
    const int idx = blockIdx.x * 256 + threadIdx.x;
    if (idx >= KKPAD * NPAD * CI) return;
    const int kk  = idx / (NPAD * CI);
    const int rem = idx - kk * (NPAD * CI);
    const int n   = rem / CI;
    const int ci  = rem - n * CI;
    const float v = (kk < KK && n < OC) ? w[((size_t)n * CI + ci) * KK + kk] : 0.f;
    const ushort_t h = bf16_trunc(v);
    bhi[idx] = h;
    blo[idx] = bf16_trunc(v - bf16_to_f(h));
}

// ---------------------------------------------------------------------------
// MFMA implicit-im2col conv (offset convs). fp32 via bf16 hi/lo split.
// ---------------------------------------------------------------------------
template<int CI, int K, int H, int W, int Ho, int Wo, int OC, int NT, int KSTEPS>
__global__ __launch_bounds__(256)
void conv_mfma(const ushort_t* __restrict__ Xhi, const ushort_t* __restrict__ Xlo,
               const ushort_t* __restrict__ Bhi, const ushort_t* __restrict__ Blo,
               const float* __restrict__ bias, float* __restrict__ out, int Mtotal)
{
    constexpr int NPAD = NT * 16;
    constexpr int HW   = H * W;
    constexpr int HoWo = Ho * Wo;

    const int lane = threadIdx.x & 63;
    const int wid  = threadIdx.x >> 6;
    const int col  = lane & 15;
    const int quad = lane >> 4;

    const int mBase  = blockIdx.x * 128 + wid * 32;
    const int mLane  = mBase + col;

    f32x4 acc[2][NT];
#pragma unroll
    for (int mt = 0; mt < 2; ++mt)
#pragma unroll
        for (int nt = 0; nt < NT; ++nt) acc[mt][nt] = (f32x4){0.f, 0.f, 0.f, 0.f};

    const int aBase = mLane * CI;
    const int bLane = col * CI;

#pragma unroll
    for (int ks = 0; ks < KSTEPS; ++ks) {
        const int k0  = ks * 32 + quad * 8;
        const int tap = k0 / CI;
        const int ci  = k0 - tap * CI;
        const int dkk = (tap / K) * W + (tap - (tap / K) * K);

        bf16x8 a[2][2];
#pragma unroll
        for (int mt = 0; mt < 2; ++mt) {
            const int aoff = aBase + mt * 16 * CI + dkk * CI + ci;
            a[mt][0] = *(const bf16x8*)(Xhi + aoff);
            a[mt][1] = *(const bf16x8*)(Xlo + aoff);
        }
#pragma unroll
        for (int nt = 0; nt < NT; ++nt) {
            const int boff = tap * NPAD * CI + nt * 16 * CI + bLane + ci;
            const bf16x8 bh = *(const bf16x8*)(Bhi + boff);
            const bf16x8 bl = *(const bf16x8*)(Blo + boff);
#pragma unroll
            for (int mt = 0; mt < 2; ++mt) {
                acc[mt][nt] = __builtin_amdgcn_mfma_f32_16x16x32_bf16(a[mt][0], bh, acc[mt][nt], 0, 0, 0);
                acc[mt][nt] = __builtin_amdgcn_mfma_f32_16x16x32_bf16(a[mt][1], bh, acc[mt][nt], 0, 0, 0);
                acc[mt][nt] = __builtin_amdgcn_mfma_f32_16x16x32_bf16(a[mt][0], bl, acc[mt][nt], 0, 0, 0);
            }
        }
    }

#pragma unroll
    for (int mt = 0; mt < 2; ++mt) {
#pragma unroll
        for (int nt = 0; nt < NT; ++nt) {
            const int n = nt * 16 + col;
            if (n < OC) {
                const float bv = bias[n];
#pragma unroll
                for (int r = 0; r < 4; ++r) {
                    const int m = mBase + mt * 16 + quad * 4 + r;
                    if (m < Mtotal) {
                        const int b   = m / HW;
                        const int pos = m - b * HW;
                        const int y   = pos / W;
                        const int x   = pos - y * W;
                        if (y < Ho && x < Wo)
                            out[((size_t)b * OC + n) * HoWo + y * Wo + x] = acc[mt][nt][r] + bv;
                    }
                }
            }
        }
    }
}

// ---------------------------------------------------------------------------
// LDS-staged deformable conv. One block per batch image; the whole image
// (CSPLIT channels per pass) lives in LDS, pixel-major with STRIDE floats per
// pixel (STRIDE=12: bank-group = (3*pos + cg/4) mod 8, 3 coprime 8 -> spread).
// Gathers become ds_read_b128; HBM sees exactly one pass over the input.
// ---------------------------------------------------------------------------
template<int K, int CI, int CO, int H, int W, int Ho, int Wo, bool RELU,
         int CSPLIT, int STRIDE, int THREADS, int PXT>
__global__ __launch_bounds__(THREADS)
void deform_lds(const float* __restrict__ x, const float* __restrict__ off,
                const float* __restrict__ w, const float* __restrict__ bias,
                float* __restrict__ out)
{
    constexpr int KK   = K * K;
    constexpr int HW   = H * W;
    constexpr int HoWo = Ho * Wo;
    constexpr int NPASS = CI / CSPLIT;
    __shared__ __align__(16) float tile[HW * STRIDE];

    const int b   = blockIdx.x;
    const int tid = threadIdx.x;

    float acc[PXT][CO];
#pragma unroll
    for (int p = 0; p < PXT; ++p)
#pragma unroll
        for (int o = 0; o < CO; ++o) acc[p][o] = 0.f;

    for (int pass = 0; pass < NPASS; ++pass) {
        const int cbase = pass * CSPLIT;
        __syncthreads();
        for (int pos = tid; pos < HW; pos += THREADS) {
#pragma unroll
            for (int c = 0; c < CSPLIT; ++c)
                tile[pos * STRIDE + c] = x[((size_t)b * CI + (cbase + c)) * HW + pos];
        }
        __syncthreads();

#pragma unroll
        for (int p = 0; p < PXT; ++p) {
            const int s = tid + p * THREADS;
            if (s < HoWo) {
                const int oy = s / Wo, ox = s - oy * Wo;
                const float* offp = off + ((size_t)b * 2 * KK) * HoWo + s;
                for (int kk = 0; kk < KK; ++kk) {
                    const float dy = offp[(size_t)(2 * kk + 0) * HoWo];
                    const float dx = offp[(size_t)(2 * kk + 1) * HoWo];
                    const float py = (float)(kk / K + oy) + dy;
                    const float px = (float)(kk % K + ox) + dx;
                    const float y0f = floorf(py), x0f = floorf(px);
                    const float wy = py - y0f, wx = px - x0f;
                    const int y0 = (int)y0f, x0 = (int)x0f;
                    const int y1 = y0 + 1,   x1 = x0 + 1;

                    const float m00 = (y0 >= 0 && y0 < H && x0 >= 0 && x0 < W) ? 1.f : 0.f;
                    const float m01 = (y0 >= 0 && y0 < H && x1 >= 0 && x1 < W) ? 1.f : 0.f;
                    const float m10 = (y1 >= 0 && y1 < H && x0 >= 0 && x0 < W) ? 1.f : 0.f;
                    const float m11 = (y1 >= 0 && y1 < H && x1 >= 0 && x1 < W) ? 1.f : 0.f;

                    const float w00 = (1.f - wy) * (1.f - wx) * m00;
                    const float w01 = (1.f - wy) * wx         * m01;
                    const float w10 = wy         * (1.f - wx) * m10;
                    const float w11 = wy         * wx         * m11;

                    const int y0c = min(max(y0, 0), H - 1), y1c = min(max(y1, 0), H - 1);
                    const int x0c = min(max(x0, 0), W - 1), x1c = min(max(x1, 0), W - 1);
                    const int i00 = (y0c * W + x0c) * STRIDE;
                    const int i01 = (y0c * W + x1c) * STRIDE;
                    const int i10 = (y1c * W + x0c) * STRIDE;
                    const int i11 = (y1c * W + x1c) * STRIDE;

                    if constexpr (CSPLIT % 4 == 0) {
#pragma unroll
                        for (int cg = 0; cg < CSPLIT; cg += 4) {
                            const f32x4 v00 = *(const f32x4*)(tile + i00 + cg);
                            const f32x4 v01 = *(const f32x4*)(tile + i01 + cg);
                            const f32x4 v10 = *(const f32x4*)(tile + i10 + cg);
                            const f32x4 v11 = *(const f32x4*)(tile + i11 + cg);
#pragma unroll
                            for (int j = 0; j < 4; ++j) {
                                const float sv = fmaf(v11[j], w11, fmaf(v10[j], w10,
                                                 fmaf(v01[j], w01, v00[j] * w00)));
#pragma unroll
                                for (int o = 0; o < CO; ++o)
                                    acc[p][o] = fmaf(sv, w[(size_t)(o * CI + cbase + cg + j) * KK + kk], acc[p][o]);
                            }
                        }
                    } else {
                        const float sv = fmaf(tile[i11], w11, fmaf(tile[i10], w10,
                                         fmaf(tile[i01], w01, tile[i00] * w00)));
#pragma unroll
                        for (int o = 0; o < CO; ++o)
                            acc[p][o] = fmaf(sv, w[(size_t)(o * CI + cbase) * KK + kk], acc[p][o]);
                    }
                }
            }
        }
    }

#pragma unroll
    for (int p = 0; p < PXT; ++p) {
        const int s = tid + p * THREADS;
        if (s < HoWo) {
            float* op = out + ((size_t)b * CO) * HoWo + s;
#pragma unroll
            for (int o = 0; o < CO; ++o) {
                float v = acc[p][o] + bias[o];
                if (RELU) v = fmaxf(v, 0.f);
                op[(size_t)o * HoWo] = v;
            }
        }
    }
}

// ---------------------------------------------------------------------------
// Register-tiled direct VALID conv (stages 1 and 6 offset convs).
// ---------------------------------------------------------------------------
template<int K, int CI, int NOC, int OC, int H, int W, int Ho, int Wo, int PIX>
__global__ __launch_bounds__(256)
void conv_tile(const float* __restrict__ x, const float* __restrict__ w,
               const float* __restrict__ bias, float* __restrict__ out)
{
    constexpr int KK   = K * K;
    constexpr int HoWo = Ho * Wo;
    constexpr int WoG  = (Wo + PIX - 1) / PIX;
    constexpr int G    = Ho * WoG;
    constexpr int XV   = PIX + K - 1;

    const int oc0   = blockIdx.y * NOC;
    const int g_all = blockIdx.x * 256 + threadIdx.x;
    const int b     = g_all / G;
    const int g     = g_all - b * G;
    const int oy    = g / WoG;
    const int ox0   = (g - oy * WoG) * PIX;

    const float* xbp = x + (b * CI) * (H * W) + oy * W + ox0;
    const float* wp  = w + oc0 * (CI * KK);

    float acc[PIX][NOC];
#pragma unroll
    for (int p = 0; p < PIX; ++p)
#pragma unroll
        for (int j = 0; j < NOC; ++j) acc[p][j] = bias[oc0 + j];

    const int lim = W - 1 - ox0;

    for (int ci = 0; ci < CI; ++ci) {
        const float* xc = xbp + ci * (H * W);
#pragma unroll
        for (int ky = 0; ky < K; ++ky) {
            float xv[XV];
#pragma unroll
            for (int i = 0; i < XV; ++i) {
                const int off = (i <= lim) ? i : lim;
                xv[i] = xc[ky * W + off];
            }
#pragma unroll
            for (int kx = 0; kx < K; ++kx) {
#pragma unroll
                for (int p = 0; p < PIX; ++p) {
                    const float v = xv[p + kx];
#pragma unroll
                    for (int j = 0; j < NOC; ++j)
                        acc[p][j] = fmaf(v, wp[j * (CI * KK) + ci * KK + ky * K + kx], acc[p][j]);
                }
            }
        }
    }

    float* op = out + (b * OC + oc0) * HoWo + oy * Wo + ox0;
#pragma unroll
    for (int p = 0; p < PIX; ++p) {
        if (ox0 + p < Wo) {
#pragma unroll
            for (int j = 0; j < NOC; ++j) op[j * HoWo + p] = acc[p][j];
        }
    }
}

__global__ void fc_kernel(const float* __restrict__ h, const float* __restrict__ w,
                          const float* __restrict__ bias, float* __restrict__ out,
                          int B, int IN, int OUT, int relu)
{
    const int idx = blockIdx.x * blockDim.x + threadIdx.x;
    if (idx >= B * OUT) return;
    const int b = idx / OUT;
    const int j = idx - b * OUT;
    const float* hb = h + b * IN;
    const float* wj = w + j * IN;
    float acc = bias[j];
    for (int i = 0; i < IN; ++i) acc = fmaf(hb[i], wj[i], acc);
    if (relu) acc = fmaxf(acc, 0.f);
    out[idx] = acc;
}

// ---------------------------------------------------------------------------
// Buffer ping-pong: stage input NCHW in P; convert writes planes into Q;
// conv_mfma consumes planes; deform reads P (via LDS) and writes Q (planes
// are dead by then). Roles swap each stage.
// ---------------------------------------------------------------------------
extern "C" void kernel_launch(void* const* d_in, const int* in_sizes, int n_in,
                              void* d_out, int out_size, void* d_ws, size_t ws_size,
                              hipStream_t stream)
{
    const int B = 512;
    const float* x = (const float*)d_in[0];
    const float *ow[6], *ob[6], *w[6], *bi[6];
    for (int i = 0; i < 6; ++i) {
        ow[i] = (const float*)d_in[1 + 4 * i];
        ob[i] = (const float*)d_in[2 + 4 * i];
        w[i]  = (const float*)d_in[3 + 4 * i];
        bi[i] = (const float*)d_in[4 + 4 * i];
    }
    const float* fc1w = (const float*)d_in[25];
    const float* fc1b = (const float*)d_in[26];
    const float* fc2w = (const float*)d_in[27];
    const float* fc2b = (const float*)d_in[28];
    float* out = (float*)d_out;

    float* P   = (float*)d_ws;        // 14M floats
    float* Q   = P  + 14000000;       // 14M floats
    float* OFF = Q  + 14000000;       // 18.2M floats
    float* Z   = OFF + 18200000;      // fc intermediate
    ushort_t* WBhi = (ushort_t*)(Z + 200000);
    ushort_t* WBlo = WBhi + 200000;

    const dim3 blk(256);
    #define GRIDT(Ho, Wo, PIX, NG) dim3((B * (Ho) * (((Wo) + (PIX) - 1) / (PIX)) + 255) / 256, (NG), 1)
    #define CEILDIV(a, b) (((a) + (b) - 1) / (b))

    // ---- stage 1: input x (CI=1). conv_tile -> OFF; deform_lds -> P ----
    conv_tile<3, 1, 6, 18, 33, 33, 31, 31, 4><<<GRIDT(31, 31, 4, 3), blk, 0, stream>>>(x, ow[0], ob[0], OFF);
    deform_lds<3, 1, 16, 33, 33, 31, 31, true, 1, 1, 512, 2><<<dim3(B), dim3(512), 0, stream>>>(x, OFF, w[0], bi[0], P);

    // ---- stage 2: CI=16 K=3 31x31->29x29 OC(off)=18 CO=32. P -> Q ----
    {
        const int M = B * 961;
        ushort_t* Xhi = (ushort_t*)Q;
        ushort_t* Xlo = Xhi + (size_t)(M + 2048) * 16;
        convert_nhwc<16, 961><<<CEILDIV(M, 256), blk, 0, stream>>>(P, Xhi, Xlo, M);
        wprep<16, 9, 10, 32, 18><<<CEILDIV(10 * 32 * 16, 256), blk, 0, stream>>>(ow[1], WBhi, WBlo);
        conv_mfma<16, 3, 31, 31, 29, 29, 18, 2, 5><<<CEILDIV(M, 128), blk, 0, stream>>>(Xhi, Xlo, WBhi, WBlo, ob[1], OFF, M);
        deform_lds<3, 16, 32, 31, 31, 29, 29, true, 8, 12, 512, 2><<<dim3(B), dim3(512), 0, stream>>>(P, OFF, w[1], bi[1], Q);
    }
    // ---- stage 3: CI=32 K=5 29x29->25x25 OC(off)=50 CO=16 (no relu). Q -> P ----
    {
        const int M = B * 841;
        ushort_t* Xhi = (ushort_t*)P;
        ushort_t* Xlo = Xhi + (size_t)(M + 2048) * 32;
        convert_nhwc<32, 841><<<CEILDIV(M, 256), blk, 0, stream>>>(Q, Xhi, Xlo, M);
        wprep<32, 25, 25, 64, 50><<<CEILDIV(25 * 64 * 32, 256), blk, 0, stream>>>(ow[2], WBhi, WBlo);
        conv_mfma<32, 5, 29, 29, 25, 25, 50, 4, 25><<<CEILDIV(M, 128), blk, 0, stream>>>(Xhi, Xlo, WBhi, WBlo, ob[2], OFF, M);
        deform_lds<5, 32, 16, 29, 29, 25, 25, false, 8, 12, 512, 2><<<dim3(B), dim3(512), 0, stream>>>(Q, OFF, w[2], bi[2], P);
    }
    // ---- stage 4: CI=16 K=7 25x25->19x19 OC(off)=98 CO=16. P -> Q ----
    {
        const int M = B * 625;
        ushort_t* Xhi = (ushort_t*)Q;
        ushort_t* Xlo = Xhi + (size_t)(M + 2048) * 16;
        convert_nhwc<16, 625><<<CEILDIV(M, 256), blk, 0, stream>>>(P, Xhi, Xlo, M);
        wprep<16, 49, 50, 112, 98><<<CEILDIV(50 * 112 * 16, 256), blk, 0, stream>>>(ow[3], WBhi, WBlo);
        conv_mfma<16, 7, 25, 25, 19, 19, 98, 7, 25><<<CEILDIV(M, 128), blk, 0, stream>>>(Xhi, Xlo, WBhi, WBlo, ob[3], OFF, M);
        deform_lds<7, 16, 16, 25, 25, 19, 19, true, 8, 12, 384, 1><<<dim3(B), dim3(384), 0, stream>>>(P, OFF, w[3], bi[3], Q);
    }
    // ---- stage 5: CI=16 K=5 19x19->15x15 OC(off)=50 CO=8. Q -> P ----
    {
        const int M = B * 361;
        ushort_t* Xhi = (ushort_t*)P;
        ushort_t* Xlo = Xhi + (size_t)(M + 2048) * 16;
        convert_nhwc<16, 361><<<CEILDIV(M, 256), blk, 0, stream>>>(Q, Xhi, Xlo, M);
        wprep<16, 25, 26, 64, 50><<<CEILDIV(26 * 64 * 16, 256), blk, 0, stream>>>(ow[4], WBhi, WBlo);
        conv_mfma<16, 5, 19, 19, 15, 15, 50, 4, 13><<<CEILDIV(M, 128), blk, 0, stream>>>(Xhi, Xlo, WBhi, WBlo, ob[4], OFF, M);
        deform_lds<5, 16, 8, 19, 19, 15, 15, true, 8, 12, 256, 1><<<dim3(B), dim3(256), 0, stream>>>(Q, OFF, w[4], bi[4], P);
    }
    // ---- stage 6: CI=8 K=3 15x15->13x13 CO=4. P -> Q ----
    conv_tile<3, 8, 6, 18, 15, 15, 13, 13, 4><<<GRIDT(13, 13, 4, 3), blk, 0, stream>>>(P, ow[5], ob[5], OFF);
    deform_lds<3, 8, 4, 15, 15, 13, 13, true, 8, 12, 192, 1><<<dim3(B), dim3(192), 0, stream>>>(P, OFF, w[5], bi[5], Q);

    // ---- FC head (reads Q = 512 x 4 x 13 x 13) ----
    fc_kernel<<<dim3(CEILDIV(B * 256, 256)), blk, 0, stream>>>(Q, fc1w, fc1b, Z, B, 676, 256, 1);
    fc_kernel<<<dim3(CEILDIV(B * 10, 256)), blk, 0, stream>>>(Z, fc2w, fc2b, out, B, 256, 10, 0);

    #undef GRIDT
    #undef CEILDIV
}

// Round 6
// 2059.736 us; speedup vs baseline: 1.8540x; 1.0243x over previous
//
#include <hip/hip_runtime.h>

typedef __attribute__((ext_vector_type(8))) short bf16x8;
typedef __attribute__((ext_vector_type(4))) float f32x4;
typedef unsigned short ushort_t;

__device__ inline ushort_t bf16_trunc(float f) { return (ushort_t)(__float_as_uint(f) >> 16); }
__device__ inline float bf16_to_f(ushort_t u) { return __uint_as_float(((unsigned int)u) << 16); }

// ---------------------------------------------------------------------------
// NCHW fp32 -> NHWC bf16 hi/lo planes (A-operand for conv_mfma).
// ---------------------------------------------------------------------------
template<int CI, int HW>
__global__ __launch_bounds__(256)
void convert_nhwc(const float* __restrict__ x, ushort_t* __restrict__ hi,
                  ushort_t* __restrict__ lo, int Mtotal)
{
    const int m = blockIdx.x * 256 + threadIdx.x;
    if (m >= Mtotal) return;
    const int b = m / HW, pos = m - b * HW;
    const float* xp = x + (size_t)b * CI * HW + pos;
    ushort_t* hp = hi + (size_t)m * CI;
    ushort_t* lp = lo + (size_t)m * CI;
#pragma unroll
    for (int ci = 0; ci < CI; ++ci) {
        const float v = xp[(size_t)ci * HW];
        const ushort_t h = bf16_trunc(v);
        hp[ci] = h;
        lp[ci] = bf16_trunc(v - bf16_to_f(h));
    }
}

// ---------------------------------------------------------------------------
// Weight prep: OIHW fp32 -> Bmat bf16 [kk][n][ci] hi/lo, zero-padded in kk,n.
// ---------------------------------------------------------------------------
template<int CI, int KK, int KKPAD, int NPAD, int OC>
__global__ __launch_bounds__(256)
void wprep(const float* __restrict__ w, ushort_t* __restrict__ bhi, ushort_t* __restrict__ blo)
{
    const int idx = blockIdx.x * 256 + threadIdx.x;
    if (idx >= KKPAD * NPAD * CI) return;
    const int kk  = idx / (NPAD * CI);
    const int rem = idx - kk * (NPAD * CI);
    const int n   = rem / CI;
    const int ci  = rem - n * CI;
    const float v = (kk < KK && n < OC) ? w[((size_t)n * CI + ci) * KK + kk] : 0.f;
    const ushort_t h = bf16_trunc(v);
    bhi[idx] = h;
    blo[idx] = bf16_trunc(v - bf16_to_f(h));
}

// ---------------------------------------------------------------------------
// MFMA implicit-im2col conv (offset convs). fp32 via bf16 hi/lo split.
// ---------------------------------------------------------------------------
template<int CI, int K, int H, int W, int Ho, int Wo, int OC, int NT, int KSTEPS>
__global__ __launch_bounds__(256)
void conv_mfma(const ushort_t* __restrict__ Xhi, const ushort_t* __restrict__ Xlo,
               const ushort_t* __restrict__ Bhi, const ushort_t* __restrict__ Blo,
               const float* __restrict__ bias, float* __restrict__ out, int Mtotal)
{
    constexpr int NPAD = NT * 16;
    constexpr int HW   = H * W;
    constexpr int HoWo = Ho * Wo;

    const int lane = threadIdx.x & 63;
    const int wid  = threadIdx.x >> 6;
    const int col  = lane & 15;
    const int quad = lane >> 4;

    const int mBase  = blockIdx.x * 128 + wid * 32;
    const int mLane  = mBase + col;

    f32x4 acc[2][NT];
#pragma unroll
    for (int mt = 0; mt < 2; ++mt)
#pragma unroll
        for (int nt = 0; nt < NT; ++nt) acc[mt][nt] = (f32x4){0.f, 0.f, 0.f, 0.f};

    const int aBase = mLane * CI;
    const int bLane = col * CI;

#pragma unroll
    for (int ks = 0; ks < KSTEPS; ++ks) {
        const int k0  = ks * 32 + quad * 8;
        const int tap = k0 / CI;
        const int ci  = k0 - tap * CI;
        const int dkk = (tap / K) * W + (tap - (tap / K) * K);

        bf16x8 a[2][2];
#pragma unroll
        for (int mt = 0; mt < 2; ++mt) {
            const int aoff = aBase + mt * 16 * CI + dkk * CI + ci;
            a[mt][0] = *(const bf16x8*)(Xhi + aoff);
            a[mt][1] = *(const bf16x8*)(Xlo + aoff);
        }
#pragma unroll
        for (int nt = 0; nt < NT; ++nt) {
            const int boff = tap * NPAD * CI + nt * 16 * CI + bLane + ci;
            const bf16x8 bh = *(const bf16x8*)(Bhi + boff);
            const bf16x8 bl = *(const bf16x8*)(Blo + boff);
#pragma unroll
            for (int mt = 0; mt < 2; ++mt) {
                acc[mt][nt] = __builtin_amdgcn_mfma_f32_16x16x32_bf16(a[mt][0], bh, acc[mt][nt], 0, 0, 0);
                acc[mt][nt] = __builtin_amdgcn_mfma_f32_16x16x32_bf16(a[mt][1], bh, acc[mt][nt], 0, 0, 0);
                acc[mt][nt] = __builtin_amdgcn_mfma_f32_16x16x32_bf16(a[mt][0], bl, acc[mt][nt], 0, 0, 0);
            }
        }
    }

#pragma unroll
    for (int mt = 0; mt < 2; ++mt) {
#pragma unroll
        for (int nt = 0; nt < NT; ++nt) {
            const int n = nt * 16 + col;
            if (n < OC) {
                const float bv = bias[n];
#pragma unroll
                for (int r = 0; r < 4; ++r) {
                    const int m = mBase + mt * 16 + quad * 4 + r;
                    if (m < Mtotal) {
                        const int b   = m / HW;
                        const int pos = m - b * HW;
                        const int y   = pos / W;
                        const int x   = pos - y * W;
                        if (y < Ho && x < Wo)
                            out[((size_t)b * OC + n) * HoWo + y * Wo + x] = acc[mt][nt][r] + bv;
                    }
                }
            }
        }
    }
}

// ---------------------------------------------------------------------------
// LDS-staged deformable conv with pixel-range SPLIT.
// Grid = B * SPLIT blocks; block (b, sp) handles pixels [sp*CHUNK, ...).
// Every block of an image loads the same LDS tile (CSPLIT channels per pass,
// pixel-major, STRIDE floats/pixel; STRIDE=12 spreads b128 bank-groups).
// Each active thread owns exactly one output pixel -> no imbalance.
// ---------------------------------------------------------------------------
template<int K, int CI, int CO, int H, int W, int Ho, int Wo, bool RELU,
         int CSPLIT, int STRIDE, int THREADS, int SPLIT>
__global__ __launch_bounds__(THREADS)
void deform_lds(const float* __restrict__ x, const float* __restrict__ off,
                const float* __restrict__ w, const float* __restrict__ bias,
                float* __restrict__ out)
{
    constexpr int KK    = K * K;
    constexpr int HW    = H * W;
    constexpr int HoWo  = Ho * Wo;
    constexpr int NPASS = CI / CSPLIT;
    constexpr int CHUNK = (HoWo + SPLIT - 1) / SPLIT;
    static_assert(CHUNK <= THREADS, "chunk must fit in one block");
    __shared__ __align__(16) float tile[HW * STRIDE];

    const int b   = blockIdx.x / SPLIT;
    const int sp  = blockIdx.x - b * SPLIT;
    const int tid = threadIdx.x;
    const int s   = sp * CHUNK + tid;
    const bool active = (tid < CHUNK) && (s < HoWo);

    const int oy = s / Wo, ox = s - oy * Wo;
    const float* offp = off + ((size_t)b * 2 * KK) * HoWo + s;

    float acc[CO];
#pragma unroll
    for (int o = 0; o < CO; ++o) acc[o] = 0.f;

    for (int pass = 0; pass < NPASS; ++pass) {
        const int cbase = pass * CSPLIT;
        __syncthreads();
        for (int pos = tid; pos < HW; pos += THREADS) {
#pragma unroll
            for (int c = 0; c < CSPLIT; ++c)
                tile[pos * STRIDE + c] = x[((size_t)b * CI + (cbase + c)) * HW + pos];
        }
        __syncthreads();

        if (active) {
            for (int kk = 0; kk < KK; ++kk) {
                const float dy = offp[(size_t)(2 * kk + 0) * HoWo];
                const float dx = offp[(size_t)(2 * kk + 1) * HoWo];
                const float py = (float)(kk / K + oy) + dy;
                const float px = (float)(kk % K + ox) + dx;
                const float y0f = floorf(py), x0f = floorf(px);
                const float wy = py - y0f, wx = px - x0f;
                const int y0 = (int)y0f, x0 = (int)x0f;
                const int y1 = y0 + 1,   x1 = x0 + 1;

                const float m00 = (y0 >= 0 && y0 < H && x0 >= 0 && x0 < W) ? 1.f : 0.f;
                const float m01 = (y0 >= 0 && y0 < H && x1 >= 0 && x1 < W) ? 1.f : 0.f;
                const float m10 = (y1 >= 0 && y1 < H && x0 >= 0 && x0 < W) ? 1.f : 0.f;
                const float m11 = (y1 >= 0 && y1 < H && x1 >= 0 && x1 < W) ? 1.f : 0.f;

                const float w00 = (1.f - wy) * (1.f - wx) * m00;
                const float w01 = (1.f - wy) * wx         * m01;
                const float w10 = wy         * (1.f - wx) * m10;
                const float w11 = wy         * wx         * m11;

                const int y0c = min(max(y0, 0), H - 1), y1c = min(max(y1, 0), H - 1);
                const int x0c = min(max(x0, 0), W - 1), x1c = min(max(x1, 0), W - 1);
                const int i00 = (y0c * W + x0c) * STRIDE;
                const int i01 = (y0c * W + x1c) * STRIDE;
                const int i10 = (y1c * W + x0c) * STRIDE;
                const int i11 = (y1c * W + x1c) * STRIDE;

                if constexpr (CSPLIT % 4 == 0) {
#pragma unroll
                    for (int cg = 0; cg < CSPLIT; cg += 4) {
                        const f32x4 v00 = *(const f32x4*)(tile + i00 + cg);
                        const f32x4 v01 = *(const f32x4*)(tile + i01 + cg);
                        const f32x4 v10 = *(const f32x4*)(tile + i10 + cg);
                        const f32x4 v11 = *(const f32x4*)(tile + i11 + cg);
#pragma unroll
                        for (int j = 0; j < 4; ++j) {
                            const float sv = fmaf(v11[j], w11, fmaf(v10[j], w10,
                                             fmaf(v01[j], w01, v00[j] * w00)));
#pragma unroll
                            for (int o = 0; o < CO; ++o)
                                acc[o] = fmaf(sv, w[(size_t)(o * CI + cbase + cg + j) * KK + kk], acc[o]);
                        }
                    }
                } else {
                    const float sv = fmaf(tile[i11], w11, fmaf(tile[i10], w10,
                                     fmaf(tile[i01], w01, tile[i00] * w00)));
#pragma unroll
                    for (int o = 0; o < CO; ++o)
                        acc[o] = fmaf(sv, w[(size_t)(o * CI + cbase) * KK + kk], acc[o]);
                }
            }
        }
    }

    if (active) {
        float* op = out + ((size_t)b * CO) * HoWo + s;
#pragma unroll
        for (int o = 0; o < CO; ++o) {
            float v = acc[o] + bias[o];
            if (RELU) v = fmaxf(v, 0.f);
            op[(size_t)o * HoWo] = v;
        }
    }
}

// ---------------------------------------------------------------------------
// Register-tiled direct VALID conv (stages 1 and 6 offset convs).
// ---------------------------------------------------------------------------
template<int K, int CI, int NOC, int OC, int H, int W, int Ho, int Wo, int PIX>
__global__ __launch_bounds__(256)
void conv_tile(const float* __restrict__ x, const float* __restrict__ w,
               const float* __restrict__ bias, float* __restrict__ out)
{
    constexpr int KK   = K * K;
    constexpr int HoWo = Ho * Wo;
    constexpr int WoG  = (Wo + PIX - 1) / PIX;
    constexpr int G    = Ho * WoG;
    constexpr int XV   = PIX + K - 1;

    const int oc0   = blockIdx.y * NOC;
    const int g_all = blockIdx.x * 256 + threadIdx.x;
    const int b     = g_all / G;
    const int g     = g_all - b * G;
    const int oy    = g / WoG;
    const int ox0   = (g - oy * WoG) * PIX;

    const float* xbp = x + (b * CI) * (H * W) + oy * W + ox0;
    const float* wp  = w + oc0 * (CI * KK);

    float acc[PIX][NOC];
#pragma unroll
    for (int p = 0; p < PIX; ++p)
#pragma unroll
        for (int j = 0; j < NOC; ++j) acc[p][j] = bias[oc0 + j];

    const int lim = W - 1 - ox0;

    for (int ci = 0; ci < CI; ++ci) {
        const float* xc = xbp + ci * (H * W);
#pragma unroll
        for (int ky = 0; ky < K; ++ky) {
            float xv[XV];
#pragma unroll
            for (int i = 0; i < XV; ++i) {
                const int off = (i <= lim) ? i : lim;
                xv[i] = xc[ky * W + off];
            }
#pragma unroll
            for (int kx = 0; kx < K; ++kx) {
#pragma unroll
                for (int p = 0; p < PIX; ++p) {
                    const float v = xv[p + kx];
#pragma unroll
                    for (int j = 0; j < NOC; ++j)
                        acc[p][j] = fmaf(v, wp[j * (CI * KK) + ci * KK + ky * K + kx], acc[p][j]);
                }
            }
        }
    }

    float* op = out + (b * OC + oc0) * HoWo + oy * Wo + ox0;
#pragma unroll
    for (int p = 0; p < PIX; ++p) {
        if (ox0 + p < Wo) {
#pragma unroll
            for (int j = 0; j < NOC; ++j) op[j * HoWo + p] = acc[p][j];
        }
    }
}

__global__ void fc_kernel(const float* __restrict__ h, const float* __restrict__ w,
                          const float* __restrict__ bias, float* __restrict__ out,
                          int B, int IN, int OUT, int relu)
{
    const int idx = blockIdx.x * blockDim.x + threadIdx.x;
    if (idx >= B * OUT) return;
    const int b = idx / OUT;
    const int j = idx - b * OUT;
    const float* hb = h + b * IN;
    const float* wj = w + j * IN;
    float acc = bias[j];
    for (int i = 0; i < IN; ++i) acc = fmaf(hb[i], wj[i], acc);
    if (relu) acc = fmaxf(acc, 0.f);
    out[idx] = acc;
}

// ---------------------------------------------------------------------------
// Buffer ping-pong: stage input NCHW in P; convert writes planes into Q;
// conv_mfma consumes planes; deform reads P (via LDS) and writes Q (planes
// are dead by then). Roles swap each stage.
// ---------------------------------------------------------------------------
extern "C" void kernel_launch(void* const* d_in, const int* in_sizes, int n_in,
                              void* d_out, int out_size, void* d_ws, size_t ws_size,
                              hipStream_t stream)
{
    const int B = 512;
    const float* x = (const float*)d_in[0];
    const float *ow[6], *ob[6], *w[6], *bi[6];
    for (int i = 0; i < 6; ++i) {
        ow[i] = (const float*)d_in[1 + 4 * i];
        ob[i] = (const float*)d_in[2 + 4 * i];
        w[i]  = (const float*)d_in[3 + 4 * i];
        bi[i] = (const float*)d_in[4 + 4 * i];
    }
    const float* fc1w = (const float*)d_in[25];
    const float* fc1b = (const float*)d_in[26];
    const float* fc2w = (const float*)d_in[27];
    const float* fc2b = (const float*)d_in[28];
    float* out = (float*)d_out;

    float* P   = (float*)d_ws;        // 14M floats
    float* Q   = P  + 14000000;       // 14M floats
    float* OFF = Q  + 14000000;       // 18.2M floats
    float* Z   = OFF + 18200000;      // fc intermediate
    ushort_t* WBhi = (ushort_t*)(Z + 200000);
    ushort_t* WBlo = WBhi + 200000;

    const dim3 blk(256);
    #define GRIDT(Ho, Wo, PIX, NG) dim3((B * (Ho) * (((Wo) + (PIX) - 1) / (PIX)) + 255) / 256, (NG), 1)
    #define CEILDIV(a, b) (((a) + (b) - 1) / (b))

    // ---- stage 1: input x (CI=1). conv_tile -> OFF; deform_lds -> P ----
    conv_tile<3, 1, 6, 18, 33, 33, 31, 31, 4><<<GRIDT(31, 31, 4, 3), blk, 0, stream>>>(x, ow[0], ob[0], OFF);
    deform_lds<3, 1, 16, 33, 33, 31, 31, true, 1, 1, 512, 2><<<dim3(B * 2), dim3(512), 0, stream>>>(x, OFF, w[0], bi[0], P);

    // ---- stage 2: CI=16 K=3 31x31->29x29 OC(off)=18 CO=32. P -> Q ----
    {
        const int M = B * 961;
        ushort_t* Xhi = (ushort_t*)Q;
        ushort_t* Xlo = Xhi + (size_t)(M + 2048) * 16;
        convert_nhwc<16, 961><<<CEILDIV(M, 256), blk, 0, stream>>>(P, Xhi, Xlo, M);
        wprep<16, 9, 10, 32, 18><<<CEILDIV(10 * 32 * 16, 256), blk, 0, stream>>>(ow[1], WBhi, WBlo);
        conv_mfma<16, 3, 31, 31, 29, 29, 18, 2, 5><<<CEILDIV(M, 128), blk, 0, stream>>>(Xhi, Xlo, WBhi, WBlo, ob[1], OFF, M);
        deform_lds<3, 16, 32, 31, 31, 29, 29, true, 8, 12, 512, 2><<<dim3(B * 2), dim3(512), 0, stream>>>(P, OFF, w[1], bi[1], Q);
    }
    // ---- stage 3: CI=32 K=5 29x29->25x25 OC(off)=50 CO=16 (no relu). Q -> P ----
    {
        const int M = B * 841;
        ushort_t* Xhi = (ushort_t*)P;
        ushort_t* Xlo = Xhi + (size_t)(M + 2048) * 32;
        convert_nhwc<32, 841><<<CEILDIV(M, 256), blk, 0, stream>>>(Q, Xhi, Xlo, M);
        wprep<32, 25, 25, 64, 50><<<CEILDIV(25 * 64 * 32, 256), blk, 0, stream>>>(ow[2], WBhi, WBlo);
        conv_mfma<32, 5, 29, 29, 25, 25, 50, 4, 25><<<CEILDIV(M, 128), blk, 0, stream>>>(Xhi, Xlo, WBhi, WBlo, ob[2], OFF, M);
        deform_lds<5, 32, 16, 29, 29, 25, 25, false, 8, 12, 384, 2><<<dim3(B * 2), dim3(384), 0, stream>>>(Q, OFF, w[2], bi[2], P);
    }
    // ---- stage 4: CI=16 K=7 25x25->19x19 OC(off)=98 CO=16. P -> Q ----
    {
        const int M = B * 625;
        ushort_t* Xhi = (ushort_t*)Q;
        ushort_t* Xlo = Xhi + (size_t)(M + 2048) * 16;
        convert_nhwc<16, 625><<<CEILDIV(M, 256), blk, 0, stream>>>(P, Xhi, Xlo, M);
        wprep<16, 49, 50, 112, 98><<<CEILDIV(50 * 112 * 16, 256), blk, 0, stream>>>(ow[3], WBhi, WBlo);
        conv_mfma<16, 7, 25, 25, 19, 19, 98, 7, 25><<<CEILDIV(M, 128), blk, 0, stream>>>(Xhi, Xlo, WBhi, WBlo, ob[3], OFF, M);
        deform_lds<7, 16, 16, 25, 25, 19, 19, true, 8, 12, 256, 2><<<dim3(B * 2), dim3(256), 0, stream>>>(P, OFF, w[3], bi[3], Q);
    }
    // ---- stage 5: CI=16 K=5 19x19->15x15 OC(off)=50 CO=8. Q -> P ----
    {
        const int M = B * 361;
        ushort_t* Xhi = (ushort_t*)P;
        ushort_t* Xlo = Xhi + (size_t)(M + 2048) * 16;
        convert_nhwc<16, 361><<<CEILDIV(M, 256), blk, 0, stream>>>(Q, Xhi, Xlo, M);
        wprep<16, 25, 26, 64, 50><<<CEILDIV(26 * 64 * 16, 256), blk, 0, stream>>>(ow[4], WBhi, WBlo);
        conv_mfma<16, 5, 19, 19, 15, 15, 50, 4, 13><<<CEILDIV(M, 128), blk, 0, stream>>>(Xhi, Xlo, WBhi, WBlo, ob[4], OFF, M);
        deform_lds<5, 16, 8, 19, 19, 15, 15, true, 8, 12, 256, 1><<<dim3(B), dim3(256), 0, stream>>>(Q, OFF, w[4], bi[4], P);
    }
    // ---- stage 6: CI=8 K=3 15x15->13x13 CO=4. P -> Q ----
    conv_tile<3, 8, 6, 18, 15, 15, 13, 13, 4><<<GRIDT(13, 13, 4, 3), blk, 0, stream>>>(P, ow[5], ob[5], OFF);
    deform_lds<3, 8, 4, 15, 15, 13, 13, true, 8, 12, 192, 1><<<dim3(B), dim3(192), 0, stream>>>(P, OFF, w[5], bi[5], Q);

    // ---- FC head (reads Q = 512 x 4 x 13 x 13) ----
    fc_kernel<<<dim3(CEILDIV(B * 256, 256)), blk, 0, stream>>>(Q, fc1w, fc1b, Z, B, 676, 256, 1);
    fc_kernel<<<dim3(CEILDIV(B * 10, 256)), blk, 0, stream>>>(Z, fc2w, fc2b, out, B, 256, 10, 0);

    #undef GRIDT
    #undef CEILDIV
}

// Round 7
// 1459.215 us; speedup vs baseline: 2.6170x; 1.4115x over previous
//
#include <hip/hip_runtime.h>

typedef __attribute__((ext_vector_type(8))) short bf16x8;
typedef __attribute__((ext_vector_type(4))) float f32x4;
typedef unsigned short ushort_t;

__device__ inline ushort_t bf16_trunc(float f) { return (ushort_t)(__float_as_uint(f) >> 16); }
__device__ inline float bf16_to_f(ushort_t u) { return __uint_as_float(((unsigned int)u) << 16); }

// ---------------------------------------------------------------------------
// NCHW fp32 -> NHWC bf16 hi/lo planes (A-operand for conv_mfma).
// ---------------------------------------------------------------------------
template<int CI, int HW>
__global__ __launch_bounds__(256)
void convert_nhwc(const float* __restrict__ x, ushort_t* __restrict__ hi,
                  ushort_t* __restrict__ lo, int Mtotal)
{
    const int m = blockIdx.x * 256 + threadIdx.x;
    if (m >= Mtotal) return;
    const int b = m / HW, pos = m - b * HW;
    const float* xp = x + (size_t)b * CI * HW + pos;
    ushort_t* hp = hi + (size_t)m * CI;
    ushort_t* lp = lo + (size_t)m * CI;
#pragma unroll
    for (int ci = 0; ci < CI; ++ci) {
        const float v = xp[(size_t)ci * HW];
        const ushort_t h = bf16_trunc(v);
        hp[ci] = h;
        lp[ci] = bf16_trunc(v - bf16_to_f(h));
    }
}

// ---------------------------------------------------------------------------
// Weight prep for conv_mfma: OIHW fp32 -> [kk][n][ci] hi/lo, zero-padded.
// ---------------------------------------------------------------------------
template<int CI, int KK, int KKPAD, int NPAD, int OC>
__global__ __launch_bounds__(256)
void wprep(const float* __restrict__ w, ushort_t* __restrict__ bhi, ushort_t* __restrict__ blo)
{
    const int idx = blockIdx.x * 256 + threadIdx.x;
    if (idx >= KKPAD * NPAD * CI) return;
    const int kk  = idx / (NPAD * CI);
    const int rem = idx - kk * (NPAD * CI);
    const int n   = rem / CI;
    const int ci  = rem - n * CI;
    const float v = (kk < KK && n < OC) ? w[((size_t)n * CI + ci) * KK + kk] : 0.f;
    const ushort_t h = bf16_trunc(v);
    bhi[idx] = h;
    blo[idx] = bf16_trunc(v - bf16_to_f(h));
}

// ---------------------------------------------------------------------------
// Weight prep for deform_mfma: pack [kslot = pass*TPAD+tap][n][j=ci_in_pass]
// so a lane's 8 B-entries (fixed k-slot, fixed n, j=0..7) are contiguous.
// ---------------------------------------------------------------------------
template<int CI, int KK, int TPAD, int NPAD, int OC>
__global__ __launch_bounds__(256)
void wprep_d(const float* __restrict__ w, ushort_t* __restrict__ bhi, ushort_t* __restrict__ blo)
{
    constexpr int NPASS = (CI + 7) / 8;
    constexpr int TOTAL = NPASS * TPAD * NPAD * 8;
    const int idx = blockIdx.x * 256 + threadIdx.x;
    if (idx >= TOTAL) return;
    const int j     = idx & 7;
    const int n     = (idx >> 3) % NPAD;
    const int kslot = (idx >> 3) / NPAD;
    const int pass  = kslot / TPAD;
    const int tap   = kslot - pass * TPAD;
    const int ci    = pass * 8 + j;
    const float v = (tap < KK && n < OC && ci < CI) ? w[((size_t)n * CI + ci) * KK + tap] : 0.f;
    const ushort_t h = bf16_trunc(v);
    bhi[idx] = h;
    blo[idx] = bf16_trunc(v - bf16_to_f(h));
}

// ---------------------------------------------------------------------------
// MFMA implicit-im2col conv (offset convs). fp32 via bf16 hi/lo split.
// ---------------------------------------------------------------------------
template<int CI, int K, int H, int W, int Ho, int Wo, int OC, int NT, int KSTEPS>
__global__ __launch_bounds__(256)
void conv_mfma(const ushort_t* __restrict__ Xhi, const ushort_t* __restrict__ Xlo,
               const ushort_t* __restrict__ Bhi, const ushort_t* __restrict__ Blo,
               const float* __restrict__ bias, float* __restrict__ out, int Mtotal)
{
    constexpr int NPAD = NT * 16;
    constexpr int HW   = H * W;
    constexpr int HoWo = Ho * Wo;

    const int lane = threadIdx.x & 63;
    const int wid  = threadIdx.x >> 6;
    const int col  = lane & 15;
    const int quad = lane >> 4;

    const int mBase  = blockIdx.x * 128 + wid * 32;
    const int mLane  = mBase + col;

    f32x4 acc[2][NT];
#pragma unroll
    for (int mt = 0; mt < 2; ++mt)
#pragma unroll
        for (int nt = 0; nt < NT; ++nt) acc[mt][nt] = (f32x4){0.f, 0.f, 0.f, 0.f};

    const int aBase = mLane * CI;
    const int bLane = col * CI;

#pragma unroll
    for (int ks = 0; ks < KSTEPS; ++ks) {
        const int k0  = ks * 32 + quad * 8;
        const int tap = k0 / CI;
        const int ci  = k0 - tap * CI;
        const int dkk = (tap / K) * W + (tap - (tap / K) * K);

        bf16x8 a[2][2];
#pragma unroll
        for (int mt = 0; mt < 2; ++mt) {
            const int aoff = aBase + mt * 16 * CI + dkk * CI + ci;
            a[mt][0] = *(const bf16x8*)(Xhi + aoff);
            a[mt][1] = *(const bf16x8*)(Xlo + aoff);
        }
#pragma unroll
        for (int nt = 0; nt < NT; ++nt) {
            const int boff = tap * NPAD * CI + nt * 16 * CI + bLane + ci;
            const bf16x8 bh = *(const bf16x8*)(Bhi + boff);
            const bf16x8 bl = *(const bf16x8*)(Blo + boff);
#pragma unroll
            for (int mt = 0; mt < 2; ++mt) {
                acc[mt][nt] = __builtin_amdgcn_mfma_f32_16x16x32_bf16(a[mt][0], bh, acc[mt][nt], 0, 0, 0);
                acc[mt][nt] = __builtin_amdgcn_mfma_f32_16x16x32_bf16(a[mt][1], bh, acc[mt][nt], 0, 0, 0);
                acc[mt][nt] = __builtin_amdgcn_mfma_f32_16x16x32_bf16(a[mt][0], bl, acc[mt][nt], 0, 0, 0);
            }
        }
    }

#pragma unroll
    for (int mt = 0; mt < 2; ++mt) {
#pragma unroll
        for (int nt = 0; nt < NT; ++nt) {
            const int n = nt * 16 + col;
            if (n < OC) {
                const float bv = bias[n];
#pragma unroll
                for (int r = 0; r < 4; ++r) {
                    const int m = mBase + mt * 16 + quad * 4 + r;
                    if (m < Mtotal) {
                        const int b   = m / HW;
                        const int pos = m - b * HW;
                        const int y   = pos / W;
                        const int x   = pos - y * W;
                        if (y < Ho && x < Wo)
                            out[((size_t)b * OC + n) * HoWo + y * Wo + x] = acc[mt][nt][r] + bv;
                    }
                }
            }
        }
    }
}

// ---------------------------------------------------------------------------
// MFMA deformable conv (stages 2-5). LDS holds 8 channels of the image
// (pixel-major, STRIDE=12 floats). k-order = (pass, tap, ci): a 32-k step is
// 4 taps x 8 LDS-resident channels. Lane (col,quad) bilinearly samples 8
// channels of tap (tg*4+quad) for pixel (pixel0+col), hi/lo-splits them into
// the A-fragment; 3 MFMAs per n-tile do the channel contraction.
// ---------------------------------------------------------------------------
template<int K, int CI, int CO, int H, int W, int Ho, int Wo, bool RELU,
         int MT, int TPAD>
__global__ __launch_bounds__(MT * 64)
void deform_mfma(const float* __restrict__ x, const float* __restrict__ off,
                 const ushort_t* __restrict__ Bph, const ushort_t* __restrict__ Bpl,
                 const float* __restrict__ bias, float* __restrict__ out)
{
    constexpr int KK     = K * K;
    constexpr int HW     = H * W;
    constexpr int HoWo   = Ho * Wo;
    constexpr int NPASS  = CI / 8;
    constexpr int NT     = (CO + 15) / 16;
    constexpr int NPAD   = NT * 16;
    constexpr int STRIDE = 12;
    constexpr int nMB    = (HoWo + MT * 16 - 1) / (MT * 16);
    constexpr int THREADS = MT * 64;
    __shared__ __align__(16) float tile[HW * STRIDE];

    const int b    = blockIdx.x / nMB;
    const int mb   = blockIdx.x - b * nMB;
    const int tid  = threadIdx.x;
    const int wid  = tid >> 6;
    const int lane = tid & 63;
    const int col  = lane & 15;
    const int quad = lane >> 4;

    const int pixel0 = (mb * MT + wid) * 16;
    const int s      = pixel0 + col;
    const bool am    = (s < HoWo);
    const int oy = s / Wo, ox = s - oy * Wo;

    const float* offB = off + (size_t)b * 2 * KK * HoWo;

    f32x4 acc[NT];
#pragma unroll
    for (int nt = 0; nt < NT; ++nt) acc[nt] = (f32x4){0.f, 0.f, 0.f, 0.f};

    for (int pass = 0; pass < NPASS; ++pass) {
        const int cbase = pass * 8;
        __syncthreads();
        for (int pos = tid; pos < HW; pos += THREADS) {
#pragma unroll
            for (int c = 0; c < 8; ++c)
                tile[pos * STRIDE + c] = x[((size_t)b * CI + (cbase + c)) * HW + pos];
        }
        __syncthreads();

#pragma unroll
        for (int tg = 0; tg < TPAD / 4; ++tg) {
            const int tap = tg * 4 + quad;
            bf16x8 ahi = (bf16x8){0,0,0,0,0,0,0,0};
            bf16x8 alo = (bf16x8){0,0,0,0,0,0,0,0};

            if (am && tap < KK) {
                const float dy = offB[(size_t)(2 * tap + 0) * HoWo + s];
                const float dx = offB[(size_t)(2 * tap + 1) * HoWo + s];
                const float py = (float)(tap / K + oy) + dy;
                const float px = (float)(tap % K + ox) + dx;
                const float y0f = floorf(py), x0f = floorf(px);
                const float wy = py - y0f, wx = px - x0f;
                const int y0 = (int)y0f, x0 = (int)x0f;
                const int y1 = y0 + 1,   x1 = x0 + 1;

                const float m00 = (y0 >= 0 && y0 < H && x0 >= 0 && x0 < W) ? 1.f : 0.f;
                const float m01 = (y0 >= 0 && y0 < H && x1 >= 0 && x1 < W) ? 1.f : 0.f;
                const float m10 = (y1 >= 0 && y1 < H && x0 >= 0 && x0 < W) ? 1.f : 0.f;
                const float m11 = (y1 >= 0 && y1 < H && x1 >= 0 && x1 < W) ? 1.f : 0.f;

                const float w00 = (1.f - wy) * (1.f - wx) * m00;
                const float w01 = (1.f - wy) * wx         * m01;
                const float w10 = wy         * (1.f - wx) * m10;
                const float w11 = wy         * wx         * m11;

                const int y0c = min(max(y0, 0), H - 1), y1c = min(max(y1, 0), H - 1);
                const int x0c = min(max(x0, 0), W - 1), x1c = min(max(x1, 0), W - 1);
                const int i00 = (y0c * W + x0c) * STRIDE;
                const int i01 = (y0c * W + x1c) * STRIDE;
                const int i10 = (y1c * W + x0c) * STRIDE;
                const int i11 = (y1c * W + x1c) * STRIDE;

                float v00[8], v01[8], v10[8], v11[8];
                *(f32x4*)(v00) = *(const f32x4*)(tile + i00); *(f32x4*)(v00 + 4) = *(const f32x4*)(tile + i00 + 4);
                *(f32x4*)(v01) = *(const f32x4*)(tile + i01); *(f32x4*)(v01 + 4) = *(const f32x4*)(tile + i01 + 4);
                *(f32x4*)(v10) = *(const f32x4*)(tile + i10); *(f32x4*)(v10 + 4) = *(const f32x4*)(tile + i10 + 4);
                *(f32x4*)(v11) = *(const f32x4*)(tile + i11); *(f32x4*)(v11 + 4) = *(const f32x4*)(tile + i11 + 4);
#pragma unroll
                for (int j = 0; j < 8; ++j) {
                    const float sv = fmaf(v11[j], w11, fmaf(v10[j], w10,
                                     fmaf(v01[j], w01, v00[j] * w00)));
                    const ushort_t h = bf16_trunc(sv);
                    ahi[j] = (short)h;
                    alo[j] = (short)bf16_trunc(sv - bf16_to_f(h));
                }
            }

            const size_t kslot = (size_t)(pass * TPAD + tap);
#pragma unroll
            for (int nt = 0; nt < NT; ++nt) {
                const bf16x8 bh = *(const bf16x8*)(Bph + (kslot * NPAD + nt * 16 + col) * 8);
                const bf16x8 bl = *(const bf16x8*)(Bpl + (kslot * NPAD + nt * 16 + col) * 8);
                acc[nt] = __builtin_amdgcn_mfma_f32_16x16x32_bf16(ahi, bh, acc[nt], 0, 0, 0);
                acc[nt] = __builtin_amdgcn_mfma_f32_16x16x32_bf16(alo, bh, acc[nt], 0, 0, 0);
                acc[nt] = __builtin_amdgcn_mfma_f32_16x16x32_bf16(ahi, bl, acc[nt], 0, 0, 0);
            }
        }
    }

#pragma unroll
    for (int nt = 0; nt < NT; ++nt) {
        const int n = nt * 16 + col;
        if (n < CO) {
            const float bv = bias[n];
#pragma unroll
            for (int r = 0; r < 4; ++r) {
                const int m = pixel0 + quad * 4 + r;
                if (m < HoWo) {
                    float v = acc[nt][r] + bv;
                    if (RELU) v = fmaxf(v, 0.f);
                    out[((size_t)b * CO + n) * HoWo + m] = v;
                }
            }
        }
    }
}

// ---------------------------------------------------------------------------
// Scalar LDS deform (stages 1 and 6).
// ---------------------------------------------------------------------------
template<int K, int CI, int CO, int H, int W, int Ho, int Wo, bool RELU,
         int CSPLIT, int STRIDE, int THREADS, int SPLIT>
__global__ __launch_bounds__(THREADS)
void deform_lds(const float* __restrict__ x, const float* __restrict__ off,
                const float* __restrict__ w, const float* __restrict__ bias,
                float* __restrict__ out)
{
    constexpr int KK    = K * K;
    constexpr int HW    = H * W;
    constexpr int HoWo  = Ho * Wo;
    constexpr int NPASS = CI / CSPLIT;
    constexpr int CHUNK = (HoWo + SPLIT - 1) / SPLIT;
    static_assert(CHUNK <= THREADS, "chunk must fit in one block");
    __shared__ __align__(16) float tile[HW * STRIDE];

    const int b   = blockIdx.x / SPLIT;
    const int sp  = blockIdx.x - b * SPLIT;
    const int tid = threadIdx.x;
    const int s   = sp * CHUNK + tid;
    const bool active = (tid < CHUNK) && (s < HoWo);

    const int oy = s / Wo, ox = s - oy * Wo;
    const float* offp = off + ((size_t)b * 2 * KK) * HoWo + s;

    float acc[CO];
#pragma unroll
    for (int o = 0; o < CO; ++o) acc[o] = 0.f;

    for (int pass = 0; pass < NPASS; ++pass) {
        const int cbase = pass * CSPLIT;
        __syncthreads();
        for (int pos = tid; pos < HW; pos += THREADS) {
#pragma unroll
            for (int c = 0; c < CSPLIT; ++c)
                tile[pos * STRIDE + c] = x[((size_t)b * CI + (cbase + c)) * HW + pos];
        }
        __syncthreads();

        if (active) {
            for (int kk = 0; kk < KK; ++kk) {
                const float dy = offp[(size_t)(2 * kk + 0) * HoWo];
                const float dx = offp[(size_t)(2 * kk + 1) * HoWo];
                const float py = (float)(kk / K + oy) + dy;
                const float px = (float)(kk % K + ox) + dx;
                const float y0f = floorf(py), x0f = floorf(px);
                const float wy = py - y0f, wx = px - x0f;
                const int y0 = (int)y0f, x0 = (int)x0f;
                const int y1 = y0 + 1,   x1 = x0 + 1;

                const float m00 = (y0 >= 0 && y0 < H && x0 >= 0 && x0 < W) ? 1.f : 0.f;
                const float m01 = (y0 >= 0 && y0 < H && x1 >= 0 && x1 < W) ? 1.f : 0.f;
                const float m10 = (y1 >= 0 && y1 < H && x0 >= 0 && x0 < W) ? 1.f : 0.f;
                const float m11 = (y1 >= 0 && y1 < H && x1 >= 0 && x1 < W) ? 1.f : 0.f;

                const float w00 = (1.f - wy) * (1.f - wx) * m00;
                const float w01 = (1.f - wy) * wx         * m01;
                const float w10 = wy         * (1.f - wx) * m10;
                const float w11 = wy         * wx         * m11;

                const int y0c = min(max(y0, 0), H - 1), y1c = min(max(y1, 0), H - 1);
                const int x0c = min(max(x0, 0), W - 1), x1c = min(max(x1, 0), W - 1);
                const int i00 = (y0c * W + x0c) * STRIDE;
                const int i01 = (y0c * W + x1c) * STRIDE;
                const int i10 = (y1c * W + x0c) * STRIDE;
                const int i11 = (y1c * W + x1c) * STRIDE;

                if constexpr (CSPLIT % 4 == 0) {
#pragma unroll
                    for (int cg = 0; cg < CSPLIT; cg += 4) {
                        const f32x4 v00 = *(const f32x4*)(tile + i00 + cg);
                        const f32x4 v01 = *(const f32x4*)(tile + i01 + cg);
                        const f32x4 v10 = *(const f32x4*)(tile + i10 + cg);
                        const f32x4 v11 = *(const f32x4*)(tile + i11 + cg);
#pragma unroll
                        for (int j = 0; j < 4; ++j) {
                            const float sv = fmaf(v11[j], w11, fmaf(v10[j], w10,
                                             fmaf(v01[j], w01, v00[j] * w00)));
#pragma unroll
                            for (int o = 0; o < CO; ++o)
                                acc[o] = fmaf(sv, w[(size_t)(o * CI + cbase + cg + j) * KK + kk], acc[o]);
                        }
                    }
                } else {
                    const float sv = fmaf(tile[i11], w11, fmaf(tile[i10], w10,
                                     fmaf(tile[i01], w01, tile[i00] * w00)));
#pragma unroll
                    for (int o = 0; o < CO; ++o)
                        acc[o] = fmaf(sv, w[(size_t)(o * CI + cbase) * KK + kk], acc[o]);
                }
            }
        }
    }

    if (active) {
        float* op = out + ((size_t)b * CO) * HoWo + s;
#pragma unroll
        for (int o = 0; o < CO; ++o) {
            float v = acc[o] + bias[o];
            if (RELU) v = fmaxf(v, 0.f);
            op[(size_t)o * HoWo] = v;
        }
    }
}

// ---------------------------------------------------------------------------
// Register-tiled direct VALID conv (stages 1 and 6 offset convs).
// ---------------------------------------------------------------------------
template<int K, int CI, int NOC, int OC, int H, int W, int Ho, int Wo, int PIX>
__global__ __launch_bounds__(256)
void conv_tile(const float* __restrict__ x, const float* __restrict__ w,
               const float* __restrict__ bias, float* __restrict__ out)
{
    constexpr int KK   = K * K;
    constexpr int HoWo = Ho * Wo;
    constexpr int WoG  = (Wo + PIX - 1) / PIX;
    constexpr int G    = Ho * WoG;
    constexpr int XV   = PIX + K - 1;

    const int oc0   = blockIdx.y * NOC;
    const int g_all = blockIdx.x * 256 + threadIdx.x;
    const int b     = g_all / G;
    const int g     = g_all - b * G;
    const int oy    = g / WoG;
    const int ox0   = (g - oy * WoG) * PIX;

    const float* xbp = x + (b * CI) * (H * W) + oy * W + ox0;
    const float* wp  = w + oc0 * (CI * KK);

    float acc[PIX][NOC];
#pragma unroll
    for (int p = 0; p < PIX; ++p)
#pragma unroll
        for (int j = 0; j < NOC; ++j) acc[p][j] = bias[oc0 + j];

    const int lim = W - 1 - ox0;

    for (int ci = 0; ci < CI; ++ci) {
        const float* xc = xbp + ci * (H * W);
#pragma unroll
        for (int ky = 0; ky < K; ++ky) {
            float xv[XV];
#pragma unroll
            for (int i = 0; i < XV; ++i) {
                const int off = (i <= lim) ? i : lim;
                xv[i] = xc[ky * W + off];
            }
#pragma unroll
            for (int kx = 0; kx < K; ++kx) {
#pragma unroll
                for (int p = 0; p < PIX; ++p) {
                    const float v = xv[p + kx];
#pragma unroll
                    for (int j = 0; j < NOC; ++j)
                        acc[p][j] = fmaf(v, wp[j * (CI * KK) + ci * KK + ky * K + kx], acc[p][j]);
                }
            }
        }
    }

    float* op = out + (b * OC + oc0) * HoWo + oy * Wo + ox0;
#pragma unroll
    for (int p = 0; p < PIX; ++p) {
        if (ox0 + p < Wo) {
#pragma unroll
            for (int j = 0; j < NOC; ++j) op[j * HoWo + p] = acc[p][j];
        }
    }
}

__global__ void fc_kernel(const float* __restrict__ h, const float* __restrict__ w,
                          const float* __restrict__ bias, float* __restrict__ out,
                          int B, int IN, int OUT, int relu)
{
    const int idx = blockIdx.x * blockDim.x + threadIdx.x;
    if (idx >= B * OUT) return;
    const int b = idx / OUT;
    const int j = idx - b * OUT;
    const float* hb = h + b * IN;
    const float* wj = w + j * IN;
    float acc = bias[j];
    for (int i = 0; i < IN; ++i) acc = fmaf(hb[i], wj[i], acc);
    if (relu) acc = fmaxf(acc, 0.f);
    out[idx] = acc;
}

// ---------------------------------------------------------------------------
extern "C" void kernel_launch(void* const* d_in, const int* in_sizes, int n_in,
                              void* d_out, int out_size, void* d_ws, size_t ws_size,
                              hipStream_t stream)
{
    const int B = 512;
    const float* x = (const float*)d_in[0];
    const float *ow[6], *ob[6], *w[6], *bi[6];
    for (int i = 0; i < 6; ++i) {
        ow[i] = (const float*)d_in[1 + 4 * i];
        ob[i] = (const float*)d_in[2 + 4 * i];
        w[i]  = (const float*)d_in[3 + 4 * i];
        bi[i] = (const float*)d_in[4 + 4 * i];
    }
    const float* fc1w = (const float*)d_in[25];
    const float* fc1b = (const float*)d_in[26];
    const float* fc2w = (const float*)d_in[27];
    const float* fc2b = (const float*)d_in[28];
    float* out = (float*)d_out;

    float* P   = (float*)d_ws;        // 14M floats
    float* Q   = P  + 14000000;       // 14M floats
    float* OFF = Q  + 14000000;       // 18.2M floats
    float* Z   = OFF + 18200000;      // fc intermediate
    ushort_t* WBhi = (ushort_t*)(Z + 200000);   // conv_mfma weights
    ushort_t* WBlo = WBhi + 200000;
    ushort_t* WDhi = WBlo + 200000;             // deform_mfma weights
    ushort_t* WDlo = WDhi + 200000;

    const dim3 blk(256);
    #define GRIDT(Ho, Wo, PIX, NG) dim3((B * (Ho) * (((Wo) + (PIX) - 1) / (PIX)) + 255) / 256, (NG), 1)
    #define CEILDIV(a, b) (((a) + (b) - 1) / (b))

    // ---- stage 1: input x (CI=1). conv_tile -> OFF; deform_lds -> P ----
    conv_tile<3, 1, 6, 18, 33, 33, 31, 31, 4><<<GRIDT(31, 31, 4, 3), blk, 0, stream>>>(x, ow[0], ob[0], OFF);
    deform_lds<3, 1, 16, 33, 33, 31, 31, true, 1, 1, 512, 2><<<dim3(B * 2), dim3(512), 0, stream>>>(x, OFF, w[0], bi[0], P);

    // ---- stage 2: CI=16 K=3 31x31->29x29 OC(off)=18 CO=32. P -> Q ----
    {
        const int M = B * 961;
        ushort_t* Xhi = (ushort_t*)Q;
        ushort_t* Xlo = Xhi + (size_t)(M + 2048) * 16;
        convert_nhwc<16, 961><<<CEILDIV(M, 256), blk, 0, stream>>>(P, Xhi, Xlo, M);
        wprep<16, 9, 10, 32, 18><<<CEILDIV(10 * 32 * 16, 256), blk, 0, stream>>>(ow[1], WBhi, WBlo);
        conv_mfma<16, 3, 31, 31, 29, 29, 18, 2, 5><<<CEILDIV(M, 128), blk, 0, stream>>>(Xhi, Xlo, WBhi, WBlo, ob[1], OFF, M);
        // deform: MT=8, TPAD=12, NPASS=2, NT=2. nMB = ceil(841/128)=7
        wprep_d<16, 9, 12, 32, 32><<<CEILDIV(2 * 12 * 32 * 8, 256), blk, 0, stream>>>(w[1], WDhi, WDlo);
        deform_mfma<3, 16, 32, 31, 31, 29, 29, true, 8, 12><<<dim3(B * 7), dim3(512), 0, stream>>>(P, OFF, WDhi, WDlo, bi[1], Q);
    }
    // ---- stage 3: CI=32 K=5 29x29->25x25 OC(off)=50 CO=16 (no relu). Q -> P ----
    {
        const int M = B * 841;
        ushort_t* Xhi = (ushort_t*)P;
        ushort_t* Xlo = Xhi + (size_t)(M + 2048) * 32;
        convert_nhwc<32, 841><<<CEILDIV(M, 256), blk, 0, stream>>>(Q, Xhi, Xlo, M);
        wprep<32, 25, 25, 64, 50><<<CEILDIV(25 * 64 * 32, 256), blk, 0, stream>>>(ow[2], WBhi, WBlo);
        conv_mfma<32, 5, 29, 29, 25, 25, 50, 4, 25><<<CEILDIV(M, 128), blk, 0, stream>>>(Xhi, Xlo, WBhi, WBlo, ob[2], OFF, M);
        // deform: MT=8, TPAD=28, NPASS=4, NT=1. nMB = ceil(625/128)=5
        wprep_d<32, 25, 28, 16, 16><<<CEILDIV(4 * 28 * 16 * 8, 256), blk, 0, stream>>>(w[2], WDhi, WDlo);
        deform_mfma<5, 32, 16, 29, 29, 25, 25, false, 8, 28><<<dim3(B * 5), dim3(512), 0, stream>>>(Q, OFF, WDhi, WDlo, bi[2], P);
    }
    // ---- stage 4: CI=16 K=7 25x25->19x19 OC(off)=98 CO=16. P -> Q ----
    {
        const int M = B * 625;
        ushort_t* Xhi = (ushort_t*)Q;
        ushort_t* Xlo = Xhi + (size_t)(M + 2048) * 16;
        convert_nhwc<16, 625><<<CEILDIV(M, 256), blk, 0, stream>>>(P, Xhi, Xlo, M);
        wprep<16, 49, 50, 112, 98><<<CEILDIV(50 * 112 * 16, 256), blk, 0, stream>>>(ow[3], WBhi, WBlo);
        conv_mfma<16, 7, 25, 25, 19, 19, 98, 7, 25><<<CEILDIV(M, 128), blk, 0, stream>>>(Xhi, Xlo, WBhi, WBlo, ob[3], OFF, M);
        // deform: MT=8, TPAD=52, NPASS=2, NT=1. nMB = ceil(361/128)=3
        wprep_d<16, 49, 52, 16, 16><<<CEILDIV(2 * 52 * 16 * 8, 256), blk, 0, stream>>>(w[3], WDhi, WDlo);
        deform_mfma<7, 16, 16, 25, 25, 19, 19, true, 8, 52><<<dim3(B * 3), dim3(512), 0, stream>>>(P, OFF, WDhi, WDlo, bi[3], Q);
    }
    // ---- stage 5: CI=16 K=5 19x19->15x15 OC(off)=50 CO=8. Q -> P ----
    {
        const int M = B * 361;
        ushort_t* Xhi = (ushort_t*)P;
        ushort_t* Xlo = Xhi + (size_t)(M + 2048) * 16;
        convert_nhwc<16, 361><<<CEILDIV(M, 256), blk, 0, stream>>>(Q, Xhi, Xlo, M);
        wprep<16, 25, 26, 64, 50><<<CEILDIV(26 * 64 * 16, 256), blk, 0, stream>>>(ow[4], WBhi, WBlo);
        conv_mfma<16, 5, 19, 19, 15, 15, 50, 4, 13><<<CEILDIV(M, 128), blk, 0, stream>>>(Xhi, Xlo, WBhi, WBlo, ob[4], OFF, M);
        // deform: MT=4, TPAD=28, NPASS=2, NT=1. nMB = ceil(225/64)=4
        wprep_d<16, 25, 28, 16, 8><<<CEILDIV(2 * 28 * 16 * 8, 256), blk, 0, stream>>>(w[4], WDhi, WDlo);
        deform_mfma<5, 16, 8, 19, 19, 15, 15, true, 4, 28><<<dim3(B * 4), dim3(256), 0, stream>>>(Q, OFF, WDhi, WDlo, bi[4], P);
    }
    // ---- stage 6: CI=8 K=3 15x15->13x13 CO=4. P -> Q ----
    conv_tile<3, 8, 6, 18, 15, 15, 13, 13, 4><<<GRIDT(13, 13, 4, 3), blk, 0, stream>>>(P, ow[5], ob[5], OFF);
    deform_lds<3, 8, 4, 15, 15, 13, 13, true, 8, 12, 192, 1><<<dim3(B), dim3(192), 0, stream>>>(P, OFF, w[5], bi[5], Q);

    // ---- FC head (reads Q = 512 x 4 x 13 x 13) ----
    fc_kernel<<<dim3(CEILDIV(B * 256, 256)), blk, 0, stream>>>(Q, fc1w, fc1b, Z, B, 676, 256, 1);
    fc_kernel<<<dim3(CEILDIV(B * 10, 256)), blk, 0, stream>>>(Z, fc2w, fc2b, out, B, 256, 10, 0);

    #undef GRIDT
    #undef CEILDIV
}

// Round 9
// 1386.397 us; speedup vs baseline: 2.7544x; 1.0525x over previous
//
#include <hip/hip_runtime.h>

typedef __attribute__((ext_vector_type(8))) short bf16x8;
typedef __attribute__((ext_vector_type(4))) float f32x4;
typedef unsigned short ushort_t;

__device__ inline ushort_t bf16_trunc(float f) { return (ushort_t)(__float_as_uint(f) >> 16); }
__device__ inline float bf16_to_f(ushort_t u) { return __uint_as_float(((unsigned int)u) << 16); }

// ---------------------------------------------------------------------------
// NCHW fp32 -> NHWC bf16 hi/lo planes (A-operand for conv_mfma).
// ---------------------------------------------------------------------------
template<int CI, int HW>
__global__ __launch_bounds__(256)
void convert_nhwc(const float* __restrict__ x, ushort_t* __restrict__ hi,
                  ushort_t* __restrict__ lo, int Mtotal)
{
    const int m = blockIdx.x * 256 + threadIdx.x;
    if (m >= Mtotal) return;
    const int b = m / HW, pos = m - b * HW;
    const float* xp = x + (size_t)b * CI * HW + pos;
    ushort_t* hp = hi + (size_t)m * CI;
    ushort_t* lp = lo + (size_t)m * CI;
#pragma unroll
    for (int ci = 0; ci < CI; ++ci) {
        const float v = xp[(size_t)ci * HW];
        const ushort_t h = bf16_trunc(v);
        hp[ci] = h;
        lp[ci] = bf16_trunc(v - bf16_to_f(h));
    }
}

// ---------------------------------------------------------------------------
// Weight prep for conv_mfma: OIHW fp32 -> [kk][n][ci] hi/lo, zero-padded.
// ---------------------------------------------------------------------------
template<int CI, int KK, int KKPAD, int NPAD, int OC>
__global__ __launch_bounds__(256)
void wprep(const float* __restrict__ w, ushort_t* __restrict__ bhi, ushort_t* __restrict__ blo)
{
    const int idx = blockIdx.x * 256 + threadIdx.x;
    if (idx >= KKPAD * NPAD * CI) return;
    const int kk  = idx / (NPAD * CI);
    const int rem = idx - kk * (NPAD * CI);
    const int n   = rem / CI;
    const int ci  = rem - n * CI;
    const float v = (kk < KK && n < OC) ? w[((size_t)n * CI + ci) * KK + kk] : 0.f;
    const ushort_t h = bf16_trunc(v);
    bhi[idx] = h;
    blo[idx] = bf16_trunc(v - bf16_to_f(h));
}

// ---------------------------------------------------------------------------
// Weight prep for deform_mfma: pack [kslot = pass*TPAD+tap][n][j=ci_in_pass].
// ---------------------------------------------------------------------------
template<int CI, int KK, int TPAD, int NPAD, int OC>
__global__ __launch_bounds__(256)
void wprep_d(const float* __restrict__ w, ushort_t* __restrict__ bhi, ushort_t* __restrict__ blo)
{
    constexpr int NPASS = (CI + 7) / 8;
    constexpr int TOTAL = NPASS * TPAD * NPAD * 8;
    const int idx = blockIdx.x * 256 + threadIdx.x;
    if (idx >= TOTAL) return;
    const int j     = idx & 7;
    const int n     = (idx >> 3) % NPAD;
    const int kslot = (idx >> 3) / NPAD;
    const int pass  = kslot / TPAD;
    const int tap   = kslot - pass * TPAD;
    const int ci    = pass * 8 + j;
    const float v = (tap < KK && n < OC && ci < CI) ? w[((size_t)n * CI + ci) * KK + tap] : 0.f;
    const ushort_t h = bf16_trunc(v);
    bhi[idx] = h;
    blo[idx] = bf16_trunc(v - bf16_to_f(h));
}

// ---------------------------------------------------------------------------
// MFMA implicit-im2col conv (offset convs). fp32 via bf16 hi/lo split.
// R7-proven structure; each wave now computes 4 m-tiles (block = 256 m) and
// grid.y splits OC into n-groups of NT0 tiles. A-reads stay global (L1/L2).
// ---------------------------------------------------------------------------
template<int CI, int K, int H, int W, int Ho, int Wo, int OC, int NTTOT, int NT0, int KSTEPS>
__global__ __launch_bounds__(256)
void conv_mfma(const ushort_t* __restrict__ Xhi, const ushort_t* __restrict__ Xlo,
               const ushort_t* __restrict__ Bhi, const ushort_t* __restrict__ Blo,
               const float* __restrict__ bias, float* __restrict__ out, int Mtotal)
{
    constexpr int NPAD = NTTOT * 16;
    constexpr int HW   = H * W;
    constexpr int HoWo = Ho * Wo;

    const int lane = threadIdx.x & 63;
    const int wid  = threadIdx.x >> 6;
    const int col  = lane & 15;
    const int quad = lane >> 4;

    const int mBase  = blockIdx.x * 256 + wid * 64;   // 4 m-tiles per wave
    const int mLane  = mBase + col;
    const int ntBase = blockIdx.y * NT0;

    f32x4 acc[4][NT0];
#pragma unroll
    for (int mt = 0; mt < 4; ++mt)
#pragma unroll
        for (int nt = 0; nt < NT0; ++nt) acc[mt][nt] = (f32x4){0.f, 0.f, 0.f, 0.f};

    const int aBase = mLane * CI;
    const int bLane = col * CI;

#pragma unroll
    for (int ks = 0; ks < KSTEPS; ++ks) {
        const int k0  = ks * 32 + quad * 8;
        const int tap = k0 / CI;
        const int ci  = k0 - tap * CI;
        const int dkk = (tap / K) * W + (tap - (tap / K) * K);

        bf16x8 ah[4], al[4];
#pragma unroll
        for (int mt = 0; mt < 4; ++mt) {
            const int aoff = aBase + (mt * 16 + dkk) * CI + ci;
            ah[mt] = *(const bf16x8*)(Xhi + aoff);
            al[mt] = *(const bf16x8*)(Xlo + aoff);
        }
#pragma unroll
        for (int nt = 0; nt < NT0; ++nt) {
            const int ntg = ntBase + nt;
            if (ntg < NTTOT) {
                const int boff = tap * NPAD * CI + ntg * 16 * CI + bLane + ci;
                const bf16x8 bh = *(const bf16x8*)(Bhi + boff);
                const bf16x8 bl = *(const bf16x8*)(Blo + boff);
#pragma unroll
                for (int mt = 0; mt < 4; ++mt) {
                    acc[mt][nt] = __builtin_amdgcn_mfma_f32_16x16x32_bf16(ah[mt], bh, acc[mt][nt], 0, 0, 0);
                    acc[mt][nt] = __builtin_amdgcn_mfma_f32_16x16x32_bf16(al[mt], bh, acc[mt][nt], 0, 0, 0);
                    acc[mt][nt] = __builtin_amdgcn_mfma_f32_16x16x32_bf16(ah[mt], bl, acc[mt][nt], 0, 0, 0);
                }
            }
        }
    }

#pragma unroll
    for (int mt = 0; mt < 4; ++mt) {
#pragma unroll
        for (int nt = 0; nt < NT0; ++nt) {
            const int ntg = ntBase + nt;
            const int n   = ntg * 16 + col;
            if (ntg < NTTOT && n < OC) {
                const float bv = bias[n];
#pragma unroll
                for (int r = 0; r < 4; ++r) {
                    const int m = mBase + mt * 16 + quad * 4 + r;
                    if (m < Mtotal) {
                        const int b   = m / HW;
                        const int pos = m - b * HW;
                        const int y   = pos / W;
                        const int x   = pos - y * W;
                        if (y < Ho && x < Wo)
                            out[((size_t)b * OC + n) * HoWo + y * Wo + x] = acc[mt][nt][r] + bv;
                    }
                }
            }
        }
    }
}

// ---------------------------------------------------------------------------
// MFMA deformable conv (stages 2-5). Unchanged from R7.
// ---------------------------------------------------------------------------
template<int K, int CI, int CO, int H, int W, int Ho, int Wo, bool RELU,
         int MT, int TPAD>
__global__ __launch_bounds__(MT * 64)
void deform_mfma(const float* __restrict__ x, const float* __restrict__ off,
                 const ushort_t* __restrict__ Bph, const ushort_t* __restrict__ Bpl,
                 const float* __restrict__ bias, float* __restrict__ out)
{
    constexpr int KK     = K * K;
    constexpr int HW     = H * W;
    constexpr int HoWo   = Ho * Wo;
    constexpr int NPASS  = CI / 8;
    constexpr int NT     = (CO + 15) / 16;
    constexpr int NPAD   = NT * 16;
    constexpr int STRIDE = 12;
    constexpr int nMB    = (HoWo + MT * 16 - 1) / (MT * 16);
    constexpr int THREADS = MT * 64;
    __shared__ __align__(16) float tile[HW * STRIDE];

    const int b    = blockIdx.x / nMB;
    const int mb   = blockIdx.x - b * nMB;
    const int tid  = threadIdx.x;
    const int wid  = tid >> 6;
    const int lane = tid & 63;
    const int col  = lane & 15;
    const int quad = lane >> 4;

    const int pixel0 = (mb * MT + wid) * 16;
    const int s      = pixel0 + col;
    const bool am    = (s < HoWo);
    const int oy = s / Wo, ox = s - oy * Wo;

    const float* offB = off + (size_t)b * 2 * KK * HoWo;

    f32x4 acc[NT];
#pragma unroll
    for (int nt = 0; nt < NT; ++nt) acc[nt] = (f32x4){0.f, 0.f, 0.f, 0.f};

    for (int pass = 0; pass < NPASS; ++pass) {
        const int cbase = pass * 8;
        __syncthreads();
        for (int pos = tid; pos < HW; pos += THREADS) {
#pragma unroll
            for (int c = 0; c < 8; ++c)
                tile[pos * STRIDE + c] = x[((size_t)b * CI + (cbase + c)) * HW + pos];
        }
        __syncthreads();

#pragma unroll
        for (int tg = 0; tg < TPAD / 4; ++tg) {
            const int tap = tg * 4 + quad;
            bf16x8 ahi = (bf16x8){0,0,0,0,0,0,0,0};
            bf16x8 alo = (bf16x8){0,0,0,0,0,0,0,0};

            if (am && tap < KK) {
                const float dy = offB[(size_t)(2 * tap + 0) * HoWo + s];
                const float dx = offB[(size_t)(2 * tap + 1) * HoWo + s];
                const float py = (float)(tap / K + oy) + dy;
                const float px = (float)(tap % K + ox) + dx;
                const float y0f = floorf(py), x0f = floorf(px);
                const float wy = py - y0f, wx = px - x0f;
                const int y0 = (int)y0f, x0 = (int)x0f;
                const int y1 = y0 + 1,   x1 = x0 + 1;

                const float m00 = (y0 >= 0 && y0 < H && x0 >= 0 && x0 < W) ? 1.f : 0.f;
                const float m01 = (y0 >= 0 && y0 < H && x1 >= 0 && x1 < W) ? 1.f : 0.f;
                const float m10 = (y1 >= 0 && y1 < H && x0 >= 0 && x0 < W) ? 1.f : 0.f;
                const float m11 = (y1 >= 0 && y1 < H && x1 >= 0 && x1 < W) ? 1.f : 0.f;

                const float w00 = (1.f - wy) * (1.f - wx) * m00;
                const float w01 = (1.f - wy) * wx         * m01;
                const float w10 = wy         * (1.f - wx) * m10;
                const float w11 = wy         * wx         * m11;

                const int y0c = min(max(y0, 0), H - 1), y1c = min(max(y1, 0), H - 1);
                const int x0c = min(max(x0, 0), W - 1), x1c = min(max(x1, 0), W - 1);
                const int i00 = (y0c * W + x0c) * STRIDE;
                const int i01 = (y0c * W + x1c) * STRIDE;
                const int i10 = (y1c * W + x0c) * STRIDE;
                const int i11 = (y1c * W + x1c) * STRIDE;

                float v00[8], v01[8], v10[8], v11[8];
                *(f32x4*)(v00) = *(const f32x4*)(tile + i00); *(f32x4*)(v00 + 4) = *(const f32x4*)(tile + i00 + 4);
                *(f32x4*)(v01) = *(const f32x4*)(tile + i01); *(f32x4*)(v01 + 4) = *(const f32x4*)(tile + i01 + 4);
                *(f32x4*)(v10) = *(const f32x4*)(tile + i10); *(f32x4*)(v10 + 4) = *(const f32x4*)(tile + i10 + 4);
                *(f32x4*)(v11) = *(const f32x4*)(tile + i11); *(f32x4*)(v11 + 4) = *(const f32x4*)(tile + i11 + 4);
#pragma unroll
                for (int j = 0; j < 8; ++j) {
                    const float sv = fmaf(v11[j], w11, fmaf(v10[j], w10,
                                     fmaf(v01[j], w01, v00[j] * w00)));
                    const ushort_t h = bf16_trunc(sv);
                    ahi[j] = (short)h;
                    alo[j] = (short)bf16_trunc(sv - bf16_to_f(h));
                }
            }

            const size_t kslot = (size_t)(pass * TPAD + tap);
#pragma unroll
            for (int nt = 0; nt < NT; ++nt) {
                const bf16x8 bh = *(const bf16x8*)(Bph + (kslot * NPAD + nt * 16 + col) * 8);
                const bf16x8 bl = *(const bf16x8*)(Bpl + (kslot * NPAD + nt * 16 + col) * 8);
                acc[nt] = __builtin_amdgcn_mfma_f32_16x16x32_bf16(ahi, bh, acc[nt], 0, 0, 0);
                acc[nt] = __builtin_amdgcn_mfma_f32_16x16x32_bf16(alo, bh, acc[nt], 0, 0, 0);
                acc[nt] = __builtin_amdgcn_mfma_f32_16x16x32_bf16(ahi, bl, acc[nt], 0, 0, 0);
            }
        }
    }

#pragma unroll
    for (int nt = 0; nt < NT; ++nt) {
        const int n = nt * 16 + col;
        if (n < CO) {
            const float bv = bias[n];
#pragma unroll
            for (int r = 0; r < 4; ++r) {
                const int m = pixel0 + quad * 4 + r;
                if (m < HoWo) {
                    float v = acc[nt][r] + bv;
                    if (RELU) v = fmaxf(v, 0.f);
                    out[((size_t)b * CO + n) * HoWo + m] = v;
                }
            }
        }
    }
}

// ---------------------------------------------------------------------------
// Scalar LDS deform (stages 1 and 6).
// ---------------------------------------------------------------------------
template<int K, int CI, int CO, int H, int W, int Ho, int Wo, bool RELU,
         int CSPLIT, int STRIDE, int THREADS, int SPLIT>
__global__ __launch_bounds__(THREADS)
void deform_lds(const float* __restrict__ x, const float* __restrict__ off,
                const float* __restrict__ w, const float* __restrict__ bias,
                float* __restrict__ out)
{
    constexpr int KK    = K * K;
    constexpr int HW    = H * W;
    constexpr int HoWo  = Ho * Wo;
    constexpr int NPASS = CI / CSPLIT;
    constexpr int CHUNK = (HoWo + SPLIT - 1) / SPLIT;
    static_assert(CHUNK <= THREADS, "chunk must fit in one block");
    __shared__ __align__(16) float tile[HW * STRIDE];

    const int b   = blockIdx.x / SPLIT;
    const int sp  = blockIdx.x - b * SPLIT;
    const int tid = threadIdx.x;
    const int s   = sp * CHUNK + tid;
    const bool active = (tid < CHUNK) && (s < HoWo);

    const int oy = s / Wo, ox = s - oy * Wo;
    const float* offp = off + ((size_t)b * 2 * KK) * HoWo + s;

    float acc[CO];
#pragma unroll
    for (int o = 0; o < CO; ++o) acc[o] = 0.f;

    for (int pass = 0; pass < NPASS; ++pass) {
        const int cbase = pass * CSPLIT;
        __syncthreads();
        for (int pos = tid; pos < HW; pos += THREADS) {
#pragma unroll
            for (int c = 0; c < CSPLIT; ++c)
                tile[pos * STRIDE + c] = x[((size_t)b * CI + (cbase + c)) * HW + pos];
        }
        __syncthreads();

        if (active) {
            for (int kk = 0; kk < KK; ++kk) {
                const float dy = offp[(size_t)(2 * kk + 0) * HoWo];
                const float dx = offp[(size_t)(2 * kk + 1) * HoWo];
                const float py = (float)(kk / K + oy) + dy;
                const float px = (float)(kk % K + ox) + dx;
                const float y0f = floorf(py), x0f = floorf(px);
                const float wy = py - y0f, wx = px - x0f;
                const int y0 = (int)y0f, x0 = (int)x0f;
                const int y1 = y0 + 1,   x1 = x0 + 1;

                const float m00 = (y0 >= 0 && y0 < H && x0 >= 0 && x0 < W) ? 1.f : 0.f;
                const float m01 = (y0 >= 0 && y0 < H && x1 >= 0 && x1 < W) ? 1.f : 0.f;
                const float m10 = (y1 >= 0 && y1 < H && x0 >= 0 && x0 < W) ? 1.f : 0.f;
                const float m11 = (y1 >= 0 && y1 < H && x1 >= 0 && x1 < W) ? 1.f : 0.f;

                const float w00 = (1.f - wy) * (1.f - wx) * m00;
                const float w01 = (1.f - wy) * wx         * m01;
                const float w10 = wy         * (1.f - wx) * m10;
                const float w11 = wy         * wx         * m11;

                const int y0c = min(max(y0, 0), H - 1), y1c = min(max(y1, 0), H - 1);
                const int x0c = min(max(x0, 0), W - 1), x1c = min(max(x1, 0), W - 1);
                const int i00 = (y0c * W + x0c) * STRIDE;
                const int i01 = (y0c * W + x1c) * STRIDE;
                const int i10 = (y1c * W + x0c) * STRIDE;
                const int i11 = (y1c * W + x1c) * STRIDE;

                if constexpr (CSPLIT % 4 == 0) {
#pragma unroll
                    for (int cg = 0; cg < CSPLIT; cg += 4) {
                        const f32x4 v00 = *(const f32x4*)(tile + i00 + cg);
                        const f32x4 v01 = *(const f32x4*)(tile + i01 + cg);
                        const f32x4 v10 = *(const f32x4*)(tile + i10 + cg);
                        const f32x4 v11 = *(const f32x4*)(tile + i11 + cg);
#pragma unroll
                        for (int j = 0; j < 4; ++j) {
                            const float sv = fmaf(v11[j], w11, fmaf(v10[j], w10,
                                             fmaf(v01[j], w01, v00[j] * w00)));
#pragma unroll
                            for (int o = 0; o < CO; ++o)
                                acc[o] = fmaf(sv, w[(size_t)(o * CI + cbase + cg + j) * KK + kk], acc[o]);
                        }
                    }
                } else {
                    const float sv = fmaf(tile[i11], w11, fmaf(tile[i10], w10,
                                     fmaf(tile[i01], w01, tile[i00] * w00)));
#pragma unroll
                    for (int o = 0; o < CO; ++o)
                        acc[o] = fmaf(sv, w[(size_t)(o * CI + cbase) * KK + kk], acc[o]);
                }
            }
        }
    }

    if (active) {
        float* op = out + ((size_t)b * CO) * HoWo + s;
#pragma unroll
        for (int o = 0; o < CO; ++o) {
            float v = acc[o] + bias[o];
            if (RELU) v = fmaxf(v, 0.f);
            op[(size_t)o * HoWo] = v;
        }
    }
}

// ---------------------------------------------------------------------------
// Register-tiled direct VALID conv (stages 1 and 6 offset convs).
// ---------------------------------------------------------------------------
template<int K, int CI, int NOC, int OC, int H, int W, int Ho, int Wo, int PIX>
__global__ __launch_bounds__(256)
void conv_tile(const float* __restrict__ x, const float* __restrict__ w,
               const float* __restrict__ bias, float* __restrict__ out)
{
    constexpr int KK   = K * K;
    constexpr int HoWo = Ho * Wo;
    constexpr int WoG  = (Wo + PIX - 1) / PIX;
    constexpr int G    = Ho * WoG;
    constexpr int XV   = PIX + K - 1;

    const int oc0   = blockIdx.y * NOC;
    const int g_all = blockIdx.x * 256 + threadIdx.x;
    const int b     = g_all / G;
    const int g     = g_all - b * G;
    const int oy    = g / WoG;
    const int ox0   = (g - oy * WoG) * PIX;

    const float* xbp = x + (b * CI) * (H * W) + oy * W + ox0;
    const float* wp  = w + oc0 * (CI * KK);

    float acc[PIX][NOC];
#pragma unroll
    for (int p = 0; p < PIX; ++p)
#pragma unroll
        for (int j = 0; j < NOC; ++j) acc[p][j] = bias[oc0 + j];

    const int lim = W - 1 - ox0;

    for (int ci = 0; ci < CI; ++ci) {
        const float* xc = xbp + ci * (H * W);
#pragma unroll
        for (int ky = 0; ky < K; ++ky) {
            float xv[XV];
#pragma unroll
            for (int i = 0; i < XV; ++i) {
                const int off = (i <= lim) ? i : lim;
                xv[i] = xc[ky * W + off];
            }
#pragma unroll
            for (int kx = 0; kx < K; ++kx) {
#pragma unroll
                for (int p = 0; p < PIX; ++p) {
                    const float v = xv[p + kx];
#pragma unroll
                    for (int j = 0; j < NOC; ++j)
                        acc[p][j] = fmaf(v, wp[j * (CI * KK) + ci * KK + ky * K + kx], acc[p][j]);
                }
            }
        }
    }

    float* op = out + (b * OC + oc0) * HoWo + oy * Wo + ox0;
#pragma unroll
    for (int p = 0; p < PIX; ++p) {
        if (ox0 + p < Wo) {
#pragma unroll
            for (int j = 0; j < NOC; ++j) op[j * HoWo + p] = acc[p][j];
        }
    }
}

__global__ void fc_kernel(const float* __restrict__ h, const float* __restrict__ w,
                          const float* __restrict__ bias, float* __restrict__ out,
                          int B, int IN, int OUT, int relu)
{
    const int idx = blockIdx.x * blockDim.x + threadIdx.x;
    if (idx >= B * OUT) return;
    const int b = idx / OUT;
    const int j = idx - b * OUT;
    const float* hb = h + b * IN;
    const float* wj = w + j * IN;
    float acc = bias[j];
    for (int i = 0; i < IN; ++i) acc = fmaf(hb[i], wj[i], acc);
    if (relu) acc = fmaxf(acc, 0.f);
    out[idx] = acc;
}

// ---------------------------------------------------------------------------
extern "C" void kernel_launch(void* const* d_in, const int* in_sizes, int n_in,
                              void* d_out, int out_size, void* d_ws, size_t ws_size,
                              hipStream_t stream)
{
    const int B = 512;
    const float* x = (const float*)d_in[0];
    const float *ow[6], *ob[6], *w[6], *bi[6];
    for (int i = 0; i < 6; ++i) {
        ow[i] = (const float*)d_in[1 + 4 * i];
        ob[i] = (const float*)d_in[2 + 4 * i];
        w[i]  = (const float*)d_in[3 + 4 * i];
        bi[i] = (const float*)d_in[4 + 4 * i];
    }
    const float* fc1w = (const float*)d_in[25];
    const float* fc1b = (const float*)d_in[26];
    const float* fc2w = (const float*)d_in[27];
    const float* fc2b = (const float*)d_in[28];
    float* out = (float*)d_out;

    float* P   = (float*)d_ws;        // 14M floats
    float* Q   = P  + 14000000;       // 14M floats
    float* OFF = Q  + 14000000;       // 18.2M floats
    float* Z   = OFF + 18200000;      // fc intermediate
    ushort_t* WBhi = (ushort_t*)(Z + 200000);   // conv_mfma weights
    ushort_t* WBlo = WBhi + 200000;
    ushort_t* WDhi = WBlo + 200000;             // deform_mfma weights
    ushort_t* WDlo = WDhi + 200000;

    const dim3 blk(256);
    #define GRIDT(Ho, Wo, PIX, NG) dim3((B * (Ho) * (((Wo) + (PIX) - 1) / (PIX)) + 255) / 256, (NG), 1)
    #define CEILDIV(a, b) (((a) + (b) - 1) / (b))

    // ---- stage 1: input x (CI=1). conv_tile -> OFF; deform_lds -> P ----
    conv_tile<3, 1, 6, 18, 33, 33, 31, 31, 4><<<GRIDT(31, 31, 4, 3), blk, 0, stream>>>(x, ow[0], ob[0], OFF);
    deform_lds<3, 1, 16, 33, 33, 31, 31, true, 1, 1, 512, 2><<<dim3(B * 2), dim3(512), 0, stream>>>(x, OFF, w[0], bi[0], P);

    // ---- stage 2: CI=16 K=3 31x31->29x29 OC(off)=18 CO=32. P -> Q ----
    {
        const int M = B * 961;
        ushort_t* Xhi = (ushort_t*)Q;
        ushort_t* Xlo = Xhi + (size_t)(M + 2048) * 16;
        convert_nhwc<16, 961><<<CEILDIV(M, 256), blk, 0, stream>>>(P, Xhi, Xlo, M);
        wprep<16, 9, 10, 32, 18><<<CEILDIV(10 * 32 * 16, 256), blk, 0, stream>>>(ow[1], WBhi, WBlo);
        conv_mfma<16, 3, 31, 31, 29, 29, 18, 2, 2, 5><<<dim3(CEILDIV(M, 256), 1), blk, 0, stream>>>(Xhi, Xlo, WBhi, WBlo, ob[1], OFF, M);
        wprep_d<16, 9, 12, 32, 32><<<CEILDIV(2 * 12 * 32 * 8, 256), blk, 0, stream>>>(w[1], WDhi, WDlo);
        deform_mfma<3, 16, 32, 31, 31, 29, 29, true, 8, 12><<<dim3(B * 7), dim3(512), 0, stream>>>(P, OFF, WDhi, WDlo, bi[1], Q);
    }
    // ---- stage 3: CI=32 K=5 29x29->25x25 OC(off)=50 CO=16 (no relu). Q -> P ----
    {
        const int M = B * 841;
        ushort_t* Xhi = (ushort_t*)P;
        ushort_t* Xlo = Xhi + (size_t)(M + 2048) * 32;
        convert_nhwc<32, 841><<<CEILDIV(M, 256), blk, 0, stream>>>(Q, Xhi, Xlo, M);
        wprep<32, 25, 25, 64, 50><<<CEILDIV(25 * 64 * 32, 256), blk, 0, stream>>>(ow[2], WBhi, WBlo);
        conv_mfma<32, 5, 29, 29, 25, 25, 50, 4, 4, 25><<<dim3(CEILDIV(M, 256), 1), blk, 0, stream>>>(Xhi, Xlo, WBhi, WBlo, ob[2], OFF, M);
        wprep_d<32, 25, 28, 16, 16><<<CEILDIV(4 * 28 * 16 * 8, 256), blk, 0, stream>>>(w[2], WDhi, WDlo);
        deform_mfma<5, 32, 16, 29, 29, 25, 25, false, 8, 28><<<dim3(B * 5), dim3(512), 0, stream>>>(Q, OFF, WDhi, WDlo, bi[2], P);
    }
    // ---- stage 4: CI=16 K=7 25x25->19x19 OC(off)=98 CO=16. P -> Q ----
    {
        const int M = B * 625;
        ushort_t* Xhi = (ushort_t*)Q;
        ushort_t* Xlo = Xhi + (size_t)(M + 2048) * 16;
        convert_nhwc<16, 625><<<CEILDIV(M, 256), blk, 0, stream>>>(P, Xhi, Xlo, M);
        wprep<16, 49, 50, 112, 98><<<CEILDIV(50 * 112 * 16, 256), blk, 0, stream>>>(ow[3], WBhi, WBlo);
        conv_mfma<16, 7, 25, 25, 19, 19, 98, 7, 4, 25><<<dim3(CEILDIV(M, 256), 2), blk, 0, stream>>>(Xhi, Xlo, WBhi, WBlo, ob[3], OFF, M);
        wprep_d<16, 49, 52, 16, 16><<<CEILDIV(2 * 52 * 16 * 8, 256), blk, 0, stream>>>(w[3], WDhi, WDlo);
        deform_mfma<7, 16, 16, 25, 25, 19, 19, true, 8, 52><<<dim3(B * 3), dim3(512), 0, stream>>>(P, OFF, WDhi, WDlo, bi[3], Q);
    }
    // ---- stage 5: CI=16 K=5 19x19->15x15 OC(off)=50 CO=8. Q -> P ----
    {
        const int M = B * 361;
        ushort_t* Xhi = (ushort_t*)P;
        ushort_t* Xlo = Xhi + (size_t)(M + 2048) * 16;
        convert_nhwc<16, 361><<<CEILDIV(M, 256), blk, 0, stream>>>(Q, Xhi, Xlo, M);
        wprep<16, 25, 26, 64, 50><<<CEILDIV(26 * 64 * 16, 256), blk, 0, stream>>>(ow[4], WBhi, WBlo);
        conv_mfma<16, 5, 19, 19, 15, 15, 50, 4, 4, 13><<<dim3(CEILDIV(M, 256), 1), blk, 0, stream>>>(Xhi, Xlo, WBhi, WBlo, ob[4], OFF, M);
        wprep_d<16, 25, 28, 16, 8><<<CEILDIV(2 * 28 * 16 * 8, 256), blk, 0, stream>>>(w[4], WDhi, WDlo);
        deform_mfma<5, 16, 8, 19, 19, 15, 15, true, 4, 28><<<dim3(B * 4), dim3(256), 0, stream>>>(Q, OFF, WDhi, WDlo, bi[4], P);
    }
    // ---- stage 6: CI=8 K=3 15x15->13x13 CO=4. P -> Q ----
    conv_tile<3, 8, 6, 18, 15, 15, 13, 13, 4><<<GRIDT(13, 13, 4, 3), blk, 0, stream>>>(P, ow[5], ob[5], OFF);
    deform_lds<3, 8, 4, 15, 15, 13, 13, true, 8, 12, 192, 1><<<dim3(B), dim3(192), 0, stream>>>(P, OFF, w[5], bi[5], Q);

    // ---- FC head (reads Q = 512 x 4 x 13 x 13) ----
    fc_kernel<<<dim3(CEILDIV(B * 256, 256)), blk, 0, stream>>>(Q, fc1w, fc1b, Z, B, 676, 256, 1);
    fc_kernel<<<dim3(CEILDIV(B * 10, 256)), blk, 0, stream>>>(Z, fc2w, fc2b, out, B, 256, 10, 0);

    #undef GRIDT
    #undef CEILDIV
}

// Round 10
// 1215.377 us; speedup vs baseline: 3.1420x; 1.1407x over previous
//
#include <hip/hip_runtime.h>

typedef __attribute__((ext_vector_type(8))) short bf16x8;
typedef __attribute__((ext_vector_type(4))) float f32x4;
typedef unsigned short ushort_t;

__device__ inline ushort_t bf16_trunc(float f) { return (ushort_t)(__float_as_uint(f) >> 16); }
__device__ inline float bf16_to_f(ushort_t u) { return __uint_as_float(((unsigned int)u) << 16); }

// ---------------------------------------------------------------------------
// NCHW fp32 -> NHWC bf16 hi/lo planes (A-operand for conv_mfma).
// ---------------------------------------------------------------------------
template<int CI, int HW>
__global__ __launch_bounds__(256)
void convert_nhwc(const float* __restrict__ x, ushort_t* __restrict__ hi,
                  ushort_t* __restrict__ lo, int Mtotal)
{
    const int m = blockIdx.x * 256 + threadIdx.x;
    if (m >= Mtotal) return;
    const int b = m / HW, pos = m - b * HW;
    const float* xp = x + (size_t)b * CI * HW + pos;
    ushort_t* hp = hi + (size_t)m * CI;
    ushort_t* lp = lo + (size_t)m * CI;
#pragma unroll
    for (int ci = 0; ci < CI; ++ci) {
        const float v = xp[(size_t)ci * HW];
        const ushort_t h = bf16_trunc(v);
        hp[ci] = h;
        lp[ci] = bf16_trunc(v - bf16_to_f(h));
    }
}

// ---------------------------------------------------------------------------
// Weight prep for conv_mfma: OIHW fp32 -> [kk][n][ci] hi/lo, zero-padded.
// ---------------------------------------------------------------------------
template<int CI, int KK, int KKPAD, int NPAD, int OC>
__global__ __launch_bounds__(256)
void wprep(const float* __restrict__ w, ushort_t* __restrict__ bhi, ushort_t* __restrict__ blo)
{
    const int idx = blockIdx.x * 256 + threadIdx.x;
    if (idx >= KKPAD * NPAD * CI) return;
    const int kk  = idx / (NPAD * CI);
    const int rem = idx - kk * (NPAD * CI);
    const int n   = rem / CI;
    const int ci  = rem - n * CI;
    const float v = (kk < KK && n < OC) ? w[((size_t)n * CI + ci) * KK + kk] : 0.f;
    const ushort_t h = bf16_trunc(v);
    bhi[idx] = h;
    blo[idx] = bf16_trunc(v - bf16_to_f(h));
}

// ---------------------------------------------------------------------------
// Weight prep for deform_mfma: pack [kslot = pass*TPAD+tap][n][j=ci_in_pass].
// ---------------------------------------------------------------------------
template<int CI, int KK, int TPAD, int NPAD, int OC>
__global__ __launch_bounds__(256)
void wprep_d(const float* __restrict__ w, ushort_t* __restrict__ bhi, ushort_t* __restrict__ blo)
{
    constexpr int NPASS = (CI + 7) / 8;
    constexpr int TOTAL = NPASS * TPAD * NPAD * 8;
    const int idx = blockIdx.x * 256 + threadIdx.x;
    if (idx >= TOTAL) return;
    const int j     = idx & 7;
    const int n     = (idx >> 3) % NPAD;
    const int kslot = (idx >> 3) / NPAD;
    const int pass  = kslot / TPAD;
    const int tap   = kslot - pass * TPAD;
    const int ci    = pass * 8 + j;
    const float v = (tap < KK && n < OC && ci < CI) ? w[((size_t)n * CI + ci) * KK + tap] : 0.f;
    const ushort_t h = bf16_trunc(v);
    bhi[idx] = h;
    blo[idx] = bf16_trunc(v - bf16_to_f(h));
}

// ---------------------------------------------------------------------------
// MFMA implicit-im2col conv (offset convs). fp32 via bf16 hi/lo split.
// m indexes VALID outputs only (m = b*HoWo + oy*Wo + ox). Per-lane A base
// (b*HW + oy*W + ox)*CI computed once; k-loop adds dkk*CI (linear). Real taps
// stay in-bounds (oy+ky<=H-1, ox+kx<=W-1); pad-tap overreads land in the
// +2048-position pad of the plane buffers and meet zero weights.
// ---------------------------------------------------------------------------
template<int CI, int K, int H, int W, int Ho, int Wo, int OC, int NTTOT, int NT0, int KSTEPS>
__global__ __launch_bounds__(256)
void conv_mfma(const ushort_t* __restrict__ Xhi, const ushort_t* __restrict__ Xlo,
               const ushort_t* __restrict__ Bhi, const ushort_t* __restrict__ Blo,
               const float* __restrict__ bias, float* __restrict__ out, int Mtotal)
{
    constexpr int NPAD = NTTOT * 16;
    constexpr int HW   = H * W;
    constexpr int HoWo = Ho * Wo;

    const int lane = threadIdx.x & 63;
    const int wid  = threadIdx.x >> 6;
    const int col  = lane & 15;
    const int quad = lane >> 4;

    const int mBase  = blockIdx.x * 256 + wid * 64;   // 4 m-tiles per wave
    const int ntBase = blockIdx.y * NT0;

    // per-mt A element base from valid-m -> (b, oy, ox)
    int aBase[4];
#pragma unroll
    for (int mt = 0; mt < 4; ++mt) {
        int mm = mBase + mt * 16 + col;
        if (mm >= Mtotal) mm = Mtotal - 1;            // clamped lanes discarded at store
        const int b   = mm / HoWo;
        const int pos = mm - b * HoWo;
        const int oy  = pos / Wo;
        const int ox  = pos - oy * Wo;
        aBase[mt] = (b * HW + oy * W + ox) * CI;
    }

    f32x4 acc[4][NT0];
#pragma unroll
    for (int mt = 0; mt < 4; ++mt)
#pragma unroll
        for (int nt = 0; nt < NT0; ++nt) acc[mt][nt] = (f32x4){0.f, 0.f, 0.f, 0.f};

    const int bLane = col * CI;

#pragma unroll
    for (int ks = 0; ks < KSTEPS; ++ks) {
        const int k0  = ks * 32 + quad * 8;
        const int tap = k0 / CI;
        const int ci  = k0 - tap * CI;
        const int dkk = (tap / K) * W + (tap - (tap / K) * K);

        bf16x8 ah[4], al[4];
#pragma unroll
        for (int mt = 0; mt < 4; ++mt) {
            const int aoff = aBase[mt] + dkk * CI + ci;
            ah[mt] = *(const bf16x8*)(Xhi + aoff);
            al[mt] = *(const bf16x8*)(Xlo + aoff);
        }
#pragma unroll
        for (int nt = 0; nt < NT0; ++nt) {
            const int ntg = ntBase + nt;
            if (ntg < NTTOT) {
                const int boff = tap * NPAD * CI + ntg * 16 * CI + bLane + ci;
                const bf16x8 bh = *(const bf16x8*)(Bhi + boff);
                const bf16x8 bl = *(const bf16x8*)(Blo + boff);
#pragma unroll
                for (int mt = 0; mt < 4; ++mt) {
                    acc[mt][nt] = __builtin_amdgcn_mfma_f32_16x16x32_bf16(ah[mt], bh, acc[mt][nt], 0, 0, 0);
                    acc[mt][nt] = __builtin_amdgcn_mfma_f32_16x16x32_bf16(al[mt], bh, acc[mt][nt], 0, 0, 0);
                    acc[mt][nt] = __builtin_amdgcn_mfma_f32_16x16x32_bf16(ah[mt], bl, acc[mt][nt], 0, 0, 0);
                }
            }
        }
    }

#pragma unroll
    for (int mt = 0; mt < 4; ++mt) {
#pragma unroll
        for (int nt = 0; nt < NT0; ++nt) {
            const int ntg = ntBase + nt;
            const int n   = ntg * 16 + col;
            if (ntg < NTTOT && n < OC) {
                const float bv = bias[n];
#pragma unroll
                for (int r = 0; r < 4; ++r) {
                    const int m = mBase + mt * 16 + quad * 4 + r;
                    if (m < Mtotal) {
                        const int b   = m / HoWo;
                        const int pos = m - b * HoWo;
                        out[((size_t)b * OC + n) * HoWo + pos] = acc[mt][nt][r] + bv;
                    }
                }
            }
        }
    }
}

// ---------------------------------------------------------------------------
// MFMA deformable conv (stages 2-5). Unchanged from R9.
// ---------------------------------------------------------------------------
template<int K, int CI, int CO, int H, int W, int Ho, int Wo, bool RELU,
         int MT, int TPAD>
__global__ __launch_bounds__(MT * 64)
void deform_mfma(const float* __restrict__ x, const float* __restrict__ off,
                 const ushort_t* __restrict__ Bph, const ushort_t* __restrict__ Bpl,
                 const float* __restrict__ bias, float* __restrict__ out)
{
    constexpr int KK     = K * K;
    constexpr int HW     = H * W;
    constexpr int HoWo   = Ho * Wo;
    constexpr int NPASS  = CI / 8;
    constexpr int NT     = (CO + 15) / 16;
    constexpr int NPAD   = NT * 16;
    constexpr int STRIDE = 12;
    constexpr int nMB    = (HoWo + MT * 16 - 1) / (MT * 16);
    constexpr int THREADS = MT * 64;
    __shared__ __align__(16) float tile[HW * STRIDE];

    const int b    = blockIdx.x / nMB;
    const int mb   = blockIdx.x - b * nMB;
    const int tid  = threadIdx.x;
    const int wid  = tid >> 6;
    const int lane = tid & 63;
    const int col  = lane & 15;
    const int quad = lane >> 4;

    const int pixel0 = (mb * MT + wid) * 16;
    const int s      = pixel0 + col;
    const bool am    = (s < HoWo);
    const int oy = s / Wo, ox = s - oy * Wo;

    const float* offB = off + (size_t)b * 2 * KK * HoWo;

    f32x4 acc[NT];
#pragma unroll
    for (int nt = 0; nt < NT; ++nt) acc[nt] = (f32x4){0.f, 0.f, 0.f, 0.f};

    for (int pass = 0; pass < NPASS; ++pass) {
        const int cbase = pass * 8;
        __syncthreads();
        for (int pos = tid; pos < HW; pos += THREADS) {
#pragma unroll
            for (int c = 0; c < 8; ++c)
                tile[pos * STRIDE + c] = x[((size_t)b * CI + (cbase + c)) * HW + pos];
        }
        __syncthreads();

#pragma unroll
        for (int tg = 0; tg < TPAD / 4; ++tg) {
            const int tap = tg * 4 + quad;
            bf16x8 ahi = (bf16x8){0,0,0,0,0,0,0,0};
            bf16x8 alo = (bf16x8){0,0,0,0,0,0,0,0};

            if (am && tap < KK) {
                const float dy = offB[(size_t)(2 * tap + 0) * HoWo + s];
                const float dx = offB[(size_t)(2 * tap + 1) * HoWo + s];
                const float py = (float)(tap / K + oy) + dy;
                const float px = (float)(tap % K + ox) + dx;
                const float y0f = floorf(py), x0f = floorf(px);
                const float wy = py - y0f, wx = px - x0f;
                const int y0 = (int)y0f, x0 = (int)x0f;
                const int y1 = y0 + 1,   x1 = x0 + 1;

                const float m00 = (y0 >= 0 && y0 < H && x0 >= 0 && x0 < W) ? 1.f : 0.f;
                const float m01 = (y0 >= 0 && y0 < H && x1 >= 0 && x1 < W) ? 1.f : 0.f;
                const float m10 = (y1 >= 0 && y1 < H && x0 >= 0 && x0 < W) ? 1.f : 0.f;
                const float m11 = (y1 >= 0 && y1 < H && x1 >= 0 && x1 < W) ? 1.f : 0.f;

                const float w00 = (1.f - wy) * (1.f - wx) * m00;
                const float w01 = (1.f - wy) * wx         * m01;
                const float w10 = wy         * (1.f - wx) * m10;
                const float w11 = wy         * wx         * m11;

                const int y0c = min(max(y0, 0), H - 1), y1c = min(max(y1, 0), H - 1);
                const int x0c = min(max(x0, 0), W - 1), x1c = min(max(x1, 0), W - 1);
                const int i00 = (y0c * W + x0c) * STRIDE;
                const int i01 = (y0c * W + x1c) * STRIDE;
                const int i10 = (y1c * W + x0c) * STRIDE;
                const int i11 = (y1c * W + x1c) * STRIDE;

                float v00[8], v01[8], v10[8], v11[8];
                *(f32x4*)(v00) = *(const f32x4*)(tile + i00); *(f32x4*)(v00 + 4) = *(const f32x4*)(tile + i00 + 4);
                *(f32x4*)(v01) = *(const f32x4*)(tile + i01); *(f32x4*)(v01 + 4) = *(const f32x4*)(tile + i01 + 4);
                *(f32x4*)(v10) = *(const f32x4*)(tile + i10); *(f32x4*)(v10 + 4) = *(const f32x4*)(tile + i10 + 4);
                *(f32x4*)(v11) = *(const f32x4*)(tile + i11); *(f32x4*)(v11 + 4) = *(const f32x4*)(tile + i11 + 4);
#pragma unroll
                for (int j = 0; j < 8; ++j) {
                    const float sv = fmaf(v11[j], w11, fmaf(v10[j], w10,
                                     fmaf(v01[j], w01, v00[j] * w00)));
                    const ushort_t h = bf16_trunc(sv);
                    ahi[j] = (short)h;
                    alo[j] = (short)bf16_trunc(sv - bf16_to_f(h));
                }
            }

            const size_t kslot = (size_t)(pass * TPAD + tap);
#pragma unroll
            for (int nt = 0; nt < NT; ++nt) {
                const bf16x8 bh = *(const bf16x8*)(Bph + (kslot * NPAD + nt * 16 + col) * 8);
                const bf16x8 bl = *(const bf16x8*)(Bpl + (kslot * NPAD + nt * 16 + col) * 8);
                acc[nt] = __builtin_amdgcn_mfma_f32_16x16x32_bf16(ahi, bh, acc[nt], 0, 0, 0);
                acc[nt] = __builtin_amdgcn_mfma_f32_16x16x32_bf16(alo, bh, acc[nt], 0, 0, 0);
                acc[nt] = __builtin_amdgcn_mfma_f32_16x16x32_bf16(ahi, bl, acc[nt], 0, 0, 0);
            }
        }
    }

#pragma unroll
    for (int nt = 0; nt < NT; ++nt) {
        const int n = nt * 16 + col;
        if (n < CO) {
            const float bv = bias[n];
#pragma unroll
            for (int r = 0; r < 4; ++r) {
                const int m = pixel0 + quad * 4 + r;
                if (m < HoWo) {
                    float v = acc[nt][r] + bv;
                    if (RELU) v = fmaxf(v, 0.f);
                    out[((size_t)b * CO + n) * HoWo + m] = v;
                }
            }
        }
    }
}

// ---------------------------------------------------------------------------
// Scalar LDS deform (stages 1 and 6).
// ---------------------------------------------------------------------------
template<int K, int CI, int CO, int H, int W, int Ho, int Wo, bool RELU,
         int CSPLIT, int STRIDE, int THREADS, int SPLIT>
__global__ __launch_bounds__(THREADS)
void deform_lds(const float* __restrict__ x, const float* __restrict__ off,
                const float* __restrict__ w, const float* __restrict__ bias,
                float* __restrict__ out)
{
    constexpr int KK    = K * K;
    constexpr int HW    = H * W;
    constexpr int HoWo  = Ho * Wo;
    constexpr int NPASS = CI / CSPLIT;
    constexpr int CHUNK = (HoWo + SPLIT - 1) / SPLIT;
    static_assert(CHUNK <= THREADS, "chunk must fit in one block");
    __shared__ __align__(16) float tile[HW * STRIDE];

    const int b   = blockIdx.x / SPLIT;
    const int sp  = blockIdx.x - b * SPLIT;
    const int tid = threadIdx.x;
    const int s   = sp * CHUNK + tid;
    const bool active = (tid < CHUNK) && (s < HoWo);

    const int oy = s / Wo, ox = s - oy * Wo;
    const float* offp = off + ((size_t)b * 2 * KK) * HoWo + s;

    float acc[CO];
#pragma unroll
    for (int o = 0; o < CO; ++o) acc[o] = 0.f;

    for (int pass = 0; pass < NPASS; ++pass) {
        const int cbase = pass * CSPLIT;
        __syncthreads();
        for (int pos = tid; pos < HW; pos += THREADS) {
#pragma unroll
            for (int c = 0; c < CSPLIT; ++c)
                tile[pos * STRIDE + c] = x[((size_t)b * CI + (cbase + c)) * HW + pos];
        }
        __syncthreads();

        if (active) {
            for (int kk = 0; kk < KK; ++kk) {
                const float dy = offp[(size_t)(2 * kk + 0) * HoWo];
                const float dx = offp[(size_t)(2 * kk + 1) * HoWo];
                const float py = (float)(kk / K + oy) + dy;
                const float px = (float)(kk % K + ox) + dx;
                const float y0f = floorf(py), x0f = floorf(px);
                const float wy = py - y0f, wx = px - x0f;
                const int y0 = (int)y0f, x0 = (int)x0f;
                const int y1 = y0 + 1,   x1 = x0 + 1;

                const float m00 = (y0 >= 0 && y0 < H && x0 >= 0 && x0 < W) ? 1.f : 0.f;
                const float m01 = (y0 >= 0 && y0 < H && x1 >= 0 && x1 < W) ? 1.f : 0.f;
                const float m10 = (y1 >= 0 && y1 < H && x0 >= 0 && x0 < W) ? 1.f : 0.f;
                const float m11 = (y1 >= 0 && y1 < H && x1 >= 0 && x1 < W) ? 1.f : 0.f;

                const float w00 = (1.f - wy) * (1.f - wx) * m00;
                const float w01 = (1.f - wy) * wx         * m01;
                const float w10 = wy         * (1.f - wx) * m10;
                const float w11 = wy         * wx         * m11;

                const int y0c = min(max(y0, 0), H - 1), y1c = min(max(y1, 0), H - 1);
                const int x0c = min(max(x0, 0), W - 1), x1c = min(max(x1, 0), W - 1);
                const int i00 = (y0c * W + x0c) * STRIDE;
                const int i01 = (y0c * W + x1c) * STRIDE;
                const int i10 = (y1c * W + x0c) * STRIDE;
                const int i11 = (y1c * W + x1c) * STRIDE;

                if constexpr (CSPLIT % 4 == 0) {
#pragma unroll
                    for (int cg = 0; cg < CSPLIT; cg += 4) {
                        const f32x4 v00 = *(const f32x4*)(tile + i00 + cg);
                        const f32x4 v01 = *(const f32x4*)(tile + i01 + cg);
                        const f32x4 v10 = *(const f32x4*)(tile + i10 + cg);
                        const f32x4 v11 = *(const f32x4*)(tile + i11 + cg);
#pragma unroll
                        for (int j = 0; j < 4; ++j) {
                            const float sv = fmaf(v11[j], w11, fmaf(v10[j], w10,
                                             fmaf(v01[j], w01, v00[j] * w00)));
#pragma unroll
                            for (int o = 0; o < CO; ++o)
                                acc[o] = fmaf(sv, w[(size_t)(o * CI + cbase + cg + j) * KK + kk], acc[o]);
                        }
                    }
                } else {
                    const float sv = fmaf(tile[i11], w11, fmaf(tile[i10], w10,
                                     fmaf(tile[i01], w01, tile[i00] * w00)));
#pragma unroll
                    for (int o = 0; o < CO; ++o)
                        acc[o] = fmaf(sv, w[(size_t)(o * CI + cbase) * KK + kk], acc[o]);
                }
            }
        }
    }

    if (active) {
        float* op = out + ((size_t)b * CO) * HoWo + s;
#pragma unroll
        for (int o = 0; o < CO; ++o) {
            float v = acc[o] + bias[o];
            if (RELU) v = fmaxf(v, 0.f);
            op[(size_t)o * HoWo] = v;
        }
    }
}

// ---------------------------------------------------------------------------
// Register-tiled direct VALID conv (stages 1 and 6 offset convs).
// ---------------------------------------------------------------------------
template<int K, int CI, int NOC, int OC, int H, int W, int Ho, int Wo, int PIX>
__global__ __launch_bounds__(256)
void conv_tile(const float* __restrict__ x, const float* __restrict__ w,
               const float* __restrict__ bias, float* __restrict__ out)
{
    constexpr int KK   = K * K;
    constexpr int HoWo = Ho * Wo;
    constexpr int WoG  = (Wo + PIX - 1) / PIX;
    constexpr int G    = Ho * WoG;
    constexpr int XV   = PIX + K - 1;

    const int oc0   = blockIdx.y * NOC;
    const int g_all = blockIdx.x * 256 + threadIdx.x;
    const int b     = g_all / G;
    const int g     = g_all - b * G;
    const int oy    = g / WoG;
    const int ox0   = (g - oy * WoG) * PIX;

    const float* xbp = x + (b * CI) * (H * W) + oy * W + ox0;
    const float* wp  = w + oc0 * (CI * KK);

    float acc[PIX][NOC];
#pragma unroll
    for (int p = 0; p < PIX; ++p)
#pragma unroll
        for (int j = 0; j < NOC; ++j) acc[p][j] = bias[oc0 + j];

    const int lim = W - 1 - ox0;

    for (int ci = 0; ci < CI; ++ci) {
        const float* xc = xbp + ci * (H * W);
#pragma unroll
        for (int ky = 0; ky < K; ++ky) {
            float xv[XV];
#pragma unroll
            for (int i = 0; i < XV; ++i) {
                const int off = (i <= lim) ? i : lim;
                xv[i] = xc[ky * W + off];
            }
#pragma unroll
            for (int kx = 0; kx < K; ++kx) {
#pragma unroll
                for (int p = 0; p < PIX; ++p) {
                    const float v = xv[p + kx];
#pragma unroll
                    for (int j = 0; j < NOC; ++j)
                        acc[p][j] = fmaf(v, wp[j * (CI * KK) + ci * KK + ky * K + kx], acc[p][j]);
                }
            }
        }
    }

    float* op = out + (b * OC + oc0) * HoWo + oy * Wo + ox0;
#pragma unroll
    for (int p = 0; p < PIX; ++p) {
        if (ox0 + p < Wo) {
#pragma unroll
            for (int j = 0; j < NOC; ++j) op[j * HoWo + p] = acc[p][j];
        }
    }
}

__global__ void fc_kernel(const float* __restrict__ h, const float* __restrict__ w,
                          const float* __restrict__ bias, float* __restrict__ out,
                          int B, int IN, int OUT, int relu)
{
    const int idx = blockIdx.x * blockDim.x + threadIdx.x;
    if (idx >= B * OUT) return;
    const int b = idx / OUT;
    const int j = idx - b * OUT;
    const float* hb = h + b * IN;
    const float* wj = w + j * IN;
    float acc = bias[j];
    for (int i = 0; i < IN; ++i) acc = fmaf(hb[i], wj[i], acc);
    if (relu) acc = fmaxf(acc, 0.f);
    out[idx] = acc;
}

// ---------------------------------------------------------------------------
extern "C" void kernel_launch(void* const* d_in, const int* in_sizes, int n_in,
                              void* d_out, int out_size, void* d_ws, size_t ws_size,
                              hipStream_t stream)
{
    const int B = 512;
    const float* x = (const float*)d_in[0];
    const float *ow[6], *ob[6], *w[6], *bi[6];
    for (int i = 0; i < 6; ++i) {
        ow[i] = (const float*)d_in[1 + 4 * i];
        ob[i] = (const float*)d_in[2 + 4 * i];
        w[i]  = (const float*)d_in[3 + 4 * i];
        bi[i] = (const float*)d_in[4 + 4 * i];
    }
    const float* fc1w = (const float*)d_in[25];
    const float* fc1b = (const float*)d_in[26];
    const float* fc2w = (const float*)d_in[27];
    const float* fc2b = (const float*)d_in[28];
    float* out = (float*)d_out;

    float* P   = (float*)d_ws;        // 14M floats
    float* Q   = P  + 14000000;       // 14M floats
    float* OFF = Q  + 14000000;       // 18.2M floats
    float* Z   = OFF + 18200000;      // fc intermediate
    ushort_t* WBhi = (ushort_t*)(Z + 200000);   // conv_mfma weights
    ushort_t* WBlo = WBhi + 200000;
    ushort_t* WDhi = WBlo + 200000;             // deform_mfma weights
    ushort_t* WDlo = WDhi + 200000;

    const dim3 blk(256);
    #define GRIDT(Ho, Wo, PIX, NG) dim3((B * (Ho) * (((Wo) + (PIX) - 1) / (PIX)) + 255) / 256, (NG), 1)
    #define CEILDIV(a, b) (((a) + (b) - 1) / (b))

    // ---- stage 1: input x (CI=1). conv_tile -> OFF; deform_lds -> P ----
    conv_tile<3, 1, 6, 18, 33, 33, 31, 31, 4><<<GRIDT(31, 31, 4, 3), blk, 0, stream>>>(x, ow[0], ob[0], OFF);
    deform_lds<3, 1, 16, 33, 33, 31, 31, true, 1, 1, 512, 2><<<dim3(B * 2), dim3(512), 0, stream>>>(x, OFF, w[0], bi[0], P);

    // ---- stage 2: CI=16 K=3 31x31->29x29 OC(off)=18 CO=32. P -> Q ----
    {
        const int Mc = B * 961;           // convert: all input positions
        const int Mv = B * 841;           // conv: valid outputs only
        ushort_t* Xhi = (ushort_t*)Q;
        ushort_t* Xlo = Xhi + (size_t)(Mc + 2048) * 16;
        convert_nhwc<16, 961><<<CEILDIV(Mc, 256), blk, 0, stream>>>(P, Xhi, Xlo, Mc);
        wprep<16, 9, 10, 32, 18><<<CEILDIV(10 * 32 * 16, 256), blk, 0, stream>>>(ow[1], WBhi, WBlo);
        conv_mfma<16, 3, 31, 31, 29, 29, 18, 2, 2, 5><<<dim3(CEILDIV(Mv, 256), 1), blk, 0, stream>>>(Xhi, Xlo, WBhi, WBlo, ob[1], OFF, Mv);
        wprep_d<16, 9, 12, 32, 32><<<CEILDIV(2 * 12 * 32 * 8, 256), blk, 0, stream>>>(w[1], WDhi, WDlo);
        deform_mfma<3, 16, 32, 31, 31, 29, 29, true, 8, 12><<<dim3(B * 7), dim3(512), 0, stream>>>(P, OFF, WDhi, WDlo, bi[1], Q);
    }
    // ---- stage 3: CI=32 K=5 29x29->25x25 OC(off)=50 CO=16 (no relu). Q -> P ----
    {
        const int Mc = B * 841;
        const int Mv = B * 625;
        ushort_t* Xhi = (ushort_t*)P;
        ushort_t* Xlo = Xhi + (size_t)(Mc + 2048) * 32;
        convert_nhwc<32, 841><<<CEILDIV(Mc, 256), blk, 0, stream>>>(Q, Xhi, Xlo, Mc);
        wprep<32, 25, 25, 64, 50><<<CEILDIV(25 * 64 * 32, 256), blk, 0, stream>>>(ow[2], WBhi, WBlo);
        conv_mfma<32, 5, 29, 29, 25, 25, 50, 4, 4, 25><<<dim3(CEILDIV(Mv, 256), 1), blk, 0, stream>>>(Xhi, Xlo, WBhi, WBlo, ob[2], OFF, Mv);
        wprep_d<32, 25, 28, 16, 16><<<CEILDIV(4 * 28 * 16 * 8, 256), blk, 0, stream>>>(w[2], WDhi, WDlo);
        deform_mfma<5, 32, 16, 29, 29, 25, 25, false, 8, 28><<<dim3(B * 5), dim3(512), 0, stream>>>(Q, OFF, WDhi, WDlo, bi[2], P);
    }
    // ---- stage 4: CI=16 K=7 25x25->19x19 OC(off)=98 CO=16. P -> Q ----
    {
        const int Mc = B * 625;
        const int Mv = B * 361;
        ushort_t* Xhi = (ushort_t*)Q;
        ushort_t* Xlo = Xhi + (size_t)(Mc + 2048) * 16;
        convert_nhwc<16, 625><<<CEILDIV(Mc, 256), blk, 0, stream>>>(P, Xhi, Xlo, Mc);
        wprep<16, 49, 50, 112, 98><<<CEILDIV(50 * 112 * 16, 256), blk, 0, stream>>>(ow[3], WBhi, WBlo);
        conv_mfma<16, 7, 25, 25, 19, 19, 98, 7, 4, 25><<<dim3(CEILDIV(Mv, 256), 2), blk, 0, stream>>>(Xhi, Xlo, WBhi, WBlo, ob[3], OFF, Mv);
        wprep_d<16, 49, 52, 16, 16><<<CEILDIV(2 * 52 * 16 * 8, 256), blk, 0, stream>>>(w[3], WDhi, WDlo);
        deform_mfma<7, 16, 16, 25, 25, 19, 19, true, 8, 52><<<dim3(B * 3), dim3(512), 0, stream>>>(P, OFF, WDhi, WDlo, bi[3], Q);
    }
    // ---- stage 5: CI=16 K=5 19x19->15x15 OC(off)=50 CO=8. Q -> P ----
    {
        const int Mc = B * 361;
        const int Mv = B * 225;
        ushort_t* Xhi = (ushort_t*)P;
        ushort_t* Xlo = Xhi + (size_t)(Mc + 2048) * 16;
        convert_nhwc<16, 361><<<CEILDIV(Mc, 256), blk, 0, stream>>>(Q, Xhi, Xlo, Mc);
        wprep<16, 25, 26, 64, 50><<<CEILDIV(26 * 64 * 16, 256), blk, 0, stream>>>(ow[4], WBhi, WBlo);
        conv_mfma<16, 5, 19, 19, 15, 15, 50, 4, 4, 13><<<dim3(CEILDIV(Mv, 256), 1), blk, 0, stream>>>(Xhi, Xlo, WBhi, WBlo, ob[4], OFF, Mv);
        wprep_d<16, 25, 28, 16, 8><<<CEILDIV(2 * 28 * 16 * 8, 256), blk, 0, stream>>>(w[4], WDhi, WDlo);
        deform_mfma<5, 16, 8, 19, 19, 15, 15, true, 4, 28><<<dim3(B * 4), dim3(256), 0, stream>>>(Q, OFF, WDhi, WDlo, bi[4], P);
    }
    // ---- stage 6: CI=8 K=3 15x15->13x13 CO=4. P -> Q ----
    conv_tile<3, 8, 6, 18, 15, 15, 13, 13, 4><<<GRIDT(13, 13, 4, 3), blk, 0, stream>>>(P, ow[5], ob[5], OFF);
    deform_lds<3, 8, 4, 15, 15, 13, 13, true, 8, 12, 192, 1><<<dim3(B), dim3(192), 0, stream>>>(P, OFF, w[5], bi[5], Q);

    // ---- FC head (reads Q = 512 x 4 x 13 x 13) ----
    fc_kernel<<<dim3(CEILDIV(B * 256, 256)), blk, 0, stream>>>(Q, fc1w, fc1b, Z, B, 676, 256, 1);
    fc_kernel<<<dim3(CEILDIV(B * 10, 256)), blk, 0, stream>>>(Z, fc2w, fc2b, out, B, 256, 10, 0);

    #undef GRIDT
    #undef CEILDIV
}

// Round 11
// 1104.597 us; speedup vs baseline: 3.4571x; 1.1003x over previous
//
#include <hip/hip_runtime.h>

typedef __attribute__((ext_vector_type(8))) short bf16x8;
typedef __attribute__((ext_vector_type(4))) float f32x4;
typedef unsigned short ushort_t;

__device__ inline ushort_t bf16_trunc(float f) { return (ushort_t)(__float_as_uint(f) >> 16); }
__device__ inline float bf16_to_f(ushort_t u) { return __uint_as_float(((unsigned int)u) << 16); }

// ---------------------------------------------------------------------------
// NCHW fp32 -> NHWC bf16 hi/lo planes (A-operand for conv_mfma).
// ---------------------------------------------------------------------------
template<int CI, int HW>
__global__ __launch_bounds__(256)
void convert_nhwc(const float* __restrict__ x, ushort_t* __restrict__ hi,
                  ushort_t* __restrict__ lo, int Mtotal)
{
    const int m = blockIdx.x * 256 + threadIdx.x;
    if (m >= Mtotal) return;
    const int b = m / HW, pos = m - b * HW;
    const float* xp = x + (size_t)b * CI * HW + pos;
    ushort_t* hp = hi + (size_t)m * CI;
    ushort_t* lp = lo + (size_t)m * CI;
#pragma unroll
    for (int ci = 0; ci < CI; ++ci) {
        const float v = xp[(size_t)ci * HW];
        const ushort_t h = bf16_trunc(v);
        hp[ci] = h;
        lp[ci] = bf16_trunc(v - bf16_to_f(h));
    }
}

// ---------------------------------------------------------------------------
// Weight prep for conv_mfma: OIHW fp32 -> [kk][n][ci] hi/lo, zero-padded.
// ---------------------------------------------------------------------------
template<int CI, int KK, int KKPAD, int NPAD, int OC>
__global__ __launch_bounds__(256)
void wprep(const float* __restrict__ w, ushort_t* __restrict__ bhi, ushort_t* __restrict__ blo)
{
    const int idx = blockIdx.x * 256 + threadIdx.x;
    if (idx >= KKPAD * NPAD * CI) return;
    const int kk  = idx / (NPAD * CI);
    const int rem = idx - kk * (NPAD * CI);
    const int n   = rem / CI;
    const int ci  = rem - n * CI;
    const float v = (kk < KK && n < OC) ? w[((size_t)n * CI + ci) * KK + kk] : 0.f;
    const ushort_t h = bf16_trunc(v);
    bhi[idx] = h;
    blo[idx] = bf16_trunc(v - bf16_to_f(h));
}

// ---------------------------------------------------------------------------
// Weight prep for deform_mfma: pack [kslot = pass*TPAD+tap][n][j=ci_in_pass].
// ---------------------------------------------------------------------------
template<int CI, int KK, int TPAD, int NPAD, int OC>
__global__ __launch_bounds__(256)
void wprep_d(const float* __restrict__ w, ushort_t* __restrict__ bhi, ushort_t* __restrict__ blo)
{
    constexpr int NPASS = (CI + 7) / 8;
    constexpr int TOTAL = NPASS * TPAD * NPAD * 8;
    const int idx = blockIdx.x * 256 + threadIdx.x;
    if (idx >= TOTAL) return;
    const int j     = idx & 7;
    const int n     = (idx >> 3) % NPAD;
    const int kslot = (idx >> 3) / NPAD;
    const int pass  = kslot / TPAD;
    const int tap   = kslot - pass * TPAD;
    const int ci    = pass * 8 + j;
    const float v = (tap < KK && n < OC && ci < CI) ? w[((size_t)n * CI + ci) * KK + tap] : 0.f;
    const ushort_t h = bf16_trunc(v);
    bhi[idx] = h;
    blo[idx] = bf16_trunc(v - bf16_to_f(h));
}

// ---------------------------------------------------------------------------
// MFMA implicit-im2col conv (offset convs). fp32 via bf16 hi/lo split.
// Valid-m indexing (R10) + double-buffered LDS staging of the B slab:
// per k-step the block fetches its NT0*16-n x 32-k B slice ONCE into LDS
// (one bf16x8 per thread per plane), all 4 waves read fragments from LDS.
// Slab rows padded to CI+8 ushorts (48B stride -> conflict-free b128 reads).
// n is clamped to NPAD-1 in the copy (clamped rows only feed MFMA tiles that
// the ntg<NTTOT guard skips); taps stay < KKPAD by construction.
// ---------------------------------------------------------------------------
template<int CI, int K, int H, int W, int Ho, int Wo, int OC, int NTTOT, int NT0, int KSTEPS>
__global__ __launch_bounds__(256)
void conv_mfma(const ushort_t* __restrict__ Xhi, const ushort_t* __restrict__ Xlo,
               const ushort_t* __restrict__ Bhi, const ushort_t* __restrict__ Blo,
               const float* __restrict__ bias, float* __restrict__ out, int Mtotal)
{
    constexpr int NPAD = NTTOT * 16;
    constexpr int HW   = H * W;
    constexpr int HoWo = Ho * Wo;
    constexpr int TKS  = 32 / CI;            // taps per 32-k step (CI | 32)
    constexpr int ROWS = TKS * NT0 * 16;     // slab rows (tap-major, n-minor)
    constexpr int BSTR = CI + 8;             // ushorts per row (48B/96B stride)
    constexpr int CH8  = CI / 8;
    constexpr int CHUNKS = ROWS * CH8;       // bf16x8 chunks per plane

    __shared__ __align__(16) ushort_t sBh[2][ROWS * BSTR];
    __shared__ __align__(16) ushort_t sBl[2][ROWS * BSTR];

    const int tid  = threadIdx.x;
    const int lane = tid & 63;
    const int wid  = tid >> 6;
    const int col  = lane & 15;
    const int quad = lane >> 4;

    const int mBase  = blockIdx.x * 256 + wid * 64;   // 4 m-tiles per wave
    const int ntBase = blockIdx.y * NT0;

    // per-mt A element base from valid-m -> (b, oy, ox)
    int aBase[4];
#pragma unroll
    for (int mt = 0; mt < 4; ++mt) {
        int mm = mBase + mt * 16 + col;
        if (mm >= Mtotal) mm = Mtotal - 1;            // clamped lanes discarded at store
        const int b   = mm / HoWo;
        const int pos = mm - b * HoWo;
        const int oy  = pos / Wo;
        const int ox  = pos - oy * Wo;
        aBase[mt] = (b * HW + oy * W + ox) * CI;
    }

    f32x4 acc[4][NT0];
#pragma unroll
    for (int mt = 0; mt < 4; ++mt)
#pragma unroll
        for (int nt = 0; nt < NT0; ++nt) acc[mt][nt] = (f32x4){0.f, 0.f, 0.f, 0.f};

    // slab copy: one bf16x8 per thread per plane (CHUNKS <= 256)
    auto loadSlab = [&](int ks, int buf) {
        const int tap0 = ks * TKS;
        for (int i = tid; i < CHUNKS; i += 256) {
            const int row = i / CH8;
            const int c8  = i - row * CH8;
            const int t   = row / (NT0 * 16);
            const int nn  = row - t * (NT0 * 16);
            int n = ntBase * 16 + nn;
            if (n > NPAD - 1) n = NPAD - 1;           // clamped rows unused by MFMA
            const int g = ((tap0 + t) * NPAD + n) * CI + c8 * 8;
            *(bf16x8*)(sBh[buf] + row * BSTR + c8 * 8) = *(const bf16x8*)(Bhi + g);
            *(bf16x8*)(sBl[buf] + row * BSTR + c8 * 8) = *(const bf16x8*)(Blo + g);
        }
    };

    loadSlab(0, 0);
    __syncthreads();

#pragma unroll
    for (int ks = 0; ks < KSTEPS; ++ks) {
        if (ks + 1 < KSTEPS) loadSlab(ks + 1, (ks + 1) & 1);

        const int k0   = ks * 32 + quad * 8;
        const int tap  = k0 / CI;
        const int tloc = tap - ks * TKS;
        const int ci   = k0 - tap * CI;
        const int dkk  = (tap / K) * W + (tap - (tap / K) * K);

        bf16x8 ah[4], al[4];
#pragma unroll
        for (int mt = 0; mt < 4; ++mt) {
            const int aoff = aBase[mt] + dkk * CI + ci;
            ah[mt] = *(const bf16x8*)(Xhi + aoff);
            al[mt] = *(const bf16x8*)(Xlo + aoff);
        }
        const ushort_t* __restrict__ bhp = sBh[ks & 1];
        const ushort_t* __restrict__ blp = sBl[ks & 1];
#pragma unroll
        for (int nt = 0; nt < NT0; ++nt) {
            const int ntg = ntBase + nt;
            if (ntg < NTTOT) {
                const int lrow = ((tloc * NT0 + nt) * 16 + col) * BSTR + ci;
                const bf16x8 bh = *(const bf16x8*)(bhp + lrow);
                const bf16x8 bl = *(const bf16x8*)(blp + lrow);
#pragma unroll
                for (int mt = 0; mt < 4; ++mt) {
                    acc[mt][nt] = __builtin_amdgcn_mfma_f32_16x16x32_bf16(ah[mt], bh, acc[mt][nt], 0, 0, 0);
                    acc[mt][nt] = __builtin_amdgcn_mfma_f32_16x16x32_bf16(al[mt], bh, acc[mt][nt], 0, 0, 0);
                    acc[mt][nt] = __builtin_amdgcn_mfma_f32_16x16x32_bf16(ah[mt], bl, acc[mt][nt], 0, 0, 0);
                }
            }
        }
        __syncthreads();
    }

#pragma unroll
    for (int mt = 0; mt < 4; ++mt) {
#pragma unroll
        for (int nt = 0; nt < NT0; ++nt) {
            const int ntg = ntBase + nt;
            const int n   = ntg * 16 + col;
            if (ntg < NTTOT && n < OC) {
                const float bv = bias[n];
#pragma unroll
                for (int r = 0; r < 4; ++r) {
                    const int m = mBase + mt * 16 + quad * 4 + r;
                    if (m < Mtotal) {
                        const int b   = m / HoWo;
                        const int pos = m - b * HoWo;
                        out[((size_t)b * OC + n) * HoWo + pos] = acc[mt][nt][r] + bv;
                    }
                }
            }
        }
    }
}

// ---------------------------------------------------------------------------
// MFMA deformable conv (stages 2-5). Unchanged from R10.
// ---------------------------------------------------------------------------
template<int K, int CI, int CO, int H, int W, int Ho, int Wo, bool RELU,
         int MT, int TPAD>
__global__ __launch_bounds__(MT * 64)
void deform_mfma(const float* __restrict__ x, const float* __restrict__ off,
                 const ushort_t* __restrict__ Bph, const ushort_t* __restrict__ Bpl,
                 const float* __restrict__ bias, float* __restrict__ out)
{
    constexpr int KK     = K * K;
    constexpr int HW     = H * W;
    constexpr int HoWo   = Ho * Wo;
    constexpr int NPASS  = CI / 8;
    constexpr int NT     = (CO + 15) / 16;
    constexpr int NPAD   = NT * 16;
    constexpr int STRIDE = 12;
    constexpr int nMB    = (HoWo + MT * 16 - 1) / (MT * 16);
    constexpr int THREADS = MT * 64;
    __shared__ __align__(16) float tile[HW * STRIDE];

    const int b    = blockIdx.x / nMB;
    const int mb   = blockIdx.x - b * nMB;
    const int tid  = threadIdx.x;
    const int wid  = tid >> 6;
    const int lane = tid & 63;
    const int col  = lane & 15;
    const int quad = lane >> 4;

    const int pixel0 = (mb * MT + wid) * 16;
    const int s      = pixel0 + col;
    const bool am    = (s < HoWo);
    const int oy = s / Wo, ox = s - oy * Wo;

    const float* offB = off + (size_t)b * 2 * KK * HoWo;

    f32x4 acc[NT];
#pragma unroll
    for (int nt = 0; nt < NT; ++nt) acc[nt] = (f32x4){0.f, 0.f, 0.f, 0.f};

    for (int pass = 0; pass < NPASS; ++pass) {
        const int cbase = pass * 8;
        __syncthreads();
        for (int pos = tid; pos < HW; pos += THREADS) {
#pragma unroll
            for (int c = 0; c < 8; ++c)
                tile[pos * STRIDE + c] = x[((size_t)b * CI + (cbase + c)) * HW + pos];
        }
        __syncthreads();

#pragma unroll
        for (int tg = 0; tg < TPAD / 4; ++tg) {
            const int tap = tg * 4 + quad;
            bf16x8 ahi = (bf16x8){0,0,0,0,0,0,0,0};
            bf16x8 alo = (bf16x8){0,0,0,0,0,0,0,0};

            if (am && tap < KK) {
                const float dy = offB[(size_t)(2 * tap + 0) * HoWo + s];
                const float dx = offB[(size_t)(2 * tap + 1) * HoWo + s];
                const float py = (float)(tap / K + oy) + dy;
                const float px = (float)(tap % K + ox) + dx;
                const float y0f = floorf(py), x0f = floorf(px);
                const float wy = py - y0f, wx = px - x0f;
                const int y0 = (int)y0f, x0 = (int)x0f;
                const int y1 = y0 + 1,   x1 = x0 + 1;

                const float m00 = (y0 >= 0 && y0 < H && x0 >= 0 && x0 < W) ? 1.f : 0.f;
                const float m01 = (y0 >= 0 && y0 < H && x1 >= 0 && x1 < W) ? 1.f : 0.f;
                const float m10 = (y1 >= 0 && y1 < H && x0 >= 0 && x0 < W) ? 1.f : 0.f;
                const float m11 = (y1 >= 0 && y1 < H && x1 >= 0 && x1 < W) ? 1.f : 0.f;

                const float w00 = (1.f - wy) * (1.f - wx) * m00;
                const float w01 = (1.f - wy) * wx         * m01;
                const float w10 = wy         * (1.f - wx) * m10;
                const float w11 = wy         * wx         * m11;

                const int y0c = min(max(y0, 0), H - 1), y1c = min(max(y1, 0), H - 1);
                const int x0c = min(max(x0, 0), W - 1), x1c = min(max(x1, 0), W - 1);
                const int i00 = (y0c * W + x0c) * STRIDE;
                const int i01 = (y0c * W + x1c) * STRIDE;
                const int i10 = (y1c * W + x0c) * STRIDE;
                const int i11 = (y1c * W + x1c) * STRIDE;

                float v00[8], v01[8], v10[8], v11[8];
                *(f32x4*)(v00) = *(const f32x4*)(tile + i00); *(f32x4*)(v00 + 4) = *(const f32x4*)(tile + i00 + 4);
                *(f32x4*)(v01) = *(const f32x4*)(tile + i01); *(f32x4*)(v01 + 4) = *(const f32x4*)(tile + i01 + 4);
                *(f32x4*)(v10) = *(const f32x4*)(tile + i10); *(f32x4*)(v10 + 4) = *(const f32x4*)(tile + i10 + 4);
                *(f32x4*)(v11) = *(const f32x4*)(tile + i11); *(f32x4*)(v11 + 4) = *(const f32x4*)(tile + i11 + 4);
#pragma unroll
                for (int j = 0; j < 8; ++j) {
                    const float sv = fmaf(v11[j], w11, fmaf(v10[j], w10,
                                     fmaf(v01[j], w01, v00[j] * w00)));
                    const ushort_t h = bf16_trunc(sv);
                    ahi[j] = (short)h;
                    alo[j] = (short)bf16_trunc(sv - bf16_to_f(h));
                }
            }

            const size_t kslot = (size_t)(pass * TPAD + tap);
#pragma unroll
            for (int nt = 0; nt < NT; ++nt) {
                const bf16x8 bh = *(const bf16x8*)(Bph + (kslot * NPAD + nt * 16 + col) * 8);
                const bf16x8 bl = *(const bf16x8*)(Bpl + (kslot * NPAD + nt * 16 + col) * 8);
                acc[nt] = __builtin_amdgcn_mfma_f32_16x16x32_bf16(ahi, bh, acc[nt], 0, 0, 0);
                acc[nt] = __builtin_amdgcn_mfma_f32_16x16x32_bf16(alo, bh, acc[nt], 0, 0, 0);
                acc[nt] = __builtin_amdgcn_mfma_f32_16x16x32_bf16(ahi, bl, acc[nt], 0, 0, 0);
            }
        }
    }

#pragma unroll
    for (int nt = 0; nt < NT; ++nt) {
        const int n = nt * 16 + col;
        if (n < CO) {
            const float bv = bias[n];
#pragma unroll
            for (int r = 0; r < 4; ++r) {
                const int m = pixel0 + quad * 4 + r;
                if (m < HoWo) {
                    float v = acc[nt][r] + bv;
                    if (RELU) v = fmaxf(v, 0.f);
                    out[((size_t)b * CO + n) * HoWo + m] = v;
                }
            }
        }
    }
}

// ---------------------------------------------------------------------------
// Scalar LDS deform (stages 1 and 6).
// ---------------------------------------------------------------------------
template<int K, int CI, int CO, int H, int W, int Ho, int Wo, bool RELU,
         int CSPLIT, int STRIDE, int THREADS, int SPLIT>
__global__ __launch_bounds__(THREADS)
void deform_lds(const float* __restrict__ x, const float* __restrict__ off,
                const float* __restrict__ w, const float* __restrict__ bias,
                float* __restrict__ out)
{
    constexpr int KK    = K * K;
    constexpr int HW    = H * W;
    constexpr int HoWo  = Ho * Wo;
    constexpr int NPASS = CI / CSPLIT;
    constexpr int CHUNK = (HoWo + SPLIT - 1) / SPLIT;
    static_assert(CHUNK <= THREADS, "chunk must fit in one block");
    __shared__ __align__(16) float tile[HW * STRIDE];

    const int b   = blockIdx.x / SPLIT;
    const int sp  = blockIdx.x - b * SPLIT;
    const int tid = threadIdx.x;
    const int s   = sp * CHUNK + tid;
    const bool active = (tid < CHUNK) && (s < HoWo);

    const int oy = s / Wo, ox = s - oy * Wo;
    const float* offp = off + ((size_t)b * 2 * KK) * HoWo + s;

    float acc[CO];
#pragma unroll
    for (int o = 0; o < CO; ++o) acc[o] = 0.f;

    for (int pass = 0; pass < NPASS; ++pass) {
        const int cbase = pass * CSPLIT;
        __syncthreads();
        for (int pos = tid; pos < HW; pos += THREADS) {
#pragma unroll
            for (int c = 0; c < CSPLIT; ++c)
                tile[pos * STRIDE + c] = x[((size_t)b * CI + (cbase + c)) * HW + pos];
        }
        __syncthreads();

        if (active) {
            for (int kk = 0; kk < KK; ++kk) {
                const float dy = offp[(size_t)(2 * kk + 0) * HoWo];
                const float dx = offp[(size_t)(2 * kk + 1) * HoWo];
                const float py = (float)(kk / K + oy) + dy;
                const float px = (float)(kk % K + ox) + dx;
                const float y0f = floorf(py), x0f = floorf(px);
                const float wy = py - y0f, wx = px - x0f;
                const int y0 = (int)y0f, x0 = (int)x0f;
                const int y1 = y0 + 1,   x1 = x0 + 1;

                const float m00 = (y0 >= 0 && y0 < H && x0 >= 0 && x0 < W) ? 1.f : 0.f;
                const float m01 = (y0 >= 0 && y0 < H && x1 >= 0 && x1 < W) ? 1.f : 0.f;
                const float m10 = (y1 >= 0 && y1 < H && x0 >= 0 && x0 < W) ? 1.f : 0.f;
                const float m11 = (y1 >= 0 && y1 < H && x1 >= 0 && x1 < W) ? 1.f : 0.f;

                const float w00 = (1.f - wy) * (1.f - wx) * m00;
                const float w01 = (1.f - wy) * wx         * m01;
                const float w10 = wy         * (1.f - wx) * m10;
                const float w11 = wy         * wx         * m11;

                const int y0c = min(max(y0, 0), H - 1), y1c = min(max(y1, 0), H - 1);
                const int x0c = min(max(x0, 0), W - 1), x1c = min(max(x1, 0), W - 1);
                const int i00 = (y0c * W + x0c) * STRIDE;
                const int i01 = (y0c * W + x1c) * STRIDE;
                const int i10 = (y1c * W + x0c) * STRIDE;
                const int i11 = (y1c * W + x1c) * STRIDE;

                if constexpr (CSPLIT % 4 == 0) {
#pragma unroll
                    for (int cg = 0; cg < CSPLIT; cg += 4) {
                        const f32x4 v00 = *(const f32x4*)(tile + i00 + cg);
                        const f32x4 v01 = *(const f32x4*)(tile + i01 + cg);
                        const f32x4 v10 = *(const f32x4*)(tile + i10 + cg);
                        const f32x4 v11 = *(const f32x4*)(tile + i11 + cg);
#pragma unroll
                        for (int j = 0; j < 4; ++j) {
                            const float sv = fmaf(v11[j], w11, fmaf(v10[j], w10,
                                             fmaf(v01[j], w01, v00[j] * w00)));
#pragma unroll
                            for (int o = 0; o < CO; ++o)
                                acc[o] = fmaf(sv, w[(size_t)(o * CI + cbase + cg + j) * KK + kk], acc[o]);
                        }
                    }
                } else {
                    const float sv = fmaf(tile[i11], w11, fmaf(tile[i10], w10,
                                     fmaf(tile[i01], w01, tile[i00] * w00)));
#pragma unroll
                    for (int o = 0; o < CO; ++o)
                        acc[o] = fmaf(sv, w[(size_t)(o * CI + cbase) * KK + kk], acc[o]);
                }
            }
        }
    }

    if (active) {
        float* op = out + ((size_t)b * CO) * HoWo + s;
#pragma unroll
        for (int o = 0; o < CO; ++o) {
            float v = acc[o] + bias[o];
            if (RELU) v = fmaxf(v, 0.f);
            op[(size_t)o * HoWo] = v;
        }
    }
}

// ---------------------------------------------------------------------------
// Register-tiled direct VALID conv (stages 1 and 6 offset convs).
// ---------------------------------------------------------------------------
template<int K, int CI, int NOC, int OC, int H, int W, int Ho, int Wo, int PIX>
__global__ __launch_bounds__(256)
void conv_tile(const float* __restrict__ x, const float* __restrict__ w,
               const float* __restrict__ bias, float* __restrict__ out)
{
    constexpr int KK   = K * K;
    constexpr int HoWo = Ho * Wo;
    constexpr int WoG  = (Wo + PIX - 1) / PIX;
    constexpr int G    = Ho * WoG;
    constexpr int XV   = PIX + K - 1;

    const int oc0   = blockIdx.y * NOC;
    const int g_all = blockIdx.x * 256 + threadIdx.x;
    const int b     = g_all / G;
    const int g     = g_all - b * G;
    const int oy    = g / WoG;
    const int ox0   = (g - oy * WoG) * PIX;

    const float* xbp = x + (b * CI) * (H * W) + oy * W + ox0;
    const float* wp  = w + oc0 * (CI * KK);

    float acc[PIX][NOC];
#pragma unroll
    for (int p = 0; p < PIX; ++p)
#pragma unroll
        for (int j = 0; j < NOC; ++j) acc[p][j] = bias[oc0 + j];

    const int lim = W - 1 - ox0;

    for (int ci = 0; ci < CI; ++ci) {
        const float* xc = xbp + ci * (H * W);
#pragma unroll
        for (int ky = 0; ky < K; ++ky) {
            float xv[XV];
#pragma unroll
            for (int i = 0; i < XV; ++i) {
                const int off = (i <= lim) ? i : lim;
                xv[i] = xc[ky * W + off];
            }
#pragma unroll
            for (int kx = 0; kx < K; ++kx) {
#pragma unroll
                for (int p = 0; p < PIX; ++p) {
                    const float v = xv[p + kx];
#pragma unroll
                    for (int j = 0; j < NOC; ++j)
                        acc[p][j] = fmaf(v, wp[j * (CI * KK) + ci * KK + ky * K + kx], acc[p][j]);
                }
            }
        }
    }

    float* op = out + (b * OC + oc0) * HoWo + oy * Wo + ox0;
#pragma unroll
    for (int p = 0; p < PIX; ++p) {
        if (ox0 + p < Wo) {
#pragma unroll
            for (int j = 0; j < NOC; ++j) op[j * HoWo + p] = acc[p][j];
        }
    }
}

__global__ void fc_kernel(const float* __restrict__ h, const float* __restrict__ w,
                          const float* __restrict__ bias, float* __restrict__ out,
                          int B, int IN, int OUT, int relu)
{
    const int idx = blockIdx.x * blockDim.x + threadIdx.x;
    if (idx >= B * OUT) return;
    const int b = idx / OUT;
    const int j = idx - b * OUT;
    const float* hb = h + b * IN;
    const float* wj = w + j * IN;
    float acc = bias[j];
    for (int i = 0; i < IN; ++i) acc = fmaf(hb[i], wj[i], acc);
    if (relu) acc = fmaxf(acc, 0.f);
    out[idx] = acc;
}

// ---------------------------------------------------------------------------
extern "C" void kernel_launch(void* const* d_in, const int* in_sizes, int n_in,
                              void* d_out, int out_size, void* d_ws, size_t ws_size,
                              hipStream_t stream)
{
    const int B = 512;
    const float* x = (const float*)d_in[0];
    const float *ow[6], *ob[6], *w[6], *bi[6];
    for (int i = 0; i < 6; ++i) {
        ow[i] = (const float*)d_in[1 + 4 * i];
        ob[i] = (const float*)d_in[2 + 4 * i];
        w[i]  = (const float*)d_in[3 + 4 * i];
        bi[i] = (const float*)d_in[4 + 4 * i];
    }
    const float* fc1w = (const float*)d_in[25];
    const float* fc1b = (const float*)d_in[26];
    const float* fc2w = (const float*)d_in[27];
    const float* fc2b = (const float*)d_in[28];
    float* out = (float*)d_out;

    float* P   = (float*)d_ws;        // 14M floats
    float* Q   = P  + 14000000;       // 14M floats
    float* OFF = Q  + 14000000;       // 18.2M floats
    float* Z   = OFF + 18200000;      // fc intermediate
    ushort_t* WBhi = (ushort_t*)(Z + 200000);   // conv_mfma weights
    ushort_t* WBlo = WBhi + 200000;
    ushort_t* WDhi = WBlo + 200000;             // deform_mfma weights
    ushort_t* WDlo = WDhi + 200000;

    const dim3 blk(256);
    #define GRIDT(Ho, Wo, PIX, NG) dim3((B * (Ho) * (((Wo) + (PIX) - 1) / (PIX)) + 255) / 256, (NG), 1)
    #define CEILDIV(a, b) (((a) + (b) - 1) / (b))

    // ---- stage 1: input x (CI=1). conv_tile -> OFF; deform_lds -> P ----
    conv_tile<3, 1, 6, 18, 33, 33, 31, 31, 4><<<GRIDT(31, 31, 4, 3), blk, 0, stream>>>(x, ow[0], ob[0], OFF);
    deform_lds<3, 1, 16, 33, 33, 31, 31, true, 1, 1, 512, 2><<<dim3(B * 2), dim3(512), 0, stream>>>(x, OFF, w[0], bi[0], P);

    // ---- stage 2: CI=16 K=3 31x31->29x29 OC(off)=18 CO=32. P -> Q ----
    {
        const int Mc = B * 961;           // convert: all input positions
        const int Mv = B * 841;           // conv: valid outputs only
        ushort_t* Xhi = (ushort_t*)Q;
        ushort_t* Xlo = Xhi + (size_t)(Mc + 2048) * 16;
        convert_nhwc<16, 961><<<CEILDIV(Mc, 256), blk, 0, stream>>>(P, Xhi, Xlo, Mc);
        wprep<16, 9, 10, 32, 18><<<CEILDIV(10 * 32 * 16, 256), blk, 0, stream>>>(ow[1], WBhi, WBlo);
        conv_mfma<16, 3, 31, 31, 29, 29, 18, 2, 2, 5><<<dim3(CEILDIV(Mv, 256), 1), blk, 0, stream>>>(Xhi, Xlo, WBhi, WBlo, ob[1], OFF, Mv);
        wprep_d<16, 9, 12, 32, 32><<<CEILDIV(2 * 12 * 32 * 8, 256), blk, 0, stream>>>(w[1], WDhi, WDlo);
        deform_mfma<3, 16, 32, 31, 31, 29, 29, true, 8, 12><<<dim3(B * 7), dim3(512), 0, stream>>>(P, OFF, WDhi, WDlo, bi[1], Q);
    }
    // ---- stage 3: CI=32 K=5 29x29->25x25 OC(off)=50 CO=16 (no relu). Q -> P ----
    {
        const int Mc = B * 841;
        const int Mv = B * 625;
        ushort_t* Xhi = (ushort_t*)P;
        ushort_t* Xlo = Xhi + (size_t)(Mc + 2048) * 32;
        convert_nhwc<32, 841><<<CEILDIV(Mc, 256), blk, 0, stream>>>(Q, Xhi, Xlo, Mc);
        wprep<32, 25, 25, 64, 50><<<CEILDIV(25 * 64 * 32, 256), blk, 0, stream>>>(ow[2], WBhi, WBlo);
        conv_mfma<32, 5, 29, 29, 25, 25, 50, 4, 4, 25><<<dim3(CEILDIV(Mv, 256), 1), blk, 0, stream>>>(Xhi, Xlo, WBhi, WBlo, ob[2], OFF, Mv);
        wprep_d<32, 25, 28, 16, 16><<<CEILDIV(4 * 28 * 16 * 8, 256), blk, 0, stream>>>(w[2], WDhi, WDlo);
        deform_mfma<5, 32, 16, 29, 29, 25, 25, false, 8, 28><<<dim3(B * 5), dim3(512), 0, stream>>>(Q, OFF, WDhi, WDlo, bi[2], P);
    }
    // ---- stage 4: CI=16 K=7 25x25->19x19 OC(off)=98 CO=16. P -> Q ----
    {
        const int Mc = B * 625;
        const int Mv = B * 361;
        ushort_t* Xhi = (ushort_t*)Q;
        ushort_t* Xlo = Xhi + (size_t)(Mc + 2048) * 16;
        convert_nhwc<16, 625><<<CEILDIV(Mc, 256), blk, 0, stream>>>(P, Xhi, Xlo, Mc);
        wprep<16, 49, 50, 112, 98><<<CEILDIV(50 * 112 * 16, 256), blk, 0, stream>>>(ow[3], WBhi, WBlo);
        conv_mfma<16, 7, 25, 25, 19, 19, 98, 7, 4, 25><<<dim3(CEILDIV(Mv, 256), 2), blk, 0, stream>>>(Xhi, Xlo, WBhi, WBlo, ob[3], OFF, Mv);
        wprep_d<16, 49, 52, 16, 16><<<CEILDIV(2 * 52 * 16 * 8, 256), blk, 0, stream>>>(w[3], WDhi, WDlo);
        deform_mfma<7, 16, 16, 25, 25, 19, 19, true, 8, 52><<<dim3(B * 3), dim3(512), 0, stream>>>(P, OFF, WDhi, WDlo, bi[3], Q);
    }
    // ---- stage 5: CI=16 K=5 19x19->15x15 OC(off)=50 CO=8. Q -> P ----
    {
        const int Mc = B * 361;
        const int Mv = B * 225;
        ushort_t* Xhi = (ushort_t*)P;
        ushort_t* Xlo = Xhi + (size_t)(Mc + 2048) * 16;
        convert_nhwc<16, 361><<<CEILDIV(Mc, 256), blk, 0, stream>>>(Q, Xhi, Xlo, Mc);
        wprep<16, 25, 26, 64, 50><<<CEILDIV(26 * 64 * 16, 256), blk, 0, stream>>>(ow[4], WBhi, WBlo);
        conv_mfma<16, 5, 19, 19, 15, 15, 50, 4, 4, 13><<<dim3(CEILDIV(Mv, 256), 1), blk, 0, stream>>>(Xhi, Xlo, WBhi, WBlo, ob[4], OFF, Mv);
        wprep_d<16, 25, 28, 16, 8><<<CEILDIV(2 * 28 * 16 * 8, 256), blk, 0, stream>>>(w[4], WDhi, WDlo);
        deform_mfma<5, 16, 8, 19, 19, 15, 15, true, 4, 28><<<dim3(B * 4), dim3(256), 0, stream>>>(Q, OFF, WDhi, WDlo, bi[4], P);
    }
    // ---- stage 6: CI=8 K=3 15x15->13x13 CO=4. P -> Q ----
    conv_tile<3, 8, 6, 18, 15, 15, 13, 13, 4><<<GRIDT(13, 13, 4, 3), blk, 0, stream>>>(P, ow[5], ob[5], OFF);
    deform_lds<3, 8, 4, 15, 15, 13, 13, true, 8, 12, 192, 1><<<dim3(B), dim3(192), 0, stream>>>(P, OFF, w[5], bi[5], Q);

    // ---- FC head (reads Q = 512 x 4 x 13 x 13) ----
    fc_kernel<<<dim3(CEILDIV(B * 256, 256)), blk, 0, stream>>>(Q, fc1w, fc1b, Z, B, 676, 256, 1);
    fc_kernel<<<dim3(CEILDIV(B * 10, 256)), blk, 0, stream>>>(Z, fc2w, fc2b, out, B, 256, 10, 0);

    #undef GRIDT
    #undef CEILDIV
}

// Round 12
// 976.310 us; speedup vs baseline: 3.9114x; 1.1314x over previous
//
#include <hip/hip_runtime.h>

typedef __attribute__((ext_vector_type(8))) short bf16x8;
typedef __attribute__((ext_vector_type(4))) float f32x4;
typedef unsigned short ushort_t;

__device__ inline ushort_t bf16_trunc(float f) { return (ushort_t)(__float_as_uint(f) >> 16); }
__device__ inline float bf16_to_f(ushort_t u) { return __uint_as_float(((unsigned int)u) << 16); }

// ---------------------------------------------------------------------------
// NCHW fp32 -> NHWC bf16 hi/lo planes (A-operand for conv_mfma).
// ---------------------------------------------------------------------------
template<int CI, int HW>
__global__ __launch_bounds__(256)
void convert_nhwc(const float* __restrict__ x, ushort_t* __restrict__ hi,
                  ushort_t* __restrict__ lo, int Mtotal)
{
    const int m = blockIdx.x * 256 + threadIdx.x;
    if (m >= Mtotal) return;
    const int b = m / HW, pos = m - b * HW;
    const float* xp = x + (size_t)b * CI * HW + pos;
    ushort_t* hp = hi + (size_t)m * CI;
    ushort_t* lp = lo + (size_t)m * CI;
#pragma unroll
    for (int ci = 0; ci < CI; ++ci) {
        const float v = xp[(size_t)ci * HW];
        const ushort_t h = bf16_trunc(v);
        hp[ci] = h;
        lp[ci] = bf16_trunc(v - bf16_to_f(h));
    }
}

// ---------------------------------------------------------------------------
// Weight prep for conv_mfma: OIHW fp32 -> [kk][n][ci] hi/lo, zero-padded.
// ---------------------------------------------------------------------------
template<int CI, int KK, int KKPAD, int NPAD, int OC>
__global__ __launch_bounds__(256)
void wprep(const float* __restrict__ w, ushort_t* __restrict__ bhi, ushort_t* __restrict__ blo)
{
    const int idx = blockIdx.x * 256 + threadIdx.x;
    if (idx >= KKPAD * NPAD * CI) return;
    const int kk  = idx / (NPAD * CI);
    const int rem = idx - kk * (NPAD * CI);
    const int n   = rem / CI;
    const int ci  = rem - n * CI;
    const float v = (kk < KK && n < OC) ? w[((size_t)n * CI + ci) * KK + kk] : 0.f;
    const ushort_t h = bf16_trunc(v);
    bhi[idx] = h;
    blo[idx] = bf16_trunc(v - bf16_to_f(h));
}

// ---------------------------------------------------------------------------
// Weight prep for deform_mfma: pack [kslot = pass*TPAD+tap][n][j=ci_in_pass].
// ---------------------------------------------------------------------------
template<int CI, int KK, int TPAD, int NPAD, int OC>
__global__ __launch_bounds__(256)
void wprep_d(const float* __restrict__ w, ushort_t* __restrict__ bhi, ushort_t* __restrict__ blo)
{
    constexpr int NPASS = (CI + 7) / 8;
    constexpr int TOTAL = NPASS * TPAD * NPAD * 8;
    const int idx = blockIdx.x * 256 + threadIdx.x;
    if (idx >= TOTAL) return;
    const int j     = idx & 7;
    const int n     = (idx >> 3) % NPAD;
    const int kslot = (idx >> 3) / NPAD;
    const int pass  = kslot / TPAD;
    const int tap   = kslot - pass * TPAD;
    const int ci    = pass * 8 + j;
    const float v = (tap < KK && n < OC && ci < CI) ? w[((size_t)n * CI + ci) * KK + tap] : 0.f;
    const ushort_t h = bf16_trunc(v);
    bhi[idx] = h;
    blo[idx] = bf16_trunc(v - bf16_to_f(h));
}

// ---------------------------------------------------------------------------
// MFMA implicit-im2col conv. Valid-m indexing + double-buffered LDS B slab.
// ---------------------------------------------------------------------------
template<int CI, int K, int H, int W, int Ho, int Wo, int OC, int NTTOT, int NT0, int KSTEPS>
__global__ __launch_bounds__(256)
void conv_mfma(const ushort_t* __restrict__ Xhi, const ushort_t* __restrict__ Xlo,
               const ushort_t* __restrict__ Bhi, const ushort_t* __restrict__ Blo,
               const float* __restrict__ bias, float* __restrict__ out, int Mtotal)
{
    constexpr int NPAD = NTTOT * 16;
    constexpr int HW   = H * W;
    constexpr int HoWo = Ho * Wo;
    constexpr int TKS  = 32 / CI;
    constexpr int ROWS = TKS * NT0 * 16;
    constexpr int BSTR = CI + 8;
    constexpr int CH8  = CI / 8;
    constexpr int CHUNKS = ROWS * CH8;

    __shared__ __align__(16) ushort_t sBh[2][ROWS * BSTR];
    __shared__ __align__(16) ushort_t sBl[2][ROWS * BSTR];

    const int tid  = threadIdx.x;
    const int lane = tid & 63;
    const int wid  = tid >> 6;
    const int col  = lane & 15;
    const int quad = lane >> 4;

    const int mBase  = blockIdx.x * 256 + wid * 64;
    const int ntBase = blockIdx.y * NT0;

    int aBase[4];
#pragma unroll
    for (int mt = 0; mt < 4; ++mt) {
        int mm = mBase + mt * 16 + col;
        if (mm >= Mtotal) mm = Mtotal - 1;
        const int b   = mm / HoWo;
        const int pos = mm - b * HoWo;
        const int oy  = pos / Wo;
        const int ox  = pos - oy * Wo;
        aBase[mt] = (b * HW + oy * W + ox) * CI;
    }

    f32x4 acc[4][NT0];
#pragma unroll
    for (int mt = 0; mt < 4; ++mt)
#pragma unroll
        for (int nt = 0; nt < NT0; ++nt) acc[mt][nt] = (f32x4){0.f, 0.f, 0.f, 0.f};

    auto loadSlab = [&](int ks, int buf) {
        const int tap0 = ks * TKS;
        for (int i = tid; i < CHUNKS; i += 256) {
            const int row = i / CH8;
            const int c8  = i - row * CH8;
            const int t   = row / (NT0 * 16);
            const int nn  = row - t * (NT0 * 16);
            int n = ntBase * 16 + nn;
            if (n > NPAD - 1) n = NPAD - 1;
            const int g = ((tap0 + t) * NPAD + n) * CI + c8 * 8;
            *(bf16x8*)(sBh[buf] + row * BSTR + c8 * 8) = *(const bf16x8*)(Bhi + g);
            *(bf16x8*)(sBl[buf] + row * BSTR + c8 * 8) = *(const bf16x8*)(Blo + g);
        }
    };

    loadSlab(0, 0);
    __syncthreads();

#pragma unroll
    for (int ks = 0; ks < KSTEPS; ++ks) {
        if (ks + 1 < KSTEPS) loadSlab(ks + 1, (ks + 1) & 1);

        const int k0   = ks * 32 + quad * 8;
        const int tap  = k0 / CI;
        const int tloc = tap - ks * TKS;
        const int ci   = k0 - tap * CI;
        const int dkk  = (tap / K) * W + (tap - (tap / K) * K);

        bf16x8 ah[4], al[4];
#pragma unroll
        for (int mt = 0; mt < 4; ++mt) {
            const int aoff = aBase[mt] + dkk * CI + ci;
            ah[mt] = *(const bf16x8*)(Xhi + aoff);
            al[mt] = *(const bf16x8*)(Xlo + aoff);
        }
        const ushort_t* __restrict__ bhp = sBh[ks & 1];
        const ushort_t* __restrict__ blp = sBl[ks & 1];
#pragma unroll
        for (int nt = 0; nt < NT0; ++nt) {
            const int ntg = ntBase + nt;
            if (ntg < NTTOT) {
                const int lrow = ((tloc * NT0 + nt) * 16 + col) * BSTR + ci;
                const bf16x8 bh = *(const bf16x8*)(bhp + lrow);
                const bf16x8 bl = *(const bf16x8*)(blp + lrow);
#pragma unroll
                for (int mt = 0; mt < 4; ++mt) {
                    acc[mt][nt] = __builtin_amdgcn_mfma_f32_16x16x32_bf16(ah[mt], bh, acc[mt][nt], 0, 0, 0);
                    acc[mt][nt] = __builtin_amdgcn_mfma_f32_16x16x32_bf16(al[mt], bh, acc[mt][nt], 0, 0, 0);
                    acc[mt][nt] = __builtin_amdgcn_mfma_f32_16x16x32_bf16(ah[mt], bl, acc[mt][nt], 0, 0, 0);
                }
            }
        }
        __syncthreads();
    }

#pragma unroll
    for (int mt = 0; mt < 4; ++mt) {
#pragma unroll
        for (int nt = 0; nt < NT0; ++nt) {
            const int ntg = ntBase + nt;
            const int n   = ntg * 16 + col;
            if (ntg < NTTOT && n < OC) {
                const float bv = bias[n];
#pragma unroll
                for (int r = 0; r < 4; ++r) {
                    const int m = mBase + mt * 16 + quad * 4 + r;
                    if (m < Mtotal) {
                        const int b   = m / HoWo;
                        const int pos = m - b * HoWo;
                        out[((size_t)b * OC + n) * HoWo + pos] = acc[mt][nt][r] + bv;
                    }
                }
            }
        }
    }
}

// ---------------------------------------------------------------------------
// MFMA deformable conv (stages 2-5). Unchanged from R11.
// ---------------------------------------------------------------------------
template<int K, int CI, int CO, int H, int W, int Ho, int Wo, bool RELU,
         int MT, int TPAD>
__global__ __launch_bounds__(MT * 64)
void deform_mfma(const float* __restrict__ x, const float* __restrict__ off,
                 const ushort_t* __restrict__ Bph, const ushort_t* __restrict__ Bpl,
                 const float* __restrict__ bias, float* __restrict__ out)
{
    constexpr int KK     = K * K;
    constexpr int HW     = H * W;
    constexpr int HoWo   = Ho * Wo;
    constexpr int NPASS  = CI / 8;
    constexpr int NT     = (CO + 15) / 16;
    constexpr int NPAD   = NT * 16;
    constexpr int STRIDE = 12;
    constexpr int nMB    = (HoWo + MT * 16 - 1) / (MT * 16);
    constexpr int THREADS = MT * 64;
    __shared__ __align__(16) float tile[HW * STRIDE];

    const int b    = blockIdx.x / nMB;
    const int mb   = blockIdx.x - b * nMB;
    const int tid  = threadIdx.x;
    const int wid  = tid >> 6;
    const int lane = tid & 63;
    const int col  = lane & 15;
    const int quad = lane >> 4;

    const int pixel0 = (mb * MT + wid) * 16;
    const int s      = pixel0 + col;
    const bool am    = (s < HoWo);
    const int oy = s / Wo, ox = s - oy * Wo;

    const float* offB = off + (size_t)b * 2 * KK * HoWo;

    f32x4 acc[NT];
#pragma unroll
    for (int nt = 0; nt < NT; ++nt) acc[nt] = (f32x4){0.f, 0.f, 0.f, 0.f};

    for (int pass = 0; pass < NPASS; ++pass) {
        const int cbase = pass * 8;
        __syncthreads();
        for (int pos = tid; pos < HW; pos += THREADS) {
#pragma unroll
            for (int c = 0; c < 8; ++c)
                tile[pos * STRIDE + c] = x[((size_t)b * CI + (cbase + c)) * HW + pos];
        }
        __syncthreads();

#pragma unroll
        for (int tg = 0; tg < TPAD / 4; ++tg) {
            const int tap = tg * 4 + quad;
            bf16x8 ahi = (bf16x8){0,0,0,0,0,0,0,0};
            bf16x8 alo = (bf16x8){0,0,0,0,0,0,0,0};

            if (am && tap < KK) {
                const float dy = offB[(size_t)(2 * tap + 0) * HoWo + s];
                const float dx = offB[(size_t)(2 * tap + 1) * HoWo + s];
                const float py = (float)(tap / K + oy) + dy;
                const float px = (float)(tap % K + ox) + dx;
                const float y0f = floorf(py), x0f = floorf(px);
                const float wy = py - y0f, wx = px - x0f;
                const int y0 = (int)y0f, x0 = (int)x0f;
                const int y1 = y0 + 1,   x1 = x0 + 1;

                const float m00 = (y0 >= 0 && y0 < H && x0 >= 0 && x0 < W) ? 1.f : 0.f;
                const float m01 = (y0 >= 0 && y0 < H && x1 >= 0 && x1 < W) ? 1.f : 0.f;
                const float m10 = (y1 >= 0 && y1 < H && x0 >= 0 && x0 < W) ? 1.f : 0.f;
                const float m11 = (y1 >= 0 && y1 < H && x1 >= 0 && x1 < W) ? 1.f : 0.f;

                const float w00 = (1.f - wy) * (1.f - wx) * m00;
                const float w01 = (1.f - wy) * wx         * m01;
                const float w10 = wy         * (1.f - wx) * m10;
                const float w11 = wy         * wx         * m11;

                const int y0c = min(max(y0, 0), H - 1), y1c = min(max(y1, 0), H - 1);
                const int x0c = min(max(x0, 0), W - 1), x1c = min(max(x1, 0), W - 1);
                const int i00 = (y0c * W + x0c) * STRIDE;
                const int i01 = (y0c * W + x1c) * STRIDE;
                const int i10 = (y1c * W + x0c) * STRIDE;
                const int i11 = (y1c * W + x1c) * STRIDE;

                float v00[8], v01[8], v10[8], v11[8];
                *(f32x4*)(v00) = *(const f32x4*)(tile + i00); *(f32x4*)(v00 + 4) = *(const f32x4*)(tile + i00 + 4);
                *(f32x4*)(v01) = *(const f32x4*)(tile + i01); *(f32x4*)(v01 + 4) = *(const f32x4*)(tile + i01 + 4);
                *(f32x4*)(v10) = *(const f32x4*)(tile + i10); *(f32x4*)(v10 + 4) = *(const f32x4*)(tile + i10 + 4);
                *(f32x4*)(v11) = *(const f32x4*)(tile + i11); *(f32x4*)(v11 + 4) = *(const f32x4*)(tile + i11 + 4);
#pragma unroll
                for (int j = 0; j < 8; ++j) {
                    const float sv = fmaf(v11[j], w11, fmaf(v10[j], w10,
                                     fmaf(v01[j], w01, v00[j] * w00)));
                    const ushort_t h = bf16_trunc(sv);
                    ahi[j] = (short)h;
                    alo[j] = (short)bf16_trunc(sv - bf16_to_f(h));
                }
            }

            const size_t kslot = (size_t)(pass * TPAD + tap);
#pragma unroll
            for (int nt = 0; nt < NT; ++nt) {
                const bf16x8 bh = *(const bf16x8*)(Bph + (kslot * NPAD + nt * 16 + col) * 8);
                const bf16x8 bl = *(const bf16x8*)(Bpl + (kslot * NPAD + nt * 16 + col) * 8);
                acc[nt] = __builtin_amdgcn_mfma_f32_16x16x32_bf16(ahi, bh, acc[nt], 0, 0, 0);
                acc[nt] = __builtin_amdgcn_mfma_f32_16x16x32_bf16(alo, bh, acc[nt], 0, 0, 0);
                acc[nt] = __builtin_amdgcn_mfma_f32_16x16x32_bf16(ahi, bl, acc[nt], 0, 0, 0);
            }
        }
    }

#pragma unroll
    for (int nt = 0; nt < NT; ++nt) {
        const int n = nt * 16 + col;
        if (n < CO) {
            const float bv = bias[n];
#pragma unroll
            for (int r = 0; r < 4; ++r) {
                const int m = pixel0 + quad * 4 + r;
                if (m < HoWo) {
                    float v = acc[nt][r] + bv;
                    if (RELU) v = fmaxf(v, 0.f);
                    out[((size_t)b * CO + n) * HoWo + m] = v;
                }
            }
        }
    }
}

// ---------------------------------------------------------------------------
// Scalar LDS deform (stages 1 and 6).
// ---------------------------------------------------------------------------
template<int K, int CI, int CO, int H, int W, int Ho, int Wo, bool RELU,
         int CSPLIT, int STRIDE, int THREADS, int SPLIT>
__global__ __launch_bounds__(THREADS)
void deform_lds(const float* __restrict__ x, const float* __restrict__ off,
                const float* __restrict__ w, const float* __restrict__ bias,
                float* __restrict__ out)
{
    constexpr int KK    = K * K;
    constexpr int HW    = H * W;
    constexpr int HoWo  = Ho * Wo;
    constexpr int NPASS = CI / CSPLIT;
    constexpr int CHUNK = (HoWo + SPLIT - 1) / SPLIT;
    static_assert(CHUNK <= THREADS, "chunk must fit in one block");
    __shared__ __align__(16) float tile[HW * STRIDE];

    const int b   = blockIdx.x / SPLIT;
    const int sp  = blockIdx.x - b * SPLIT;
    const int tid = threadIdx.x;
    const int s   = sp * CHUNK + tid;
    const bool active = (tid < CHUNK) && (s < HoWo);

    const int oy = s / Wo, ox = s - oy * Wo;
    const float* offp = off + ((size_t)b * 2 * KK) * HoWo + s;

    float acc[CO];
#pragma unroll
    for (int o = 0; o < CO; ++o) acc[o] = 0.f;

    for (int pass = 0; pass < NPASS; ++pass) {
        const int cbase = pass * CSPLIT;
        __syncthreads();
        for (int pos = tid; pos < HW; pos += THREADS) {
#pragma unroll
            for (int c = 0; c < CSPLIT; ++c)
                tile[pos * STRIDE + c] = x[((size_t)b * CI + (cbase + c)) * HW + pos];
        }
        __syncthreads();

        if (active) {
            for (int kk = 0; kk < KK; ++kk) {
                const float dy = offp[(size_t)(2 * kk + 0) * HoWo];
                const float dx = offp[(size_t)(2 * kk + 1) * HoWo];
                const float py = (float)(kk / K + oy) + dy;
                const float px = (float)(kk % K + ox) + dx;
                const float y0f = floorf(py), x0f = floorf(px);
                const float wy = py - y0f, wx = px - x0f;
                const int y0 = (int)y0f, x0 = (int)x0f;
                const int y1 = y0 + 1,   x1 = x0 + 1;

                const float m00 = (y0 >= 0 && y0 < H && x0 >= 0 && x0 < W) ? 1.f : 0.f;
                const float m01 = (y0 >= 0 && y0 < H && x1 >= 0 && x1 < W) ? 1.f : 0.f;
                const float m10 = (y1 >= 0 && y1 < H && x0 >= 0 && x0 < W) ? 1.f : 0.f;
                const float m11 = (y1 >= 0 && y1 < H && x1 >= 0 && x1 < W) ? 1.f : 0.f;

                const float w00 = (1.f - wy) * (1.f - wx) * m00;
                const float w01 = (1.f - wy) * wx         * m01;
                const float w10 = wy         * (1.f - wx) * m10;
                const float w11 = wy         * wx         * m11;

                const int y0c = min(max(y0, 0), H - 1), y1c = min(max(y1, 0), H - 1);
                const int x0c = min(max(x0, 0), W - 1), x1c = min(max(x1, 0), W - 1);
                const int i00 = (y0c * W + x0c) * STRIDE;
                const int i01 = (y0c * W + x1c) * STRIDE;
                const int i10 = (y1c * W + x0c) * STRIDE;
                const int i11 = (y1c * W + x1c) * STRIDE;

                if constexpr (CSPLIT % 4 == 0) {
#pragma unroll
                    for (int cg = 0; cg < CSPLIT; cg += 4) {
                        const f32x4 v00 = *(const f32x4*)(tile + i00 + cg);
                        const f32x4 v01 = *(const f32x4*)(tile + i01 + cg);
                        const f32x4 v10 = *(const f32x4*)(tile + i10 + cg);
                        const f32x4 v11 = *(const f32x4*)(tile + i11 + cg);
#pragma unroll
                        for (int j = 0; j < 4; ++j) {
                            const float sv = fmaf(v11[j], w11, fmaf(v10[j], w10,
                                             fmaf(v01[j], w01, v00[j] * w00)));
#pragma unroll
                            for (int o = 0; o < CO; ++o)
                                acc[o] = fmaf(sv, w[(size_t)(o * CI + cbase + cg + j) * KK + kk], acc[o]);
                        }
                    }
                } else {
                    const float sv = fmaf(tile[i11], w11, fmaf(tile[i10], w10,
                                     fmaf(tile[i01], w01, tile[i00] * w00)));
#pragma unroll
                    for (int o = 0; o < CO; ++o)
                        acc[o] = fmaf(sv, w[(size_t)(o * CI + cbase) * KK + kk], acc[o]);
                }
            }
        }
    }

    if (active) {
        float* op = out + ((size_t)b * CO) * HoWo + s;
#pragma unroll
        for (int o = 0; o < CO; ++o) {
            float v = acc[o] + bias[o];
            if (RELU) v = fmaxf(v, 0.f);
            op[(size_t)o * HoWo] = v;
        }
    }
}

// ---------------------------------------------------------------------------
// Register-tiled direct VALID conv (stages 1 and 6 offset convs).
// ---------------------------------------------------------------------------
template<int K, int CI, int NOC, int OC, int H, int W, int Ho, int Wo, int PIX>
__global__ __launch_bounds__(256)
void conv_tile(const float* __restrict__ x, const float* __restrict__ w,
               const float* __restrict__ bias, float* __restrict__ out)
{
    constexpr int KK   = K * K;
    constexpr int HoWo = Ho * Wo;
    constexpr int WoG  = (Wo + PIX - 1) / PIX;
    constexpr int G    = Ho * WoG;
    constexpr int XV   = PIX + K - 1;

    const int oc0   = blockIdx.y * NOC;
    const int g_all = blockIdx.x * 256 + threadIdx.x;
    const int b     = g_all / G;
    const int g     = g_all - b * G;
    const int oy    = g / WoG;
    const int ox0   = (g - oy * WoG) * PIX;

    const float* xbp = x + (b * CI) * (H * W) + oy * W + ox0;
    const float* wp  = w + oc0 * (CI * KK);

    float acc[PIX][NOC];
#pragma unroll
    for (int p = 0; p < PIX; ++p)
#pragma unroll
        for (int j = 0; j < NOC; ++j) acc[p][j] = bias[oc0 + j];

    const int lim = W - 1 - ox0;

    for (int ci = 0; ci < CI; ++ci) {
        const float* xc = xbp + ci * (H * W);
#pragma unroll
        for (int ky = 0; ky < K; ++ky) {
            float xv[XV];
#pragma unroll
            for (int i = 0; i < XV; ++i) {
                const int off = (i <= lim) ? i : lim;
                xv[i] = xc[ky * W + off];
            }
#pragma unroll
            for (int kx = 0; kx < K; ++kx) {
#pragma unroll
                for (int p = 0; p < PIX; ++p) {
                    const float v = xv[p + kx];
#pragma unroll
                    for (int j = 0; j < NOC; ++j)
                        acc[p][j] = fmaf(v, wp[j * (CI * KK) + ci * KK + ky * K + kx], acc[p][j]);
                }
            }
        }
    }

    float* op = out + (b * OC + oc0) * HoWo + oy * Wo + ox0;
#pragma unroll
    for (int p = 0; p < PIX; ++p) {
        if (ox0 + p < Wo) {
#pragma unroll
            for (int j = 0; j < NOC; ++j) op[j * HoWo + p] = acc[p][j];
        }
    }
}

// ---------------------------------------------------------------------------
// FC weight transpose: wT[i][j] = w[j][i].
// ---------------------------------------------------------------------------
template<int IN, int OUT>
__global__ __launch_bounds__(256)
void wtrans(const float* __restrict__ w, float* __restrict__ wt)
{
    const int idx = blockIdx.x * 256 + threadIdx.x;
    if (idx >= IN * OUT) return;
    const int i = idx / OUT, j = idx - i * OUT;
    wt[idx] = w[(size_t)j * IN + i];
}

// ---------------------------------------------------------------------------
// Coalesced FC: lane j reads wT[i*OUT + j] (consecutive lanes -> consecutive
// addresses); h[b*IN+i] is wave-uniform when OUT >= block width per b.
// IN/OUT compile-time -> fully unrolled, pipelined loads.
// ---------------------------------------------------------------------------
template<int IN, int OUT, bool RELU>
__global__ __launch_bounds__(256)
void fc_t(const float* __restrict__ h, const float* __restrict__ wt,
          const float* __restrict__ bias, float* __restrict__ out, int B)
{
    const int idx = blockIdx.x * 256 + threadIdx.x;
    if (idx >= B * OUT) return;
    const int b = idx / OUT;
    const int j = idx - b * OUT;
    const float* hb = h + (size_t)b * IN;
    float acc = bias[j];
#pragma unroll 4
    for (int i = 0; i < IN; ++i)
        acc = fmaf(hb[i], wt[(size_t)i * OUT + j], acc);
    if (RELU) acc = fmaxf(acc, 0.f);
    out[idx] = acc;
}

// ---------------------------------------------------------------------------
extern "C" void kernel_launch(void* const* d_in, const int* in_sizes, int n_in,
                              void* d_out, int out_size, void* d_ws, size_t ws_size,
                              hipStream_t stream)
{
    const int B = 512;
    const float* x = (const float*)d_in[0];
    const float *ow[6], *ob[6], *w[6], *bi[6];
    for (int i = 0; i < 6; ++i) {
        ow[i] = (const float*)d_in[1 + 4 * i];
        ob[i] = (const float*)d_in[2 + 4 * i];
        w[i]  = (const float*)d_in[3 + 4 * i];
        bi[i] = (const float*)d_in[4 + 4 * i];
    }
    const float* fc1w = (const float*)d_in[25];
    const float* fc1b = (const float*)d_in[26];
    const float* fc2w = (const float*)d_in[27];
    const float* fc2b = (const float*)d_in[28];
    float* out = (float*)d_out;

    float* P   = (float*)d_ws;        // 14M floats
    float* Q   = P  + 14000000;       // 14M floats
    float* OFF = Q  + 14000000;       // 18.2M floats
    float* Z   = OFF + 18200000;      // fc intermediate
    ushort_t* WBhi = (ushort_t*)(Z + 200000);   // conv_mfma weights
    ushort_t* WBlo = WBhi + 200000;
    ushort_t* WDhi = WBlo + 200000;             // deform_mfma weights
    ushort_t* WDlo = WDhi + 200000;
    float* WT1 = (float*)(WDlo + 200000);       // fc1 wT: 676*256 floats
    float* WT2 = WT1 + 173056;                  // fc2 wT: 256*10 floats

    const dim3 blk(256);
    #define GRIDT(Ho, Wo, PIX, NG) dim3((B * (Ho) * (((Wo) + (PIX) - 1) / (PIX)) + 255) / 256, (NG), 1)
    #define CEILDIV(a, b) (((a) + (b) - 1) / (b))

    // ---- stage 1: input x (CI=1). conv_tile -> OFF; deform_lds -> P ----
    conv_tile<3, 1, 6, 18, 33, 33, 31, 31, 4><<<GRIDT(31, 31, 4, 3), blk, 0, stream>>>(x, ow[0], ob[0], OFF);
    deform_lds<3, 1, 16, 33, 33, 31, 31, true, 1, 1, 512, 2><<<dim3(B * 2), dim3(512), 0, stream>>>(x, OFF, w[0], bi[0], P);

    // ---- stage 2: CI=16 K=3 31x31->29x29 OC(off)=18 CO=32. P -> Q ----
    {
        const int Mc = B * 961;
        const int Mv = B * 841;
        ushort_t* Xhi = (ushort_t*)Q;
        ushort_t* Xlo = Xhi + (size_t)(Mc + 2048) * 16;
        convert_nhwc<16, 961><<<CEILDIV(Mc, 256), blk, 0, stream>>>(P, Xhi, Xlo, Mc);
        wprep<16, 9, 10, 32, 18><<<CEILDIV(10 * 32 * 16, 256), blk, 0, stream>>>(ow[1], WBhi, WBlo);
        conv_mfma<16, 3, 31, 31, 29, 29, 18, 2, 2, 5><<<dim3(CEILDIV(Mv, 256), 1), blk, 0, stream>>>(Xhi, Xlo, WBhi, WBlo, ob[1], OFF, Mv);
        wprep_d<16, 9, 12, 32, 32><<<CEILDIV(2 * 12 * 32 * 8, 256), blk, 0, stream>>>(w[1], WDhi, WDlo);
        deform_mfma<3, 16, 32, 31, 31, 29, 29, true, 8, 12><<<dim3(B * 7), dim3(512), 0, stream>>>(P, OFF, WDhi, WDlo, bi[1], Q);
    }
    // ---- stage 3: CI=32 K=5 29x29->25x25 OC(off)=50 CO=16 (no relu). Q -> P ----
    {
        const int Mc = B * 841;
        const int Mv = B * 625;
        ushort_t* Xhi = (ushort_t*)P;
        ushort_t* Xlo = Xhi + (size_t)(Mc + 2048) * 32;
        convert_nhwc<32, 841><<<CEILDIV(Mc, 256), blk, 0, stream>>>(Q, Xhi, Xlo, Mc);
        wprep<32, 25, 25, 64, 50><<<CEILDIV(25 * 64 * 32, 256), blk, 0, stream>>>(ow[2], WBhi, WBlo);
        conv_mfma<32, 5, 29, 29, 25, 25, 50, 4, 4, 25><<<dim3(CEILDIV(Mv, 256), 1), blk, 0, stream>>>(Xhi, Xlo, WBhi, WBlo, ob[2], OFF, Mv);
        wprep_d<32, 25, 28, 16, 16><<<CEILDIV(4 * 28 * 16 * 8, 256), blk, 0, stream>>>(w[2], WDhi, WDlo);
        deform_mfma<5, 32, 16, 29, 29, 25, 25, false, 8, 28><<<dim3(B * 5), dim3(512), 0, stream>>>(Q, OFF, WDhi, WDlo, bi[2], P);
    }
    // ---- stage 4: CI=16 K=7 25x25->19x19 OC(off)=98 CO=16. P -> Q ----
    {
        const int Mc = B * 625;
        const int Mv = B * 361;
        ushort_t* Xhi = (ushort_t*)Q;
        ushort_t* Xlo = Xhi + (size_t)(Mc + 2048) * 16;
        convert_nhwc<16, 625><<<CEILDIV(Mc, 256), blk, 0, stream>>>(P, Xhi, Xlo, Mc);
        wprep<16, 49, 50, 112, 98><<<CEILDIV(50 * 112 * 16, 256), blk, 0, stream>>>(ow[3], WBhi, WBlo);
        conv_mfma<16, 7, 25, 25, 19, 19, 98, 7, 4, 25><<<dim3(CEILDIV(Mv, 256), 2), blk, 0, stream>>>(Xhi, Xlo, WBhi, WBlo, ob[3], OFF, Mv);
        wprep_d<16, 49, 52, 16, 16><<<CEILDIV(2 * 52 * 16 * 8, 256), blk, 0, stream>>>(w[3], WDhi, WDlo);
        deform_mfma<7, 16, 16, 25, 25, 19, 19, true, 8, 52><<<dim3(B * 3), dim3(512), 0, stream>>>(P, OFF, WDhi, WDlo, bi[3], Q);
    }
    // ---- stage 5: CI=16 K=5 19x19->15x15 OC(off)=50 CO=8. Q -> P ----
    {
        const int Mc = B * 361;
        const int Mv = B * 225;
        ushort_t* Xhi = (ushort_t*)P;
        ushort_t* Xlo = Xhi + (size_t)(Mc + 2048) * 16;
        convert_nhwc<16, 361><<<CEILDIV(Mc, 256), blk, 0, stream>>>(Q, Xhi, Xlo, Mc);
        wprep<16, 25, 26, 64, 50><<<CEILDIV(26 * 64 * 16, 256), blk, 0, stream>>>(ow[4], WBhi, WBlo);
        conv_mfma<16, 5, 19, 19, 15, 15, 50, 4, 4, 13><<<dim3(CEILDIV(Mv, 256), 1), blk, 0, stream>>>(Xhi, Xlo, WBhi, WBlo, ob[4], OFF, Mv);
        wprep_d<16, 25, 28, 16, 8><<<CEILDIV(2 * 28 * 16 * 8, 256), blk, 0, stream>>>(w[4], WDhi, WDlo);
        deform_mfma<5, 16, 8, 19, 19, 15, 15, true, 4, 28><<<dim3(B * 4), dim3(256), 0, stream>>>(Q, OFF, WDhi, WDlo, bi[4], P);
    }
    // ---- stage 6: CI=8 K=3 15x15->13x13 CO=4. P -> Q ----
    conv_tile<3, 8, 6, 18, 15, 15, 13, 13, 4><<<GRIDT(13, 13, 4, 3), blk, 0, stream>>>(P, ow[5], ob[5], OFF);
    deform_lds<3, 8, 4, 15, 15, 13, 13, true, 8, 12, 192, 1><<<dim3(B), dim3(192), 0, stream>>>(P, OFF, w[5], bi[5], Q);

    // ---- FC head (reads Q = 512 x 4 x 13 x 13) ----
    wtrans<676, 256><<<CEILDIV(676 * 256, 256), blk, 0, stream>>>(fc1w, WT1);
    wtrans<256, 10><<<CEILDIV(256 * 10, 256), blk, 0, stream>>>(fc2w, WT2);
    fc_t<676, 256, true><<<dim3(CEILDIV(B * 256, 256)), blk, 0, stream>>>(Q, WT1, fc1b, Z, B);
    fc_t<256, 10, false><<<dim3(CEILDIV(B * 10, 256)), blk, 0, stream>>>(Z, WT2, fc2b, out, B);

    #undef GRIDT
    #undef CEILDIV
}